// Round 1
// baseline (1345.872 us; speedup 1.0000x reference)
//
#include <hip/hip_runtime.h>

namespace {
constexpr int kB = 2;
constexpr int kC = 256;
constexpr int kH = 56;
constexpr int kW = 56;
constexpr int kN = kH * kW;        // 3136
constexpr int kNH = 8;
constexpr int kHD = 32;
constexpr int kNF = kW / 2 + 1;    // 29
constexpr int kSpec = kH * kNF;    // 1624
constexpr long kCN = (long)kC * kN;        // 802816
constexpr float kAttScale = 0.17677669529663687f;   // 32^-0.5
constexpr float kAng = 6.283185307179586f / 56.0f;  // 2*pi/56
}

// ---------------------------------------------------------------------------
// GEMM: Y[b,o,n] = sum_i W[o,i] * X[b,i,n]  (+bias | bn+relu epilogue)
// Tile: 64(o) x 128(n), BK=16. 256 threads, each 4x8.
// ---------------------------------------------------------------------------
constexpr int GO = 64, GN = 128, GK = 16;

__global__ __launch_bounds__(256)
void gemm_kernel(const float* __restrict__ Wm, const float* __restrict__ X,
                 const float* __restrict__ bias, const float* __restrict__ gamma,
                 const float* __restrict__ beta, float* __restrict__ Y,
                 int CI, long xbs, long ybs, int mode)
{
    const int b  = blockIdx.z;
    const int o0 = blockIdx.y * GO;
    const int n0 = blockIdx.x * GN;
    const float* Xb = X + (long)b * xbs;
    float* Yb = Y + (long)b * ybs;

    __shared__ float Wt[GO][GK + 1];
    __shared__ float Xt[GK][GN];

    const int tid = threadIdx.x;
    const int to = tid >> 4;   // 0..15
    const int tn = tid & 15;   // 0..15

    float acc[4][8];
#pragma unroll
    for (int i = 0; i < 4; ++i)
#pragma unroll
        for (int j = 0; j < 8; ++j) acc[i][j] = 0.f;

    for (int k0 = 0; k0 < CI; k0 += GK) {
#pragma unroll
        for (int i = 0; i < 4; ++i) {
            int el = tid + i * 256;
            int o = el >> 4, k = el & 15;
            Wt[o][k] = Wm[(long)(o0 + o) * CI + (k0 + k)];
        }
#pragma unroll
        for (int i = 0; i < 8; ++i) {
            int el = tid + i * 256;
            int k = el >> 7, n = el & 127;
            int nn = n0 + n;
            Xt[k][n] = (nn < kN) ? Xb[(long)(k0 + k) * kN + nn] : 0.f;
        }
        __syncthreads();
#pragma unroll
        for (int k = 0; k < GK; ++k) {
            const float4 xa  = *(const float4*)&Xt[k][tn * 8];
            const float4 xb4 = *(const float4*)&Xt[k][tn * 8 + 4];
            float xv[8] = {xa.x, xa.y, xa.z, xa.w, xb4.x, xb4.y, xb4.z, xb4.w};
            float wv[4] = {Wt[to * 4 + 0][k], Wt[to * 4 + 1][k],
                           Wt[to * 4 + 2][k], Wt[to * 4 + 3][k]};
#pragma unroll
            for (int i = 0; i < 4; ++i)
#pragma unroll
                for (int j = 0; j < 8; ++j)
                    acc[i][j] = fmaf(wv[i], xv[j], acc[i][j]);
        }
        __syncthreads();
    }

    const float rs = rsqrtf(1.0f + 1e-5f);
    const bool nvalid = (n0 + tn * 8) < kN;   // tail tile: per-thread all-or-nothing
    if (nvalid) {
#pragma unroll
        for (int i = 0; i < 4; ++i) {
            const int o = o0 + to * 4 + i;
            float badd = 0.f, ga = 1.f, be = 0.f;
            if (mode == 0) { if (bias) badd = bias[o]; }
            else { ga = gamma[o] * rs; be = beta[o]; }
            float* dst = Yb + (long)o * kN + n0 + tn * 8;
#pragma unroll
            for (int j = 0; j < 8; ++j) {
                float v = acc[i][j];
                v = (mode == 0) ? (v + badd) : fmaxf(fmaf(v, ga, be), 0.f);
                dst[j] = v;
            }
        }
    }
}

// ---------------------------------------------------------------------------
// Depthwise 3x3, stride 1, zero pad. input = sv slice of skv (rows 256..511)
// ---------------------------------------------------------------------------
__global__ __launch_bounds__(256)
void dwconv_kernel(const float* __restrict__ skv, const float* __restrict__ wgt,
                   const float* __restrict__ bias, float* __restrict__ out)
{
    int e = blockIdx.x * 256 + threadIdx.x;
    if (e >= kB * kC * kN) return;
    int n = e % kN; int bc = e / kN; int c = bc % kC; int b = bc / kC;
    int y = n / kW, x = n - y * kW;
    const float* src = skv + (long)b * (2 * kCN) + (long)(kC + c) * kN;
    float s = bias[c];
#pragma unroll
    for (int ky = 0; ky < 3; ++ky) {
        int yy = y + ky - 1;
        if (yy < 0 || yy >= kH) continue;
#pragma unroll
        for (int kx = 0; kx < 3; ++kx) {
            int xx = x + kx - 1;
            if (xx < 0 || xx >= kW) continue;
            s = fmaf(src[yy * kW + xx], wgt[c * 9 + ky * 3 + kx], s);
        }
    }
    out[(long)b * kCN + (long)c * kN + n] = s;
}

// ---------------------------------------------------------------------------
// Forward 2D DFT (unnormalized, e^{-i}), real 56x56 -> complex 56x29.
// One workgroup per channel. ch -> b = ch>>8, c = ch&255.
// ---------------------------------------------------------------------------
__global__ __launch_bounds__(256)
void dft_fwd_kernel(const float* __restrict__ src, long batchStride,
                    float* __restrict__ spec)
{
    const int ch = blockIdx.x;
    const int b = ch >> 8, c = ch & 255;
    const float* img = src + (long)b * batchStride + (long)c * kN;

    __shared__ float simg[kN];
    __shared__ float sA[kSpec];
    __shared__ float sB[kSpec];
    __shared__ float cs[56], sn[56];

    const int tid = threadIdx.x;
    for (int i = tid; i < kN; i += 256) simg[i] = img[i];
    if (tid < 56) { float a = tid * kAng; cs[tid] = cosf(a); sn[tid] = sinf(a); }
    __syncthreads();

    // phase 1: A[y,v] = sum_x img[y,x] cos(2pi vx/56) ; B[y,v] = sum_x img sin
    for (int idx = tid; idx < kSpec; idx += 256) {
        int y = idx / kNF, v = idx - y * kNF;
        const float* row = &simg[y * kW];
        float a = 0.f, bb = 0.f; int t = 0;
        for (int x = 0; x < kW; ++x) {
            float q = row[x];
            a  = fmaf(q, cs[t], a);
            bb = fmaf(q, sn[t], bb);
            t += v; if (t >= 56) t -= 56;
        }
        sA[idx] = a; sB[idx] = bb;
    }
    __syncthreads();

    // phase 2: Q[u,v] = sum_y (cos(uy) - i sin(uy)) * (A - iB)
    float2* outp = (float2*)spec + (long)ch * kSpec;
    for (int idx = tid; idx < kSpec; idx += 256) {
        int u = idx / kNF, v = idx - u * kNF;
        float rr = 0.f, ii = 0.f; int t = 0;
        for (int y = 0; y < kH; ++y) {
            float A = sA[y * kNF + v], Bv = sB[y * kNF + v];
            float cu = cs[t], su = sn[t];
            rr += cu * A - su * Bv;
            ii += su * A + cu * Bv;
            t += u; if (t >= 56) t -= 56;
        }
        outp[idx] = make_float2(rr, -ii);
    }
}

// ---------------------------------------------------------------------------
// Complex multiplies (elementwise)
// ---------------------------------------------------------------------------
__global__ __launch_bounds__(256)
void cmul_spec_kernel(float* __restrict__ fQ, const float* __restrict__ fK)
{
    int e = blockIdx.x * 256 + threadIdx.x;
    if (e >= kB * kC * kSpec) return;
    float2* q = (float2*)fQ; const float2* k = (const float2*)fK;
    float2 a = q[e], b = k[e];
    q[e] = make_float2(a.x * b.x - a.y * b.y, a.x * b.y + a.y * b.x);
}

__global__ __launch_bounds__(256)
void cmul_tok_kernel(float* __restrict__ fV, const float* __restrict__ cw)
{
    int e = blockIdx.x * 256 + threadIdx.x;
    if (e >= kB * kC * kSpec) return;
    int ch = e / kSpec; int j = e - ch * kSpec; int c = ch & 255;
    float2 a = ((float2*)fV)[e];
    float2 w = ((const float2*)cw)[(long)c * kSpec + j];
    ((float2*)fV)[e] = make_float2(a.x * w.x - a.y * w.y, a.x * w.y + a.y * w.x);
}

// ---------------------------------------------------------------------------
// Inverse: out[y,x] = scale * sum_{u,v} w_v Re(P[u,v] e^{+2pi i(uy+vx)/56})
// w_v = 1 for v in {0,28}, else 2 (Hermitian fold; Im of DC/Nyq cols drops out)
// ---------------------------------------------------------------------------
__global__ __launch_bounds__(256)
void dft_inv_kernel(const float* __restrict__ spec, float* __restrict__ dst,
                    float scale)
{
    const int ch = blockIdx.x;
    __shared__ float sPr[kSpec], sPi[kSpec];
    __shared__ float sT1[kSpec], sT2[kSpec];
    __shared__ float cs[56], sn[56];
    const int tid = threadIdx.x;

    const float2* P = (const float2*)spec + (long)ch * kSpec;
    for (int i = tid; i < kSpec; i += 256) { float2 p = P[i]; sPr[i] = p.x; sPi[i] = p.y; }
    if (tid < 56) { float a = tid * kAng; cs[tid] = cosf(a); sn[tid] = sinf(a); }
    __syncthreads();

    // T1[y,v] + i T2[y,v] = sum_u (Pr + iPi)(cos(uy) + i sin(uy))
    for (int idx = tid; idx < kSpec; idx += 256) {
        int y = idx / kNF, v = idx - y * kNF;
        float t1 = 0.f, t2 = 0.f; int t = 0;
        for (int u = 0; u < kH; ++u) {
            float pr = sPr[u * kNF + v], pi = sPi[u * kNF + v];
            float cu = cs[t], su = sn[t];
            t1 += pr * cu - pi * su;
            t2 += pr * su + pi * cu;
            t += y; if (t >= 56) t -= 56;
        }
        float wv = ((v == 0) || (v == kNF - 1)) ? 1.0f : 2.0f;
        wv *= scale;
        sT1[idx] = t1 * wv; sT2[idx] = t2 * wv;
    }
    __syncthreads();

    float* outp = dst + (long)ch * kN;
    for (int idx = tid; idx < kN; idx += 256) {
        int y = idx / kW, x = idx - y * kW;
        const float* T1r = &sT1[y * kNF];
        const float* T2r = &sT2[y * kNF];
        float s = 0.f; int t = 0;
        for (int v = 0; v < kNF; ++v) {
            s += T1r[v] * cs[t] - T2r[v] * sn[t];
            t += x; if (t >= 56) t -= 56;
        }
        outp[idx] = s;
    }
}

// ---------------------------------------------------------------------------
// spre: vloc = amap * sv + vloc   (sv = skv rows 256..511)
// ---------------------------------------------------------------------------
__global__ __launch_bounds__(256)
void spre_kernel(float* __restrict__ vloc, const float* __restrict__ amap,
                 const float* __restrict__ skv)
{
    long e = (long)blockIdx.x * 256 + threadIdx.x;
    if (e >= (long)kB * kCN) return;
    long b = e / kCN, r = e - b * kCN;
    float sv = skv[b * 2 * kCN + kCN + r];
    vloc[e] = fmaf(amap[e], sv, vloc[e]);
}

__global__ __launch_bounds__(256)
void add_kernel(float* __restrict__ a, const float* __restrict__ b)
{
    long e = (long)blockIdx.x * 256 + threadIdx.x;
    if (e >= (long)kB * kCN) return;
    a[e] += b[e];
}

// ---------------------------------------------------------------------------
// Token attention, fp32 streaming softmax (no max-subtract: logits are O(1)).
// One thread per query; K/V tiles of 64 keys staged in LDS.
// ---------------------------------------------------------------------------
__global__ __launch_bounds__(256)
void attn_kernel(const float* __restrict__ tq, const float* __restrict__ tkv,
                 float* __restrict__ xo)
{
    const int b = blockIdx.z, h = blockIdx.y;
    const int n = blockIdx.x * 256 + threadIdx.x;
    const bool valid = n < kN;
    const float* qb = tq  + (long)b * kCN     + (long)h * kHD * kN;
    const float* kb = tkv + (long)b * 2 * kCN + (long)h * kHD * kN;
    const float* vb = kb + kCN;

    float q[kHD];
    if (valid) {
#pragma unroll
        for (int d = 0; d < kHD; ++d) q[d] = qb[(long)d * kN + n] * kAttScale;
    } else {
#pragma unroll
        for (int d = 0; d < kHD; ++d) q[d] = 0.f;
    }

    __shared__ __align__(16) float Kt[64][36];
    __shared__ __align__(16) float Vt[64][36];

    float o[kHD];
#pragma unroll
    for (int d = 0; d < kHD; ++d) o[d] = 0.f;
    float l = 0.f;

    for (int kt = 0; kt < kN / 64; ++kt) {
        __syncthreads();
#pragma unroll
        for (int r = 0; r < 8; ++r) {
            int el = threadIdx.x + r * 256;
            int m = el & 63, d = el >> 6;
            Kt[m][d] = kb[(long)d * kN + kt * 64 + m];
            Vt[m][d] = vb[(long)d * kN + kt * 64 + m];
        }
        __syncthreads();
        if (valid) {
            for (int m = 0; m < 64; ++m) {
                const float4* kr = (const float4*)&Kt[m][0];
                float s = 0.f;
#pragma unroll
                for (int dq = 0; dq < 8; ++dq) {
                    float4 k4 = kr[dq];
                    s += q[dq * 4 + 0] * k4.x + q[dq * 4 + 1] * k4.y +
                         q[dq * 4 + 2] * k4.z + q[dq * 4 + 3] * k4.w;
                }
                float e = __expf(s);
                l += e;
                const float4* vr = (const float4*)&Vt[m][0];
#pragma unroll
                for (int dq = 0; dq < 8; ++dq) {
                    float4 v4 = vr[dq];
                    o[dq * 4 + 0] = fmaf(e, v4.x, o[dq * 4 + 0]);
                    o[dq * 4 + 1] = fmaf(e, v4.y, o[dq * 4 + 1]);
                    o[dq * 4 + 2] = fmaf(e, v4.z, o[dq * 4 + 2]);
                    o[dq * 4 + 3] = fmaf(e, v4.w, o[dq * 4 + 3]);
                }
            }
        }
    }
    if (valid) {
        float inv = 1.f / l;
#pragma unroll
        for (int d = 0; d < kHD; ++d)
            xo[(long)b * kCN + (long)(h * kHD + d) * kN + n] = o[d] * inv;
    }
}

// ---------------------------------------------------------------------------
// Gate: one wave per pixel, reduce 256-dot; sigmoid -> gate[B*N]
// ---------------------------------------------------------------------------
__global__ __launch_bounds__(256)
void gate_kernel(const float* __restrict__ hbuf, const float* __restrict__ w2,
                 const float* __restrict__ b2, float* __restrict__ gate)
{
    const int wave = threadIdx.x >> 6;
    const int lane = threadIdx.x & 63;
    const int p = blockIdx.x * 4 + wave;
    if (p >= kB * kN) return;
    const int b = p / kN, n = p - b * kN;
    const float* hb = hbuf + (long)b * kCN + n;
    float s = 0.f;
#pragma unroll
    for (int c0 = 0; c0 < kC; c0 += 64) {
        int c = c0 + lane;
        s = fmaf(w2[c], hb[(long)c * kN], s);
    }
#pragma unroll
    for (int off = 32; off > 0; off >>= 1) s += __shfl_down(s, off, 64);
    if (lane == 0) gate[p] = 1.f / (1.f + __expf(-(s + b2[0])));
}

__global__ __launch_bounds__(256)
void blend_kernel(const float* __restrict__ gcat, const float* __restrict__ gate,
                  float* __restrict__ out)
{
    long e = (long)blockIdx.x * 256 + threadIdx.x;
    if (e >= (long)kB * kCN) return;
    long b = e / kCN, r = e - b * kCN;
    long n = r % kN;
    float g = gate[b * kN + n];
    float os = gcat[b * 2 * kCN + r];
    float ot = gcat[b * 2 * kCN + kCN + r];
    out[e] = g * os + (1.f - g) * ot;
}

// ---------------------------------------------------------------------------
extern "C" void kernel_launch(void* const* d_in, const int* in_sizes, int n_in,
                              void* d_out, int out_size, void* d_ws, size_t ws_size,
                              hipStream_t stream)
{
    const float* x      = (const float*)d_in[0];
    const float* ctx    = (const float*)d_in[1];
    const float* s_q_w  = (const float*)d_in[2];
    const float* s_kv_w = (const float*)d_in[3];
    const float* s_p_w  = (const float*)d_in[4];
    const float* s_p_b  = (const float*)d_in[5];
    const float* s_dw_w = (const float*)d_in[6];
    const float* s_dw_b = (const float*)d_in[7];
    const float* t_q_w  = (const float*)d_in[8];
    const float* t_kv_w = (const float*)d_in[9];
    const float* t_p_w  = (const float*)d_in[10];
    const float* t_p_b  = (const float*)d_in[11];
    const float* t_cw   = (const float*)d_in[12];
    const float* g_w1   = (const float*)d_in[13];
    const float* g_bn_g = (const float*)d_in[14];
    const float* g_bn_b = (const float*)d_in[15];
    const float* g_w2   = (const float*)d_in[16];
    const float* g_b2   = (const float*)d_in[17];
    float* out = (float*)d_out;

    float* ws = (float*)d_ws;
    const long SPEC2 = (long)kB * kC * kSpec * 2;
    float* sq   = ws;                    // B*C*N   (later: amap, then xattn+tpre)
    float* skv  = sq   + kB * kCN;       // B*2C*N  (k rows 0..255, v rows 256..511)
    float* tq   = skv  + kB * 2 * kCN;   // B*C*N   (later: vres)
    float* tkv  = tq   + kB * kCN;       // B*2C*N  (later: h)
    float* vloc = tkv  + kB * 2 * kCN;   // B*C*N   (later: spre)
    float* fQ   = vloc + kB * kCN;       // B*C*1624*2 (later: spectral product)
    float* fK   = fQ   + SPEC2;
    float* fV   = fK   + SPEC2;          // (later: token product)
    float* gcat = fV   + SPEC2;          // B*2C*N : [os ; ot]
    float* gate = gcat + kB * 2 * kCN;   // B*N

    dim3 blk(256, 1, 1);
    const int EW = (int)((long)kB * kCN / 256);          // 6272
    const int ES = (kB * kC * kSpec + 255) / 256;        // 3248

    // 1x1 projections (q/kv both branches)
    gemm_kernel<<<dim3(25, 4, kB), blk, 0, stream>>>(s_q_w,  x,   nullptr, nullptr, nullptr, sq,  kC,     kCN, kCN,     0);
    gemm_kernel<<<dim3(25, 8, kB), blk, 0, stream>>>(s_kv_w, ctx, nullptr, nullptr, nullptr, skv, kC,     kCN, 2 * kCN, 0);
    gemm_kernel<<<dim3(25, 4, kB), blk, 0, stream>>>(t_q_w,  x,   nullptr, nullptr, nullptr, tq,  kC,     kCN, kCN,     0);
    gemm_kernel<<<dim3(25, 8, kB), blk, 0, stream>>>(t_kv_w, ctx, nullptr, nullptr, nullptr, tkv, kC,     kCN, 2 * kCN, 0);

    // spectral branch
    dwconv_kernel<<<dim3(EW), blk, 0, stream>>>(skv, s_dw_w, s_dw_b, vloc);
    dft_fwd_kernel<<<dim3(kB * kC), blk, 0, stream>>>(sq,        kCN,     fQ);
    dft_fwd_kernel<<<dim3(kB * kC), blk, 0, stream>>>(skv,       2 * kCN, fK);
    dft_fwd_kernel<<<dim3(kB * kC), blk, 0, stream>>>(tkv + kCN, 2 * kCN, fV);
    cmul_spec_kernel<<<dim3(ES), blk, 0, stream>>>(fQ, fK);
    dft_inv_kernel<<<dim3(kB * kC), blk, 0, stream>>>(fQ, sq, 1.0f / 175616.0f); // amap -> sq
    spre_kernel<<<dim3(EW), blk, 0, stream>>>(vloc, sq, skv);                    // spre -> vloc
    gemm_kernel<<<dim3(25, 4, kB), blk, 0, stream>>>(s_p_w, vloc, s_p_b, nullptr, nullptr, gcat, kC, kCN, 2 * kCN, 0); // os

    // token branch
    attn_kernel<<<dim3(13, kNH, kB), blk, 0, stream>>>(tq, tkv, sq);             // xattn -> sq
    cmul_tok_kernel<<<dim3(ES), blk, 0, stream>>>(fV, t_cw);
    dft_inv_kernel<<<dim3(kB * kC), blk, 0, stream>>>(fV, tq, 1.0f / 3136.0f);   // vres -> tq
    add_kernel<<<dim3(EW), blk, 0, stream>>>(sq, tq);                            // tpre
    gemm_kernel<<<dim3(25, 4, kB), blk, 0, stream>>>(t_p_w, sq, t_p_b, nullptr, nullptr, gcat + kCN, kC, kCN, 2 * kCN, 0); // ot

    // gate + blend
    gemm_kernel<<<dim3(25, 4, kB), blk, 0, stream>>>(g_w1, gcat, nullptr, g_bn_g, g_bn_b, tkv, 2 * kC, 2 * kCN, kCN, 1); // h -> tkv
    gate_kernel<<<dim3(kB * kN / 4), blk, 0, stream>>>(tkv, g_w2, g_b2, gate);
    blend_kernel<<<dim3(EW), blk, 0, stream>>>(gcat, gate, out);
}

// Round 2
// 812.872 us; speedup vs baseline: 1.6557x; 1.6557x over previous
//
#include <hip/hip_runtime.h>

namespace {
constexpr int kB = 2;
constexpr int kC = 256;
constexpr int kH = 56;
constexpr int kW = 56;
constexpr int kN = kH * kW;        // 3136
constexpr int kNH = 8;
constexpr int kHD = 32;
constexpr int kNF = kW / 2 + 1;    // 29
constexpr int kSpec = kH * kNF;    // 1624
constexpr long kCN = (long)kC * kN;        // 802816
constexpr float kAttScale = 0.17677669529663687f;   // 32^-0.5
constexpr float kAng = 6.283185307179586f / 56.0f;  // 2*pi/56
}

typedef __attribute__((ext_vector_type(8))) short short8;
typedef __attribute__((ext_vector_type(4))) float float4v;

union Frag {
    short8 s;
    unsigned short u[8];
    uint2 u2[2];
    uint4 u4;
};

__device__ __forceinline__ unsigned short f2b(float f) {
    unsigned u = __float_as_uint(f);
    return (unsigned short)((u + 0x7FFFu + ((u >> 16) & 1u)) >> 16);
}
__device__ __forceinline__ unsigned f2b_pk(float a, float b) {
    unsigned ua = __float_as_uint(a); ua = (ua + 0x7FFFu + ((ua >> 16) & 1u)) >> 16;
    unsigned ub = __float_as_uint(b); ub = (ub + 0x7FFFu + ((ub >> 16) & 1u)) >> 16;
    return ua | (ub << 16);
}

// ---------------------------------------------------------------------------
// GEMM: Y[b,o,n] = sum_i W[o,i] * X[b,i,n]  (+bias | bn+relu epilogue)
// ---------------------------------------------------------------------------
constexpr int GO = 64, GN = 128, GK = 16;

__global__ __launch_bounds__(256)
void gemm_kernel(const float* __restrict__ Wm, const float* __restrict__ X,
                 const float* __restrict__ bias, const float* __restrict__ gamma,
                 const float* __restrict__ beta, float* __restrict__ Y,
                 int CI, long xbs, long ybs, int mode)
{
    const int b  = blockIdx.z;
    const int o0 = blockIdx.y * GO;
    const int n0 = blockIdx.x * GN;
    const float* Xb = X + (long)b * xbs;
    float* Yb = Y + (long)b * ybs;

    __shared__ float Wt[GO][GK + 1];
    __shared__ float Xt[GK][GN];

    const int tid = threadIdx.x;
    const int to = tid >> 4;
    const int tn = tid & 15;

    float acc[4][8];
#pragma unroll
    for (int i = 0; i < 4; ++i)
#pragma unroll
        for (int j = 0; j < 8; ++j) acc[i][j] = 0.f;

    for (int k0 = 0; k0 < CI; k0 += GK) {
#pragma unroll
        for (int i = 0; i < 4; ++i) {
            int el = tid + i * 256;
            int o = el >> 4, k = el & 15;
            Wt[o][k] = Wm[(long)(o0 + o) * CI + (k0 + k)];
        }
#pragma unroll
        for (int i = 0; i < 8; ++i) {
            int el = tid + i * 256;
            int k = el >> 7, n = el & 127;
            int nn = n0 + n;
            Xt[k][n] = (nn < kN) ? Xb[(long)(k0 + k) * kN + nn] : 0.f;
        }
        __syncthreads();
#pragma unroll
        for (int k = 0; k < GK; ++k) {
            const float4 xa  = *(const float4*)&Xt[k][tn * 8];
            const float4 xb4 = *(const float4*)&Xt[k][tn * 8 + 4];
            float xv[8] = {xa.x, xa.y, xa.z, xa.w, xb4.x, xb4.y, xb4.z, xb4.w};
            float wv[4] = {Wt[to * 4 + 0][k], Wt[to * 4 + 1][k],
                           Wt[to * 4 + 2][k], Wt[to * 4 + 3][k]};
#pragma unroll
            for (int i = 0; i < 4; ++i)
#pragma unroll
                for (int j = 0; j < 8; ++j)
                    acc[i][j] = fmaf(wv[i], xv[j], acc[i][j]);
        }
        __syncthreads();
    }

    const float rs = rsqrtf(1.0f + 1e-5f);
    const bool nvalid = (n0 + tn * 8) < kN;
    if (nvalid) {
#pragma unroll
        for (int i = 0; i < 4; ++i) {
            const int o = o0 + to * 4 + i;
            float badd = 0.f, ga = 1.f, be = 0.f;
            if (mode == 0) { if (bias) badd = bias[o]; }
            else { ga = gamma[o] * rs; be = beta[o]; }
            float* dst = Yb + (long)o * kN + n0 + tn * 8;
#pragma unroll
            for (int j = 0; j < 8; ++j) {
                float v = acc[i][j];
                v = (mode == 0) ? (v + badd) : fmaxf(fmaf(v, ga, be), 0.f);
                dst[j] = v;
            }
        }
    }
}

// ---------------------------------------------------------------------------
// Depthwise 3x3
// ---------------------------------------------------------------------------
__global__ __launch_bounds__(256)
void dwconv_kernel(const float* __restrict__ skv, const float* __restrict__ wgt,
                   const float* __restrict__ bias, float* __restrict__ out)
{
    int e = blockIdx.x * 256 + threadIdx.x;
    if (e >= kB * kC * kN) return;
    int n = e % kN; int bc = e / kN; int c = bc % kC; int b = bc / kC;
    int y = n / kW, x = n - y * kW;
    const float* src = skv + (long)b * (2 * kCN) + (long)(kC + c) * kN;
    float s = bias[c];
#pragma unroll
    for (int ky = 0; ky < 3; ++ky) {
        int yy = y + ky - 1;
        if (yy < 0 || yy >= kH) continue;
#pragma unroll
        for (int kx = 0; kx < 3; ++kx) {
            int xx = x + kx - 1;
            if (xx < 0 || xx >= kW) continue;
            s = fmaf(src[yy * kW + xx], wgt[c * 9 + ky * 3 + kx], s);
        }
    }
    out[(long)b * kCN + (long)c * kN + n] = s;
}

// ---------------------------------------------------------------------------
// Forward 2D DFT (unnormalized), real 56x56 -> complex 56x29
// ---------------------------------------------------------------------------
__global__ __launch_bounds__(256)
void dft_fwd_kernel(const float* __restrict__ src, long batchStride,
                    float* __restrict__ spec)
{
    const int ch = blockIdx.x;
    const int b = ch >> 8, c = ch & 255;
    const float* img = src + (long)b * batchStride + (long)c * kN;

    __shared__ float simg[kN];
    __shared__ float sA[kSpec];
    __shared__ float sB[kSpec];
    __shared__ float cs[56], sn[56];

    const int tid = threadIdx.x;
    for (int i = tid; i < kN; i += 256) simg[i] = img[i];
    if (tid < 56) { float a = tid * kAng; cs[tid] = cosf(a); sn[tid] = sinf(a); }
    __syncthreads();

    for (int idx = tid; idx < kSpec; idx += 256) {
        int y = idx / kNF, v = idx - y * kNF;
        const float* row = &simg[y * kW];
        float a = 0.f, bb = 0.f; int t = 0;
        for (int x = 0; x < kW; ++x) {
            float q = row[x];
            a  = fmaf(q, cs[t], a);
            bb = fmaf(q, sn[t], bb);
            t += v; if (t >= 56) t -= 56;
        }
        sA[idx] = a; sB[idx] = bb;
    }
    __syncthreads();

    float2* outp = (float2*)spec + (long)ch * kSpec;
    for (int idx = tid; idx < kSpec; idx += 256) {
        int u = idx / kNF, v = idx - u * kNF;
        float rr = 0.f, ii = 0.f; int t = 0;
        for (int y = 0; y < kH; ++y) {
            float A = sA[y * kNF + v], Bv = sB[y * kNF + v];
            float cu = cs[t], su = sn[t];
            rr += cu * A - su * Bv;
            ii += su * A + cu * Bv;
            t += u; if (t >= 56) t -= 56;
        }
        outp[idx] = make_float2(rr, -ii);
    }
}

// ---------------------------------------------------------------------------
// Complex multiplies
// ---------------------------------------------------------------------------
__global__ __launch_bounds__(256)
void cmul_spec_kernel(float* __restrict__ fQ, const float* __restrict__ fK)
{
    int e = blockIdx.x * 256 + threadIdx.x;
    if (e >= kB * kC * kSpec) return;
    float2* q = (float2*)fQ; const float2* k = (const float2*)fK;
    float2 a = q[e], b = k[e];
    q[e] = make_float2(a.x * b.x - a.y * b.y, a.x * b.y + a.y * b.x);
}

__global__ __launch_bounds__(256)
void cmul_tok_kernel(float* __restrict__ fV, const float* __restrict__ cw)
{
    int e = blockIdx.x * 256 + threadIdx.x;
    if (e >= kB * kC * kSpec) return;
    int ch = e / kSpec; int j = e - ch * kSpec; int c = ch & 255;
    float2 a = ((float2*)fV)[e];
    float2 w = ((const float2*)cw)[(long)c * kSpec + j];
    ((float2*)fV)[e] = make_float2(a.x * w.x - a.y * w.y, a.x * w.y + a.y * w.x);
}

// ---------------------------------------------------------------------------
// Inverse DFT: out[y,x] = scale * sum_{u,v} w_v Re(P[u,v] e^{+i...})
// ---------------------------------------------------------------------------
__global__ __launch_bounds__(256)
void dft_inv_kernel(const float* __restrict__ spec, float* __restrict__ dst,
                    float scale)
{
    const int ch = blockIdx.x;
    __shared__ float sPr[kSpec], sPi[kSpec];
    __shared__ float sT1[kSpec], sT2[kSpec];
    __shared__ float cs[56], sn[56];
    const int tid = threadIdx.x;

    const float2* P = (const float2*)spec + (long)ch * kSpec;
    for (int i = tid; i < kSpec; i += 256) { float2 p = P[i]; sPr[i] = p.x; sPi[i] = p.y; }
    if (tid < 56) { float a = tid * kAng; cs[tid] = cosf(a); sn[tid] = sinf(a); }
    __syncthreads();

    for (int idx = tid; idx < kSpec; idx += 256) {
        int y = idx / kNF, v = idx - y * kNF;
        float t1 = 0.f, t2 = 0.f; int t = 0;
        for (int u = 0; u < kH; ++u) {
            float pr = sPr[u * kNF + v], pi = sPi[u * kNF + v];
            float cu = cs[t], su = sn[t];
            t1 += pr * cu - pi * su;
            t2 += pr * su + pi * cu;
            t += y; if (t >= 56) t -= 56;
        }
        float wv = ((v == 0) || (v == kNF - 1)) ? 1.0f : 2.0f;
        wv *= scale;
        sT1[idx] = t1 * wv; sT2[idx] = t2 * wv;
    }
    __syncthreads();

    float* outp = dst + (long)ch * kN;
    for (int idx = tid; idx < kN; idx += 256) {
        int y = idx / kW, x = idx - y * kW;
        const float* T1r = &sT1[y * kNF];
        const float* T2r = &sT2[y * kNF];
        float s = 0.f; int t = 0;
        for (int v = 0; v < kNF; ++v) {
            s += T1r[v] * cs[t] - T2r[v] * sn[t];
            t += x; if (t >= 56) t -= 56;
        }
        outp[idx] = s;
    }
}

// ---------------------------------------------------------------------------
// spre / add
// ---------------------------------------------------------------------------
__global__ __launch_bounds__(256)
void spre_kernel(float* __restrict__ vloc, const float* __restrict__ amap,
                 const float* __restrict__ skv)
{
    long e = (long)blockIdx.x * 256 + threadIdx.x;
    if (e >= (long)kB * kCN) return;
    long b = e / kCN, r = e - b * kCN;
    float sv = skv[b * 2 * kCN + kCN + r];
    vloc[e] = fmaf(amap[e], sv, vloc[e]);
}

__global__ __launch_bounds__(256)
void add_kernel(float* __restrict__ a, const float* __restrict__ b)
{
    long e = (long)blockIdx.x * 256 + threadIdx.x;
    if (e >= (long)kB * kCN) return;
    a[e] += b[e];
}

// ---------------------------------------------------------------------------
// Token attention via MFMA bf16, streaming softmax w/o max-subtract.
// Block: 256 threads = 4 waves, 32 queries/wave (128/block).
// K-tiles of 64 keys staged in LDS (K transposed, V direct), prefetched.
// S^T = K*Q^T orientation -> P packs to LDS with b64 writes / b128 A-frag reads.
// ---------------------------------------------------------------------------
__global__ __launch_bounds__(256)
void attn_mfma_kernel(const float* __restrict__ tq, const float* __restrict__ tkv,
                      float* __restrict__ xo)
{
    const int b = blockIdx.z, h = blockIdx.y;
    const int q0 = blockIdx.x * 128;
    const int tid = threadIdx.x;
    const int wave = tid >> 6, lane = tid & 63;
    const int qd = lane >> 4, ln = lane & 15;

    const float* qb = tq  + (long)b * kCN + (long)h * kHD * kN;
    const float* kb = tkv + (long)b * 2 * kCN + (long)h * kHD * kN;
    const float* vb = kb + kCN;

    __shared__ __align__(16) char smem[19712];
    unsigned short (*Kt)[36] = (unsigned short(*)[36])smem;          // [key][d]   4608 B
    unsigned short (*VT)[68] = (unsigned short(*)[68])(smem + 4608); // [d][key]   4352 B
    unsigned short* Ps = (unsigned short*)(smem + 8960);             // 4*[32q][40k] 10240 B
    float* lbuf = (float*)(smem + 19200);                            // 4*32 floats
    float (*Os)[133] = (float(*)[133])smem;                          // epilogue overlay

    unsigned short* PsW = Ps + wave * (32 * 40);

    // Q fragments (B-operand): B[k=d=qd*8+j][n=q=ln]; scale folded in.
    Frag qf[2];
#pragma unroll
    for (int qt = 0; qt < 2; ++qt) {
        int qg = q0 + wave * 32 + qt * 16 + ln;
        bool qv = qg < kN;
#pragma unroll
        for (int j = 0; j < 8; ++j) {
            int d = qd * 8 + j;
            float v = qv ? qb[(long)d * kN + qg] * kAttScale : 0.f;
            qf[qt].u[j] = f2b(v);
        }
    }

    float4v o[2][2];
#pragma unroll
    for (int qt = 0; qt < 2; ++qt)
#pragma unroll
        for (int dh = 0; dh < 2; ++dh) o[qt][dh] = (float4v){0.f, 0.f, 0.f, 0.f};
    float lsum[2] = {0.f, 0.f};

    const int nst = tid & 63, dst = tid >> 6;  // staging coords: key, d-base

    float kreg[8], vreg[8];
#pragma unroll
    for (int i = 0; i < 8; ++i) {
        int dd = dst + i * 4;
        kreg[i] = kb[(long)dd * kN + nst];
        vreg[i] = vb[(long)dd * kN + nst];
    }

    for (int k0 = 0; k0 < kN; k0 += 64) {
        // write staged tile
#pragma unroll
        for (int i = 0; i < 8; ++i) {
            int dd = dst + i * 4;
            Kt[nst][dd] = f2b(kreg[i]);
            VT[dd][nst] = f2b(vreg[i]);
        }
        __syncthreads();

        // prefetch next tile
        if (k0 + 64 < kN) {
#pragma unroll
            for (int i = 0; i < 8; ++i) {
                int dd = dst + i * 4;
                kreg[i] = kb[(long)dd * kN + (k0 + 64) + nst];
                vreg[i] = vb[(long)dd * kN + (k0 + 64) + nst];
            }
        }

        // S^T = K * Q^T  (4 key-tiles x 2 q-tiles)
        Frag ka[4];
#pragma unroll
        for (int m = 0; m < 4; ++m) {
            const unsigned short* p = &Kt[m * 16 + ln][qd * 8];
            ka[m].u2[0] = *(const uint2*)p;
            ka[m].u2[1] = *(const uint2*)(p + 4);
        }
        float4v st[4][2];
#pragma unroll
        for (int m = 0; m < 4; ++m)
#pragma unroll
            for (int qt = 0; qt < 2; ++qt)
                st[m][qt] = __builtin_amdgcn_mfma_f32_16x16x32_bf16(
                    ka[m].s, qf[qt].s, (float4v){0.f, 0.f, 0.f, 0.f}, 0, 0, 0);

        // exp, denominator accum, pack P into LDS [q][key]
#pragma unroll
        for (int m = 0; m < 4; ++m)
#pragma unroll
            for (int qt = 0; qt < 2; ++qt) {
                float e0 = __expf(st[m][qt][0]);
                float e1 = __expf(st[m][qt][1]);
                float e2 = __expf(st[m][qt][2]);
                float e3 = __expf(st[m][qt][3]);
                lsum[qt] += (e0 + e1) + (e2 + e3);
                uint2 w = make_uint2(f2b_pk(e0, e1), f2b_pk(e2, e3));
                *(uint2*)&PsW[(qt * 16 + ln) * 40 + m * 16 + qd * 4] = w;
            }

        // O += P * V  (2 key-32 groups x 2 q-tiles x 2 d-halves)
#pragma unroll
        for (int g = 0; g < 2; ++g) {
            Frag pa[2], va[2];
#pragma unroll
            for (int qt = 0; qt < 2; ++qt)
                pa[qt].u4 = *(const uint4*)&PsW[(qt * 16 + ln) * 40 + g * 32 + qd * 8];
#pragma unroll
            for (int dh = 0; dh < 2; ++dh) {
                const unsigned short* p = &VT[dh * 16 + ln][g * 32 + qd * 8];
                va[dh].u2[0] = *(const uint2*)p;
                va[dh].u2[1] = *(const uint2*)(p + 4);
            }
#pragma unroll
            for (int qt = 0; qt < 2; ++qt)
#pragma unroll
                for (int dh = 0; dh < 2; ++dh)
                    o[qt][dh] = __builtin_amdgcn_mfma_f32_16x16x32_bf16(
                        pa[qt].s, va[dh].s, o[qt][dh], 0, 0, 0);
        }
        __syncthreads();
    }

    // denominators: reduce over quads (each quad holds 8-key partials per tile pass)
#pragma unroll
    for (int qt = 0; qt < 2; ++qt) {
        lsum[qt] += __shfl_xor(lsum[qt], 16, 64);
        lsum[qt] += __shfl_xor(lsum[qt], 32, 64);
        if (qd == 0) lbuf[wave * 32 + qt * 16 + ln] = lsum[qt];
    }
    __syncthreads();

    // normalize + transpose through LDS
#pragma unroll
    for (int qt = 0; qt < 2; ++qt)
#pragma unroll
        for (int dh = 0; dh < 2; ++dh)
#pragma unroll
            for (int r = 0; r < 4; ++r) {
                float l = lbuf[wave * 32 + qt * 16 + qd * 4 + r];
                Os[dh * 16 + ln][wave * 32 + qt * 16 + qd * 4 + r] = o[qt][dh][r] / l;
            }
    __syncthreads();

    for (int i = tid; i < 32 * 128; i += 256) {
        int d = i >> 7, qq = i & 127;
        if (q0 + qq < kN)
            xo[(long)b * kCN + (long)(h * kHD + d) * kN + q0 + qq] = Os[d][qq];
    }
}

// ---------------------------------------------------------------------------
// Gate + blend
// ---------------------------------------------------------------------------
__global__ __launch_bounds__(256)
void gate_kernel(const float* __restrict__ hbuf, const float* __restrict__ w2,
                 const float* __restrict__ b2, float* __restrict__ gate)
{
    const int wave = threadIdx.x >> 6;
    const int lane = threadIdx.x & 63;
    const int p = blockIdx.x * 4 + wave;
    if (p >= kB * kN) return;
    const int b = p / kN, n = p - b * kN;
    const float* hb = hbuf + (long)b * kCN + n;
    float s = 0.f;
#pragma unroll
    for (int c0 = 0; c0 < kC; c0 += 64) {
        int c = c0 + lane;
        s = fmaf(w2[c], hb[(long)c * kN], s);
    }
#pragma unroll
    for (int off = 32; off > 0; off >>= 1) s += __shfl_down(s, off, 64);
    if (lane == 0) gate[p] = 1.f / (1.f + __expf(-(s + b2[0])));
}

__global__ __launch_bounds__(256)
void blend_kernel(const float* __restrict__ gcat, const float* __restrict__ gate,
                  float* __restrict__ out)
{
    long e = (long)blockIdx.x * 256 + threadIdx.x;
    if (e >= (long)kB * kCN) return;
    long b = e / kCN, r = e - b * kCN;
    long n = r % kN;
    float g = gate[b * kN + n];
    float os = gcat[b * 2 * kCN + r];
    float ot = gcat[b * 2 * kCN + kCN + r];
    out[e] = g * os + (1.f - g) * ot;
}

// ---------------------------------------------------------------------------
extern "C" void kernel_launch(void* const* d_in, const int* in_sizes, int n_in,
                              void* d_out, int out_size, void* d_ws, size_t ws_size,
                              hipStream_t stream)
{
    const float* x      = (const float*)d_in[0];
    const float* ctx    = (const float*)d_in[1];
    const float* s_q_w  = (const float*)d_in[2];
    const float* s_kv_w = (const float*)d_in[3];
    const float* s_p_w  = (const float*)d_in[4];
    const float* s_p_b  = (const float*)d_in[5];
    const float* s_dw_w = (const float*)d_in[6];
    const float* s_dw_b = (const float*)d_in[7];
    const float* t_q_w  = (const float*)d_in[8];
    const float* t_kv_w = (const float*)d_in[9];
    const float* t_p_w  = (const float*)d_in[10];
    const float* t_p_b  = (const float*)d_in[11];
    const float* t_cw   = (const float*)d_in[12];
    const float* g_w1   = (const float*)d_in[13];
    const float* g_bn_g = (const float*)d_in[14];
    const float* g_bn_b = (const float*)d_in[15];
    const float* g_w2   = (const float*)d_in[16];
    const float* g_b2   = (const float*)d_in[17];
    float* out = (float*)d_out;

    float* ws = (float*)d_ws;
    const long SPEC2 = (long)kB * kC * kSpec * 2;
    float* sq   = ws;                    // B*C*N   (later: amap, then xattn+tpre)
    float* skv  = sq   + kB * kCN;       // B*2C*N
    float* tq   = skv  + kB * 2 * kCN;   // B*C*N   (later: vres)
    float* tkv  = tq   + kB * kCN;       // B*2C*N  (later: h)
    float* vloc = tkv  + kB * 2 * kCN;   // B*C*N   (later: spre)
    float* fQ   = vloc + kB * kCN;
    float* fK   = fQ   + SPEC2;
    float* fV   = fK   + SPEC2;
    float* gcat = fV   + SPEC2;          // B*2C*N : [os ; ot]
    float* gate = gcat + kB * 2 * kCN;   // B*N

    dim3 blk(256, 1, 1);
    const int EW = (int)((long)kB * kCN / 256);
    const int ES = (kB * kC * kSpec + 255) / 256;

    gemm_kernel<<<dim3(25, 4, kB), blk, 0, stream>>>(s_q_w,  x,   nullptr, nullptr, nullptr, sq,  kC,     kCN, kCN,     0);
    gemm_kernel<<<dim3(25, 8, kB), blk, 0, stream>>>(s_kv_w, ctx, nullptr, nullptr, nullptr, skv, kC,     kCN, 2 * kCN, 0);
    gemm_kernel<<<dim3(25, 4, kB), blk, 0, stream>>>(t_q_w,  x,   nullptr, nullptr, nullptr, tq,  kC,     kCN, kCN,     0);
    gemm_kernel<<<dim3(25, 8, kB), blk, 0, stream>>>(t_kv_w, ctx, nullptr, nullptr, nullptr, tkv, kC,     kCN, 2 * kCN, 0);

    dwconv_kernel<<<dim3(EW), blk, 0, stream>>>(skv, s_dw_w, s_dw_b, vloc);
    dft_fwd_kernel<<<dim3(kB * kC), blk, 0, stream>>>(sq,        kCN,     fQ);
    dft_fwd_kernel<<<dim3(kB * kC), blk, 0, stream>>>(skv,       2 * kCN, fK);
    dft_fwd_kernel<<<dim3(kB * kC), blk, 0, stream>>>(tkv + kCN, 2 * kCN, fV);
    cmul_spec_kernel<<<dim3(ES), blk, 0, stream>>>(fQ, fK);
    dft_inv_kernel<<<dim3(kB * kC), blk, 0, stream>>>(fQ, sq, 1.0f / 175616.0f); // amap
    spre_kernel<<<dim3(EW), blk, 0, stream>>>(vloc, sq, skv);
    gemm_kernel<<<dim3(25, 4, kB), blk, 0, stream>>>(s_p_w, vloc, s_p_b, nullptr, nullptr, gcat, kC, kCN, 2 * kCN, 0); // os

    attn_mfma_kernel<<<dim3(25, kNH, kB), blk, 0, stream>>>(tq, tkv, sq);        // xattn
    cmul_tok_kernel<<<dim3(ES), blk, 0, stream>>>(fV, t_cw);
    dft_inv_kernel<<<dim3(kB * kC), blk, 0, stream>>>(fV, tq, 1.0f / 3136.0f);   // vres
    add_kernel<<<dim3(EW), blk, 0, stream>>>(sq, tq);                            // tpre
    gemm_kernel<<<dim3(25, 4, kB), blk, 0, stream>>>(t_p_w, sq, t_p_b, nullptr, nullptr, gcat + kCN, kC, kCN, 2 * kCN, 0); // ot

    gemm_kernel<<<dim3(25, 4, kB), blk, 0, stream>>>(g_w1, gcat, nullptr, g_bn_g, g_bn_b, tkv, 2 * kC, 2 * kCN, kCN, 1); // h
    gate_kernel<<<dim3(kB * kN / 4), blk, 0, stream>>>(tkv, g_w2, g_b2, gate);
    blend_kernel<<<dim3(EW), blk, 0, stream>>>(gcat, gate, out);
}

// Round 3
// 543.647 us; speedup vs baseline: 2.4756x; 1.4952x over previous
//
#include <hip/hip_runtime.h>

namespace {
constexpr int kB = 2;
constexpr int kC = 256;
constexpr int kH = 56;
constexpr int kW = 56;
constexpr int kN = kH * kW;        // 3136
constexpr int kNH = 8;
constexpr int kHD = 32;
constexpr int kNF = kW / 2 + 1;    // 29
constexpr int kSpec = kH * kNF;    // 1624
constexpr long kCN = (long)kC * kN;        // 802816
constexpr float kAttScale = 0.17677669529663687f;   // 32^-0.5
constexpr float kAng = 6.283185307179586f / 56.0f;  // 2*pi/56
}

typedef __attribute__((ext_vector_type(8))) short short8;
typedef __attribute__((ext_vector_type(4))) float float4v;

union Frag {
    short8 s;
    unsigned short u[8];
    uint2 u2[2];
    uint4 u4;
};

__device__ __forceinline__ unsigned short f2b(float f) {
    unsigned u = __float_as_uint(f);
    return (unsigned short)((u + 0x7FFFu + ((u >> 16) & 1u)) >> 16);
}
__device__ __forceinline__ unsigned f2b_pk(float a, float b) {
    unsigned ua = __float_as_uint(a); ua = (ua + 0x7FFFu + ((ua >> 16) & 1u)) >> 16;
    unsigned ub = __float_as_uint(b); ub = (ub + 0x7FFFu + ((ub >> 16) & 1u)) >> 16;
    return ua | (ub << 16);
}
__device__ __forceinline__ uint4 pk8(const float* v) {
    return make_uint4(f2b_pk(v[0], v[1]), f2b_pk(v[2], v[3]),
                      f2b_pk(v[4], v[5]), f2b_pk(v[6], v[7]));
}

// ---------------------------------------------------------------------------
// MFMA GEMM: Y[b,o,n] = sum_i W[o,i] * X[b,i,n]  (+bias | bn+relu epilogue)
// Block 64o x 128n, 4 waves of 32o x 64n (2x4 tiles of 16x16x32 bf16), BK=32.
// LDS: Wt[o][k] (A-frags b128), Xt[n][k] transposed (B-frags b128), pad->40.
// X staged k-major: thread owns one n col, 16 k vals -> coalesced dword loads.
// ---------------------------------------------------------------------------
__global__ __launch_bounds__(256)
void gemm_kernel(const float* __restrict__ Wm, const float* __restrict__ X,
                 const float* __restrict__ bias, const float* __restrict__ gamma,
                 const float* __restrict__ beta, float* __restrict__ Y,
                 int CI, long xbs, long ybs, int mode)
{
    const int b  = blockIdx.z;
    const int o0 = blockIdx.y * 64;
    const int n0 = blockIdx.x * 128;
    const float* Xb = X + (long)b * xbs;
    float* Yb = Y + (long)b * ybs;

    __shared__ __align__(16) unsigned short Wt[64][40];
    __shared__ __align__(16) unsigned short Xt[128][40];

    const int tid = threadIdx.x;
    const int wave = tid >> 6, lane = tid & 63;
    const int ln = lane & 15, qd = lane >> 4;
    const int wy = wave >> 1, wx = wave & 1;

    // staging coords
    const int ow = tid >> 2, kcw = tid & 3;      // W: row o, k-chunk (8 k)
    const int nx = tid & 127, kcx = tid >> 7;    // X: col n, 16-k half
    const bool xvalid = (n0 + nx) < kN;

    float4v acc[2][4];
#pragma unroll
    for (int i = 0; i < 2; ++i)
#pragma unroll
        for (int j = 0; j < 4; ++j) acc[i][j] = (float4v){0.f, 0.f, 0.f, 0.f};

    float wpre[8], xpre[16];
    {
        const float* ws = Wm + (long)(o0 + ow) * CI + kcw * 8;
        *(float4*)&wpre[0] = *(const float4*)ws;
        *(float4*)&wpre[4] = *(const float4*)(ws + 4);
#pragma unroll
        for (int j = 0; j < 16; ++j)
            xpre[j] = xvalid ? Xb[(long)(kcx * 16 + j) * kN + n0 + nx] : 0.f;
    }

    for (int k0 = 0; k0 < CI; k0 += 32) {
        *(uint4*)&Wt[ow][kcw * 8]      = pk8(wpre);
        *(uint4*)&Xt[nx][kcx * 16]     = pk8(xpre);
        *(uint4*)&Xt[nx][kcx * 16 + 8] = pk8(xpre + 8);
        __syncthreads();

        if (k0 + 32 < CI) {
            const float* ws = Wm + (long)(o0 + ow) * CI + k0 + 32 + kcw * 8;
            *(float4*)&wpre[0] = *(const float4*)ws;
            *(float4*)&wpre[4] = *(const float4*)(ws + 4);
#pragma unroll
            for (int j = 0; j < 16; ++j)
                xpre[j] = xvalid ? Xb[(long)(k0 + 32 + kcx * 16 + j) * kN + n0 + nx] : 0.f;
        }

        Frag af[2], bf4[4];
#pragma unroll
        for (int mt = 0; mt < 2; ++mt)
            af[mt].u4 = *(const uint4*)&Wt[wy * 32 + mt * 16 + ln][qd * 8];
#pragma unroll
        for (int nt = 0; nt < 4; ++nt)
            bf4[nt].u4 = *(const uint4*)&Xt[wx * 64 + nt * 16 + ln][qd * 8];
#pragma unroll
        for (int mt = 0; mt < 2; ++mt)
#pragma unroll
            for (int nt = 0; nt < 4; ++nt)
                acc[mt][nt] = __builtin_amdgcn_mfma_f32_16x16x32_bf16(
                    af[mt].s, bf4[nt].s, acc[mt][nt], 0, 0, 0);
        __syncthreads();
    }

    const float rs = rsqrtf(1.0f + 1e-5f);
#pragma unroll
    for (int mt = 0; mt < 2; ++mt) {
        const int ob = o0 + wy * 32 + mt * 16 + qd * 4;
#pragma unroll
        for (int nt = 0; nt < 4; ++nt) {
            const int n = n0 + wx * 64 + nt * 16 + ln;
            if (n < kN) {
#pragma unroll
                for (int r = 0; r < 4; ++r) {
                    const int o = ob + r;
                    float v = acc[mt][nt][r];
                    if (mode == 0) { if (bias) v += bias[o]; }
                    else v = fmaxf(fmaf(v, gamma[o] * rs, beta[o]), 0.f);
                    Yb[(long)o * kN + n] = v;
                }
            }
        }
    }
}

// ---------------------------------------------------------------------------
// Depthwise 3x3
// ---------------------------------------------------------------------------
__global__ __launch_bounds__(256)
void dwconv_kernel(const float* __restrict__ skv, const float* __restrict__ wgt,
                   const float* __restrict__ bias, float* __restrict__ out)
{
    int e = blockIdx.x * 256 + threadIdx.x;
    if (e >= kB * kC * kN) return;
    int n = e % kN; int bc = e / kN; int c = bc % kC; int b = bc / kC;
    int y = n / kW, x = n - y * kW;
    const float* src = skv + (long)b * (2 * kCN) + (long)(kC + c) * kN;
    float s = bias[c];
#pragma unroll
    for (int ky = 0; ky < 3; ++ky) {
        int yy = y + ky - 1;
        if (yy < 0 || yy >= kH) continue;
#pragma unroll
        for (int kx = 0; kx < 3; ++kx) {
            int xx = x + kx - 1;
            if (xx < 0 || xx >= kW) continue;
            s = fmaf(src[yy * kW + xx], wgt[c * 9 + ky * 3 + kx], s);
        }
    }
    out[(long)b * kCN + (long)c * kN + n] = s;
}

// ---------------------------------------------------------------------------
// Forward 2D DFT (unnormalized), real 56x56 -> complex 56x29
// ---------------------------------------------------------------------------
__global__ __launch_bounds__(256)
void dft_fwd_kernel(const float* __restrict__ src, long batchStride,
                    float* __restrict__ spec)
{
    const int ch = blockIdx.x;
    const int b = ch >> 8, c = ch & 255;
    const float* img = src + (long)b * batchStride + (long)c * kN;

    __shared__ float simg[kN];
    __shared__ float sA[kSpec];
    __shared__ float sB[kSpec];
    __shared__ float cs[56], sn[56];

    const int tid = threadIdx.x;
    for (int i = tid; i < kN; i += 256) simg[i] = img[i];
    if (tid < 56) { float a = tid * kAng; cs[tid] = cosf(a); sn[tid] = sinf(a); }
    __syncthreads();

    for (int idx = tid; idx < kSpec; idx += 256) {
        int y = idx / kNF, v = idx - y * kNF;
        const float* row = &simg[y * kW];
        float a = 0.f, bb = 0.f; int t = 0;
        for (int x = 0; x < kW; ++x) {
            float q = row[x];
            a  = fmaf(q, cs[t], a);
            bb = fmaf(q, sn[t], bb);
            t += v; if (t >= 56) t -= 56;
        }
        sA[idx] = a; sB[idx] = bb;
    }
    __syncthreads();

    float2* outp = (float2*)spec + (long)ch * kSpec;
    for (int idx = tid; idx < kSpec; idx += 256) {
        int u = idx / kNF, v = idx - u * kNF;
        float rr = 0.f, ii = 0.f; int t = 0;
        for (int y = 0; y < kH; ++y) {
            float A = sA[y * kNF + v], Bv = sB[y * kNF + v];
            float cu = cs[t], su = sn[t];
            rr += cu * A - su * Bv;
            ii += su * A + cu * Bv;
            t += u; if (t >= 56) t -= 56;
        }
        outp[idx] = make_float2(rr, -ii);
    }
}

// ---------------------------------------------------------------------------
// Complex multiplies
// ---------------------------------------------------------------------------
__global__ __launch_bounds__(256)
void cmul_spec_kernel(float* __restrict__ fQ, const float* __restrict__ fK)
{
    int e = blockIdx.x * 256 + threadIdx.x;
    if (e >= kB * kC * kSpec) return;
    float2* q = (float2*)fQ; const float2* k = (const float2*)fK;
    float2 a = q[e], b = k[e];
    q[e] = make_float2(a.x * b.x - a.y * b.y, a.x * b.y + a.y * b.x);
}

__global__ __launch_bounds__(256)
void cmul_tok_kernel(float* __restrict__ fV, const float* __restrict__ cw)
{
    int e = blockIdx.x * 256 + threadIdx.x;
    if (e >= kB * kC * kSpec) return;
    int ch = e / kSpec; int j = e - ch * kSpec; int c = ch & 255;
    float2 a = ((float2*)fV)[e];
    float2 w = ((const float2*)cw)[(long)c * kSpec + j];
    ((float2*)fV)[e] = make_float2(a.x * w.x - a.y * w.y, a.x * w.y + a.y * w.x);
}

// ---------------------------------------------------------------------------
// Inverse DFT: out[y,x] = scale * sum_{u,v} w_v Re(P[u,v] e^{+i...})
// ---------------------------------------------------------------------------
__global__ __launch_bounds__(256)
void dft_inv_kernel(const float* __restrict__ spec, float* __restrict__ dst,
                    float scale)
{
    const int ch = blockIdx.x;
    __shared__ float sPr[kSpec], sPi[kSpec];
    __shared__ float sT1[kSpec], sT2[kSpec];
    __shared__ float cs[56], sn[56];
    const int tid = threadIdx.x;

    const float2* P = (const float2*)spec + (long)ch * kSpec;
    for (int i = tid; i < kSpec; i += 256) { float2 p = P[i]; sPr[i] = p.x; sPi[i] = p.y; }
    if (tid < 56) { float a = tid * kAng; cs[tid] = cosf(a); sn[tid] = sinf(a); }
    __syncthreads();

    for (int idx = tid; idx < kSpec; idx += 256) {
        int y = idx / kNF, v = idx - y * kNF;
        float t1 = 0.f, t2 = 0.f; int t = 0;
        for (int u = 0; u < kH; ++u) {
            float pr = sPr[u * kNF + v], pi = sPi[u * kNF + v];
            float cu = cs[t], su = sn[t];
            t1 += pr * cu - pi * su;
            t2 += pr * su + pi * cu;
            t += y; if (t >= 56) t -= 56;
        }
        float wv = ((v == 0) || (v == kNF - 1)) ? 1.0f : 2.0f;
        wv *= scale;
        sT1[idx] = t1 * wv; sT2[idx] = t2 * wv;
    }
    __syncthreads();

    float* outp = dst + (long)ch * kN;
    for (int idx = tid; idx < kN; idx += 256) {
        int y = idx / kW, x = idx - y * kW;
        const float* T1r = &sT1[y * kNF];
        const float* T2r = &sT2[y * kNF];
        float s = 0.f; int t = 0;
        for (int v = 0; v < kNF; ++v) {
            s += T1r[v] * cs[t] - T2r[v] * sn[t];
            t += x; if (t >= 56) t -= 56;
        }
        outp[idx] = s;
    }
}

// ---------------------------------------------------------------------------
// spre / add
// ---------------------------------------------------------------------------
__global__ __launch_bounds__(256)
void spre_kernel(float* __restrict__ vloc, const float* __restrict__ amap,
                 const float* __restrict__ skv)
{
    long e = (long)blockIdx.x * 256 + threadIdx.x;
    if (e >= (long)kB * kCN) return;
    long b = e / kCN, r = e - b * kCN;
    float sv = skv[b * 2 * kCN + kCN + r];
    vloc[e] = fmaf(amap[e], sv, vloc[e]);
}

__global__ __launch_bounds__(256)
void add_kernel(float* __restrict__ a, const float* __restrict__ b)
{
    long e = (long)blockIdx.x * 256 + threadIdx.x;
    if (e >= (long)kB * kCN) return;
    a[e] += b[e];
}

// ---------------------------------------------------------------------------
// Token attention via MFMA bf16 (unchanged from round 2)
// ---------------------------------------------------------------------------
__global__ __launch_bounds__(256)
void attn_mfma_kernel(const float* __restrict__ tq, const float* __restrict__ tkv,
                      float* __restrict__ xo)
{
    const int b = blockIdx.z, h = blockIdx.y;
    const int q0 = blockIdx.x * 128;
    const int tid = threadIdx.x;
    const int wave = tid >> 6, lane = tid & 63;
    const int qd = lane >> 4, ln = lane & 15;

    const float* qb = tq  + (long)b * kCN + (long)h * kHD * kN;
    const float* kb = tkv + (long)b * 2 * kCN + (long)h * kHD * kN;
    const float* vb = kb + kCN;

    __shared__ __align__(16) char smem[19712];
    unsigned short (*Kt)[36] = (unsigned short(*)[36])smem;
    unsigned short (*VT)[68] = (unsigned short(*)[68])(smem + 4608);
    unsigned short* Ps = (unsigned short*)(smem + 8960);
    float* lbuf = (float*)(smem + 19200);
    float (*Os)[133] = (float(*)[133])smem;

    unsigned short* PsW = Ps + wave * (32 * 40);

    Frag qf[2];
#pragma unroll
    for (int qt = 0; qt < 2; ++qt) {
        int qg = q0 + wave * 32 + qt * 16 + ln;
        bool qv = qg < kN;
#pragma unroll
        for (int j = 0; j < 8; ++j) {
            int d = qd * 8 + j;
            float v = qv ? qb[(long)d * kN + qg] * kAttScale : 0.f;
            qf[qt].u[j] = f2b(v);
        }
    }

    float4v o[2][2];
#pragma unroll
    for (int qt = 0; qt < 2; ++qt)
#pragma unroll
        for (int dh = 0; dh < 2; ++dh) o[qt][dh] = (float4v){0.f, 0.f, 0.f, 0.f};
    float lsum[2] = {0.f, 0.f};

    const int nst = tid & 63, dst = tid >> 6;

    float kreg[8], vreg[8];
#pragma unroll
    for (int i = 0; i < 8; ++i) {
        int dd = dst + i * 4;
        kreg[i] = kb[(long)dd * kN + nst];
        vreg[i] = vb[(long)dd * kN + nst];
    }

    for (int k0 = 0; k0 < kN; k0 += 64) {
#pragma unroll
        for (int i = 0; i < 8; ++i) {
            int dd = dst + i * 4;
            Kt[nst][dd] = f2b(kreg[i]);
            VT[dd][nst] = f2b(vreg[i]);
        }
        __syncthreads();

        if (k0 + 64 < kN) {
#pragma unroll
            for (int i = 0; i < 8; ++i) {
                int dd = dst + i * 4;
                kreg[i] = kb[(long)dd * kN + (k0 + 64) + nst];
                vreg[i] = vb[(long)dd * kN + (k0 + 64) + nst];
            }
        }

        Frag ka[4];
#pragma unroll
        for (int m = 0; m < 4; ++m) {
            const unsigned short* p = &Kt[m * 16 + ln][qd * 8];
            ka[m].u2[0] = *(const uint2*)p;
            ka[m].u2[1] = *(const uint2*)(p + 4);
        }
        float4v st[4][2];
#pragma unroll
        for (int m = 0; m < 4; ++m)
#pragma unroll
            for (int qt = 0; qt < 2; ++qt)
                st[m][qt] = __builtin_amdgcn_mfma_f32_16x16x32_bf16(
                    ka[m].s, qf[qt].s, (float4v){0.f, 0.f, 0.f, 0.f}, 0, 0, 0);

#pragma unroll
        for (int m = 0; m < 4; ++m)
#pragma unroll
            for (int qt = 0; qt < 2; ++qt) {
                float e0 = __expf(st[m][qt][0]);
                float e1 = __expf(st[m][qt][1]);
                float e2 = __expf(st[m][qt][2]);
                float e3 = __expf(st[m][qt][3]);
                lsum[qt] += (e0 + e1) + (e2 + e3);
                uint2 w = make_uint2(f2b_pk(e0, e1), f2b_pk(e2, e3));
                *(uint2*)&PsW[(qt * 16 + ln) * 40 + m * 16 + qd * 4] = w;
            }

#pragma unroll
        for (int g = 0; g < 2; ++g) {
            Frag pa[2], va[2];
#pragma unroll
            for (int qt = 0; qt < 2; ++qt)
                pa[qt].u4 = *(const uint4*)&PsW[(qt * 16 + ln) * 40 + g * 32 + qd * 8];
#pragma unroll
            for (int dh = 0; dh < 2; ++dh) {
                const unsigned short* p = &VT[dh * 16 + ln][g * 32 + qd * 8];
                va[dh].u2[0] = *(const uint2*)p;
                va[dh].u2[1] = *(const uint2*)(p + 4);
            }
#pragma unroll
            for (int qt = 0; qt < 2; ++qt)
#pragma unroll
                for (int dh = 0; dh < 2; ++dh)
                    o[qt][dh] = __builtin_amdgcn_mfma_f32_16x16x32_bf16(
                        pa[qt].s, va[dh].s, o[qt][dh], 0, 0, 0);
        }
        __syncthreads();
    }

#pragma unroll
    for (int qt = 0; qt < 2; ++qt) {
        lsum[qt] += __shfl_xor(lsum[qt], 16, 64);
        lsum[qt] += __shfl_xor(lsum[qt], 32, 64);
        if (qd == 0) lbuf[wave * 32 + qt * 16 + ln] = lsum[qt];
    }
    __syncthreads();

#pragma unroll
    for (int qt = 0; qt < 2; ++qt)
#pragma unroll
        for (int dh = 0; dh < 2; ++dh)
#pragma unroll
            for (int r = 0; r < 4; ++r) {
                float l = lbuf[wave * 32 + qt * 16 + qd * 4 + r];
                Os[dh * 16 + ln][wave * 32 + qt * 16 + qd * 4 + r] = o[qt][dh][r] / l;
            }
    __syncthreads();

    for (int i = tid; i < 32 * 128; i += 256) {
        int d = i >> 7, qq = i & 127;
        if (q0 + qq < kN)
            xo[(long)b * kCN + (long)(h * kHD + d) * kN + q0 + qq] = Os[d][qq];
    }
}

// ---------------------------------------------------------------------------
// Gate + blend
// ---------------------------------------------------------------------------
__global__ __launch_bounds__(256)
void gate_kernel(const float* __restrict__ hbuf, const float* __restrict__ w2,
                 const float* __restrict__ b2, float* __restrict__ gate)
{
    const int wave = threadIdx.x >> 6;
    const int lane = threadIdx.x & 63;
    const int p = blockIdx.x * 4 + wave;
    if (p >= kB * kN) return;
    const int b = p / kN, n = p - b * kN;
    const float* hb = hbuf + (long)b * kCN + n;
    float s = 0.f;
#pragma unroll
    for (int c0 = 0; c0 < kC; c0 += 64) {
        int c = c0 + lane;
        s = fmaf(w2[c], hb[(long)c * kN], s);
    }
#pragma unroll
    for (int off = 32; off > 0; off >>= 1) s += __shfl_down(s, off, 64);
    if (lane == 0) gate[p] = 1.f / (1.f + __expf(-(s + b2[0])));
}

__global__ __launch_bounds__(256)
void blend_kernel(const float* __restrict__ gcat, const float* __restrict__ gate,
                  float* __restrict__ out)
{
    long e = (long)blockIdx.x * 256 + threadIdx.x;
    if (e >= (long)kB * kCN) return;
    long b = e / kCN, r = e - b * kCN;
    long n = r % kN;
    float g = gate[b * kN + n];
    float os = gcat[b * 2 * kCN + r];
    float ot = gcat[b * 2 * kCN + kCN + r];
    out[e] = g * os + (1.f - g) * ot;
}

// ---------------------------------------------------------------------------
extern "C" void kernel_launch(void* const* d_in, const int* in_sizes, int n_in,
                              void* d_out, int out_size, void* d_ws, size_t ws_size,
                              hipStream_t stream)
{
    const float* x      = (const float*)d_in[0];
    const float* ctx    = (const float*)d_in[1];
    const float* s_q_w  = (const float*)d_in[2];
    const float* s_kv_w = (const float*)d_in[3];
    const float* s_p_w  = (const float*)d_in[4];
    const float* s_p_b  = (const float*)d_in[5];
    const float* s_dw_w = (const float*)d_in[6];
    const float* s_dw_b = (const float*)d_in[7];
    const float* t_q_w  = (const float*)d_in[8];
    const float* t_kv_w = (const float*)d_in[9];
    const float* t_p_w  = (const float*)d_in[10];
    const float* t_p_b  = (const float*)d_in[11];
    const float* t_cw   = (const float*)d_in[12];
    const float* g_w1   = (const float*)d_in[13];
    const float* g_bn_g = (const float*)d_in[14];
    const float* g_bn_b = (const float*)d_in[15];
    const float* g_w2   = (const float*)d_in[16];
    const float* g_b2   = (const float*)d_in[17];
    float* out = (float*)d_out;

    float* ws = (float*)d_ws;
    const long SPEC2 = (long)kB * kC * kSpec * 2;
    float* sq   = ws;                    // B*C*N   (later: amap, then xattn+tpre)
    float* skv  = sq   + kB * kCN;       // B*2C*N
    float* tq   = skv  + kB * 2 * kCN;   // B*C*N   (later: vres)
    float* tkv  = tq   + kB * kCN;       // B*2C*N  (later: h)
    float* vloc = tkv  + kB * 2 * kCN;   // B*C*N   (later: spre)
    float* fQ   = vloc + kB * kCN;
    float* fK   = fQ   + SPEC2;
    float* fV   = fK   + SPEC2;
    float* gcat = fV   + SPEC2;          // B*2C*N : [os ; ot]
    float* gate = gcat + kB * 2 * kCN;   // B*N

    dim3 blk(256, 1, 1);
    const int EW = (int)((long)kB * kCN / 256);
    const int ES = (kB * kC * kSpec + 255) / 256;

    gemm_kernel<<<dim3(25, 4, kB), blk, 0, stream>>>(s_q_w,  x,   nullptr, nullptr, nullptr, sq,  kC,     kCN, kCN,     0);
    gemm_kernel<<<dim3(25, 8, kB), blk, 0, stream>>>(s_kv_w, ctx, nullptr, nullptr, nullptr, skv, kC,     kCN, 2 * kCN, 0);
    gemm_kernel<<<dim3(25, 4, kB), blk, 0, stream>>>(t_q_w,  x,   nullptr, nullptr, nullptr, tq,  kC,     kCN, kCN,     0);
    gemm_kernel<<<dim3(25, 8, kB), blk, 0, stream>>>(t_kv_w, ctx, nullptr, nullptr, nullptr, tkv, kC,     kCN, 2 * kCN, 0);

    dwconv_kernel<<<dim3(EW), blk, 0, stream>>>(skv, s_dw_w, s_dw_b, vloc);
    dft_fwd_kernel<<<dim3(kB * kC), blk, 0, stream>>>(sq,        kCN,     fQ);
    dft_fwd_kernel<<<dim3(kB * kC), blk, 0, stream>>>(skv,       2 * kCN, fK);
    dft_fwd_kernel<<<dim3(kB * kC), blk, 0, stream>>>(tkv + kCN, 2 * kCN, fV);
    cmul_spec_kernel<<<dim3(ES), blk, 0, stream>>>(fQ, fK);
    dft_inv_kernel<<<dim3(kB * kC), blk, 0, stream>>>(fQ, sq, 1.0f / 175616.0f); // amap
    spre_kernel<<<dim3(EW), blk, 0, stream>>>(vloc, sq, skv);
    gemm_kernel<<<dim3(25, 4, kB), blk, 0, stream>>>(s_p_w, vloc, s_p_b, nullptr, nullptr, gcat, kC, kCN, 2 * kCN, 0); // os

    attn_mfma_kernel<<<dim3(25, kNH, kB), blk, 0, stream>>>(tq, tkv, sq);        // xattn
    cmul_tok_kernel<<<dim3(ES), blk, 0, stream>>>(fV, t_cw);
    dft_inv_kernel<<<dim3(kB * kC), blk, 0, stream>>>(fV, tq, 1.0f / 3136.0f);   // vres
    add_kernel<<<dim3(EW), blk, 0, stream>>>(sq, tq);                            // tpre
    gemm_kernel<<<dim3(25, 4, kB), blk, 0, stream>>>(t_p_w, sq, t_p_b, nullptr, nullptr, gcat + kCN, kC, kCN, 2 * kCN, 0); // ot

    gemm_kernel<<<dim3(25, 4, kB), blk, 0, stream>>>(g_w1, gcat, nullptr, g_bn_g, g_bn_b, tkv, 2 * kC, 2 * kCN, kCN, 1); // h
    gate_kernel<<<dim3(kB * kN / 4), blk, 0, stream>>>(tkv, g_w2, g_b2, gate);
    blend_kernel<<<dim3(EW), blk, 0, stream>>>(gcat, gate, out);
}

// Round 4
// 391.240 us; speedup vs baseline: 3.4400x; 1.3895x over previous
//
#include <hip/hip_runtime.h>

namespace {
constexpr int kB = 2;
constexpr int kC = 256;
constexpr int kH = 56;
constexpr int kW = 56;
constexpr int kN = kH * kW;        // 3136
constexpr int kNH = 8;
constexpr int kHD = 32;
constexpr int kNF = kW / 2 + 1;    // 29
constexpr int kSpec = kH * kNF;    // 1624
constexpr long kCN = (long)kC * kN;        // 802816
constexpr float kAttScale = 0.17677669529663687f;   // 32^-0.5
constexpr float kAng = 6.283185307179586f / 56.0f;  // 2*pi/56
// twiddle table offsets in u16 units
constexpr int TW1F = 0;            // [128][64]
constexpr int TW2F = 8192;         // [64][64]
constexpr int TW1I = 12288;        // [128][64]
constexpr int TW2I = 20480;        // [64][64]
constexpr int TWTOT = 24576;
}

typedef __attribute__((ext_vector_type(8))) short short8;
typedef __attribute__((ext_vector_type(4))) float float4v;

union Frag {
    short8 s;
    unsigned short u[8];
    uint2 u2[2];
    uint4 u4;
};

__device__ __forceinline__ unsigned short f2b(float f) {
    unsigned u = __float_as_uint(f);
    return (unsigned short)((u + 0x7FFFu + ((u >> 16) & 1u)) >> 16);
}
__device__ __forceinline__ unsigned f2b_pk(float a, float b) {
    unsigned ua = __float_as_uint(a); ua = (ua + 0x7FFFu + ((ua >> 16) & 1u)) >> 16;
    unsigned ub = __float_as_uint(b); ub = (ub + 0x7FFFu + ((ub >> 16) & 1u)) >> 16;
    return ua | (ub << 16);
}
__device__ __forceinline__ uint4 pk8(const float* v) {
    return make_uint4(f2b_pk(v[0], v[1]), f2b_pk(v[2], v[3]),
                      f2b_pk(v[4], v[5]), f2b_pk(v[6], v[7]));
}

// ---------------------------------------------------------------------------
// Twiddle tables (bf16), built fresh every launch into d_ws.
// TW1F[uc][y]: uc<56: cos(uy), 56..111: sin(uy), else 0; cols>=56 zero.
// TW2F[vc][x]: vc<29: cos(vx), 32..60: sin(vx), else 0; cols>=56 zero.
// TW1I[yc][u]: yc<56: cos(yu), 64..119: sin(yu), else 0; cols>=56 zero.
// TW2I[x][vc]: vc=2v: wv*cos(vx); 2v+1: -wv*sin(vx) (v<29,x<56); else 0.
// ---------------------------------------------------------------------------
__global__ __launch_bounds__(256)
void twiddle_init_kernel(unsigned short* __restrict__ tw)
{
    int idx = blockIdx.x * 256 + threadIdx.x;
    if (idx >= TWTOT) return;
    float val = 0.f;
    if (idx < TW2F) {                       // TW1F
        int r = idx >> 6, c = idx & 63;
        if (c < 56) {
            if (r < 56)       val = cosf(kAng * (float)((r * c) % 56));
            else if (r < 112) val = sinf(kAng * (float)(((r - 56) * c) % 56));
        }
    } else if (idx < TW1I) {                // TW2F
        int t = idx - TW2F; int r = t >> 6, c = t & 63;
        if (c < 56) {
            if (r < 29)                  val = cosf(kAng * (float)((r * c) % 56));
            else if (r >= 32 && r < 61)  val = sinf(kAng * (float)(((r - 32) * c) % 56));
        }
    } else if (idx < TW2I) {                // TW1I
        int t = idx - TW1I; int r = t >> 6, c = t & 63;
        if (c < 56) {
            if (r < 56)                  val = cosf(kAng * (float)((r * c) % 56));
            else if (r >= 64 && r < 120) val = sinf(kAng * (float)(((r - 64) * c) % 56));
        }
    } else {                                // TW2I
        int t = idx - TW2I; int x = t >> 6, c = t & 63;
        if (x < 56 && c < 58) {
            int v = c >> 1;
            float wv = ((v == 0) || (v == 28)) ? 1.f : 2.f;
            float a = kAng * (float)((v * x) % 56);
            val = (c & 1) ? (-wv * sinf(a)) : (wv * cosf(a));
        }
    }
    tw[idx] = f2b(val);
}

// ---------------------------------------------------------------------------
// Forward 2D DFT via MFMA. One workgroup per channel image (56x56).
// F1: G[uc][x] = sum_y TW1F[uc][y]*img[y][x]   (M=128,N=64,K=64)
// F2: Y[vc][uc] = sum_x TW2F[vc][x]*G[uc][x]   (M=64,N=112,K=64)
// Qr[u][v] = Y[v][u] - Y[32+v][56+u]; Qi = -Y[32+v][u] - Y[v][56+u]
// ---------------------------------------------------------------------------
__global__ __launch_bounds__(256)
void dft_fwd_mfma(const float* __restrict__ src, long batchStride,
                  float* __restrict__ spec, const unsigned short* __restrict__ tw)
{
    const int ch = blockIdx.x;
    const int b = ch >> 8, c = ch & 255;
    const float* img = src + (long)b * batchStride + (long)c * kN;

    __shared__ __align__(16) char smem[48128];
    unsigned short (*Gb)[72]   = (unsigned short(*)[72])smem;            // 18432
    unsigned short (*imgT)[72] = (unsigned short(*)[72])(smem + 18432);  // 9216
    float (*Yb)[116]           = (float(*)[116])(smem + 18432);          // 29696 (overlays imgT after F1)

    const int tid = threadIdx.x;
    const int wave = tid >> 6, lane = tid & 63;
    const int ln = lane & 15, qd = lane >> 4;

    // stage imgT[x][y] (bf16), zero pads
    for (int i = tid; i < 64 * 72; i += 256) {
        int r = i / 72, cc = i - r * 72;
        if (r >= 56 || cc >= 56) imgT[r][cc] = 0;
    }
    for (int i = tid; i < kN; i += 256) {
        int y = i / 56, x = i - y * 56;
        imgT[x][y] = f2b(img[i]);
    }
    __syncthreads();

    // F1: wave w -> M-tiles 2w, 2w+1
    float4v acc1[2][4];
#pragma unroll
    for (int m = 0; m < 2; ++m)
#pragma unroll
        for (int n = 0; n < 4; ++n) acc1[m][n] = (float4v){0.f, 0.f, 0.f, 0.f};
#pragma unroll
    for (int ks = 0; ks < 2; ++ks) {
        Frag a[2], bf[4];
#pragma unroll
        for (int m = 0; m < 2; ++m)
            a[m].u4 = *(const uint4*)(tw + TW1F + ((2 * wave + m) * 16 + ln) * 64 + ks * 32 + qd * 8);
#pragma unroll
        for (int n = 0; n < 4; ++n)
            bf[n].u4 = *(const uint4*)&imgT[n * 16 + ln][ks * 32 + qd * 8];
#pragma unroll
        for (int m = 0; m < 2; ++m)
#pragma unroll
            for (int n = 0; n < 4; ++n)
                acc1[m][n] = __builtin_amdgcn_mfma_f32_16x16x32_bf16(a[m].s, bf[n].s, acc1[m][n], 0, 0, 0);
    }
#pragma unroll
    for (int m = 0; m < 2; ++m)
#pragma unroll
        for (int n = 0; n < 4; ++n)
#pragma unroll
            for (int r = 0; r < 4; ++r)
                Gb[(2 * wave + m) * 16 + qd * 4 + r][n * 16 + ln] = f2b(acc1[m][n][r]);
    __syncthreads();

    // F2: wave w -> M-tile w; n-tiles 0..6 over uc
    float4v acc2[7];
#pragma unroll
    for (int n = 0; n < 7; ++n) acc2[n] = (float4v){0.f, 0.f, 0.f, 0.f};
#pragma unroll
    for (int ks = 0; ks < 2; ++ks) {
        Frag a;
        a.u4 = *(const uint4*)(tw + TW2F + (wave * 16 + ln) * 64 + ks * 32 + qd * 8);
#pragma unroll
        for (int n = 0; n < 7; ++n) {
            Frag bb;
            bb.u4 = *(const uint4*)&Gb[n * 16 + ln][ks * 32 + qd * 8];
            acc2[n] = __builtin_amdgcn_mfma_f32_16x16x32_bf16(a.s, bb.s, acc2[n], 0, 0, 0);
        }
    }
#pragma unroll
    for (int n = 0; n < 7; ++n)
#pragma unroll
        for (int r = 0; r < 4; ++r)
            Yb[wave * 16 + qd * 4 + r][n * 16 + ln] = acc2[n][r];
    __syncthreads();

    float2* outp = (float2*)spec + (long)ch * kSpec;
    for (int i = tid; i < kSpec; i += 256) {
        int u = i / kNF, v = i - u * kNF;
        float Qr = Yb[v][u] - Yb[32 + v][56 + u];
        float Qi = -Yb[32 + v][u] - Yb[v][56 + u];
        outp[i] = make_float2(Qr, Qi);
    }
}

// ---------------------------------------------------------------------------
// Inverse 2D DFT via MFMA. One workgroup per channel.
// I1: Y[yc][vc] = sum_u TW1I[yc][u]*Pb[vc][u]  (Pb = scale*P, transposed)
// Tr[y][v] = Y[y][2v]-Y[64+y][2v+1]; Ti[y][v] = Y[y][2v+1]+Y[64+y][2v]
// I2: out[y][x] = sum_vc TW2I[x][vc]*T2[y][vc]
// ---------------------------------------------------------------------------
__global__ __launch_bounds__(256)
void dft_inv_mfma(const float* __restrict__ spec, float* __restrict__ dst,
                  float scale, const unsigned short* __restrict__ tw)
{
    const int ch = blockIdx.x;
    __shared__ __align__(16) char smem[41984];
    unsigned short (*Pb)[72] = (unsigned short(*)[72])smem;           // 9216
    float (*Yb)[64]          = (float(*)[64])(smem + 9216);           // 32768
    unsigned short (*T2)[72] = (unsigned short(*)[72])smem;           // overlays Pb after I1

    const int tid = threadIdx.x;
    const int wave = tid >> 6, lane = tid & 63;
    const int ln = lane & 15, qd = lane >> 4;

    const float2* Pin = (const float2*)spec + (long)ch * kSpec;
    for (int i = tid; i < 64 * 72; i += 256) {
        int r = i / 72, cc = i - r * 72;
        if (r >= 58 || cc >= 56) Pb[r][cc] = 0;
    }
    for (int i = tid; i < kSpec; i += 256) {
        int u = i / kNF, v = i - u * kNF;
        float2 p = Pin[i];
        Pb[2 * v][u]     = f2b(p.x * scale);
        Pb[2 * v + 1][u] = f2b(p.y * scale);
    }
    __syncthreads();

    // I1: wave w -> M-tiles 2w,2w+1 (yc)
    float4v acc1[2][4];
#pragma unroll
    for (int m = 0; m < 2; ++m)
#pragma unroll
        for (int n = 0; n < 4; ++n) acc1[m][n] = (float4v){0.f, 0.f, 0.f, 0.f};
#pragma unroll
    for (int ks = 0; ks < 2; ++ks) {
        Frag a[2], bf[4];
#pragma unroll
        for (int m = 0; m < 2; ++m)
            a[m].u4 = *(const uint4*)(tw + TW1I + ((2 * wave + m) * 16 + ln) * 64 + ks * 32 + qd * 8);
#pragma unroll
        for (int n = 0; n < 4; ++n)
            bf[n].u4 = *(const uint4*)&Pb[n * 16 + ln][ks * 32 + qd * 8];
#pragma unroll
        for (int m = 0; m < 2; ++m)
#pragma unroll
            for (int n = 0; n < 4; ++n)
                acc1[m][n] = __builtin_amdgcn_mfma_f32_16x16x32_bf16(a[m].s, bf[n].s, acc1[m][n], 0, 0, 0);
    }
#pragma unroll
    for (int m = 0; m < 2; ++m)
#pragma unroll
        for (int n = 0; n < 4; ++n)
#pragma unroll
            for (int r = 0; r < 4; ++r)
                Yb[(2 * wave + m) * 16 + qd * 4 + r][n * 16 + ln] = acc1[m][n][r];
    __syncthreads();

    // T2 build (overlays Pb — safe after barrier)
    for (int i = tid; i < 64 * 72; i += 256) {
        int r = i / 72, cc = i - r * 72;
        if (r >= 56 || cc >= 58) T2[r][cc] = 0;
    }
    __syncthreads();
    for (int i = tid; i < 56 * kNF; i += 256) {
        int y = i / kNF, v = i - y * kNF;
        float Tr = Yb[y][2 * v]     - Yb[64 + y][2 * v + 1];
        float Ti = Yb[y][2 * v + 1] + Yb[64 + y][2 * v];
        T2[y][2 * v]     = f2b(Tr);
        T2[y][2 * v + 1] = f2b(Ti);
    }
    __syncthreads();

    // I2: wave w -> M-tile w (x); n-tiles over y
    float4v acc2[4];
#pragma unroll
    for (int n = 0; n < 4; ++n) acc2[n] = (float4v){0.f, 0.f, 0.f, 0.f};
#pragma unroll
    for (int ks = 0; ks < 2; ++ks) {
        Frag a;
        a.u4 = *(const uint4*)(tw + TW2I + (wave * 16 + ln) * 64 + ks * 32 + qd * 8);
#pragma unroll
        for (int n = 0; n < 4; ++n) {
            Frag bb;
            bb.u4 = *(const uint4*)&T2[n * 16 + ln][ks * 32 + qd * 8];
            acc2[n] = __builtin_amdgcn_mfma_f32_16x16x32_bf16(a.s, bb.s, acc2[n], 0, 0, 0);
        }
    }
    float* outd = dst + (long)ch * kN;
#pragma unroll
    for (int n = 0; n < 4; ++n) {
        int y = n * 16 + ln;
        if (y < 56) {
#pragma unroll
            for (int r = 0; r < 4; ++r) {
                int x = wave * 16 + qd * 4 + r;
                if (x < 56) outd[y * 56 + x] = acc2[n][r];
            }
        }
    }
}

// ---------------------------------------------------------------------------
// MFMA GEMM: Y[b,o,n] = sum_i W[o,i] * X[b,i,n]  (+bias | bn+relu epilogue)
// ---------------------------------------------------------------------------
__global__ __launch_bounds__(256)
void gemm_kernel(const float* __restrict__ Wm, const float* __restrict__ X,
                 const float* __restrict__ bias, const float* __restrict__ gamma,
                 const float* __restrict__ beta, float* __restrict__ Y,
                 int CI, long xbs, long ybs, int mode)
{
    const int b  = blockIdx.z;
    const int o0 = blockIdx.y * 64;
    const int n0 = blockIdx.x * 128;
    const float* Xb = X + (long)b * xbs;
    float* Yb = Y + (long)b * ybs;

    __shared__ __align__(16) unsigned short Wt[64][40];
    __shared__ __align__(16) unsigned short Xt[128][40];

    const int tid = threadIdx.x;
    const int wave = tid >> 6, lane = tid & 63;
    const int ln = lane & 15, qd = lane >> 4;
    const int wy = wave >> 1, wx = wave & 1;

    const int ow = tid >> 2, kcw = tid & 3;
    const int nx = tid & 127, kcx = tid >> 7;
    const bool xvalid = (n0 + nx) < kN;

    float4v acc[2][4];
#pragma unroll
    for (int i = 0; i < 2; ++i)
#pragma unroll
        for (int j = 0; j < 4; ++j) acc[i][j] = (float4v){0.f, 0.f, 0.f, 0.f};

    float wpre[8], xpre[16];
    {
        const float* ws = Wm + (long)(o0 + ow) * CI + kcw * 8;
        *(float4*)&wpre[0] = *(const float4*)ws;
        *(float4*)&wpre[4] = *(const float4*)(ws + 4);
#pragma unroll
        for (int j = 0; j < 16; ++j)
            xpre[j] = xvalid ? Xb[(long)(kcx * 16 + j) * kN + n0 + nx] : 0.f;
    }

    for (int k0 = 0; k0 < CI; k0 += 32) {
        *(uint4*)&Wt[ow][kcw * 8]      = pk8(wpre);
        *(uint4*)&Xt[nx][kcx * 16]     = pk8(xpre);
        *(uint4*)&Xt[nx][kcx * 16 + 8] = pk8(xpre + 8);
        __syncthreads();

        if (k0 + 32 < CI) {
            const float* ws = Wm + (long)(o0 + ow) * CI + k0 + 32 + kcw * 8;
            *(float4*)&wpre[0] = *(const float4*)ws;
            *(float4*)&wpre[4] = *(const float4*)(ws + 4);
#pragma unroll
            for (int j = 0; j < 16; ++j)
                xpre[j] = xvalid ? Xb[(long)(k0 + 32 + kcx * 16 + j) * kN + n0 + nx] : 0.f;
        }

        Frag af[2], bf4[4];
#pragma unroll
        for (int mt = 0; mt < 2; ++mt)
            af[mt].u4 = *(const uint4*)&Wt[wy * 32 + mt * 16 + ln][qd * 8];
#pragma unroll
        for (int nt = 0; nt < 4; ++nt)
            bf4[nt].u4 = *(const uint4*)&Xt[wx * 64 + nt * 16 + ln][qd * 8];
#pragma unroll
        for (int mt = 0; mt < 2; ++mt)
#pragma unroll
            for (int nt = 0; nt < 4; ++nt)
                acc[mt][nt] = __builtin_amdgcn_mfma_f32_16x16x32_bf16(
                    af[mt].s, bf4[nt].s, acc[mt][nt], 0, 0, 0);
        __syncthreads();
    }

    const float rs = rsqrtf(1.0f + 1e-5f);
#pragma unroll
    for (int mt = 0; mt < 2; ++mt) {
        const int ob = o0 + wy * 32 + mt * 16 + qd * 4;
#pragma unroll
        for (int nt = 0; nt < 4; ++nt) {
            const int n = n0 + wx * 64 + nt * 16 + ln;
            if (n < kN) {
#pragma unroll
                for (int r = 0; r < 4; ++r) {
                    const int o = ob + r;
                    float v = acc[mt][nt][r];
                    if (mode == 0) { if (bias) v += bias[o]; }
                    else v = fmaxf(fmaf(v, gamma[o] * rs, beta[o]), 0.f);
                    Yb[(long)o * kN + n] = v;
                }
            }
        }
    }
}

// ---------------------------------------------------------------------------
// Depthwise 3x3
// ---------------------------------------------------------------------------
__global__ __launch_bounds__(256)
void dwconv_kernel(const float* __restrict__ skv, const float* __restrict__ wgt,
                   const float* __restrict__ bias, float* __restrict__ out)
{
    int e = blockIdx.x * 256 + threadIdx.x;
    if (e >= kB * kC * kN) return;
    int n = e % kN; int bc = e / kN; int c = bc % kC; int b = bc / kC;
    int y = n / kW, x = n - y * kW;
    const float* src = skv + (long)b * (2 * kCN) + (long)(kC + c) * kN;
    float s = bias[c];
#pragma unroll
    for (int ky = 0; ky < 3; ++ky) {
        int yy = y + ky - 1;
        if (yy < 0 || yy >= kH) continue;
#pragma unroll
        for (int kx = 0; kx < 3; ++kx) {
            int xx = x + kx - 1;
            if (xx < 0 || xx >= kW) continue;
            s = fmaf(src[yy * kW + xx], wgt[c * 9 + ky * 3 + kx], s);
        }
    }
    out[(long)b * kCN + (long)c * kN + n] = s;
}

// ---------------------------------------------------------------------------
// Complex multiplies
// ---------------------------------------------------------------------------
__global__ __launch_bounds__(256)
void cmul_spec_kernel(float* __restrict__ fQ, const float* __restrict__ fK)
{
    int e = blockIdx.x * 256 + threadIdx.x;
    if (e >= kB * kC * kSpec) return;
    float2* q = (float2*)fQ; const float2* k = (const float2*)fK;
    float2 a = q[e], b = k[e];
    q[e] = make_float2(a.x * b.x - a.y * b.y, a.x * b.y + a.y * b.x);
}

__global__ __launch_bounds__(256)
void cmul_tok_kernel(float* __restrict__ fV, const float* __restrict__ cw)
{
    int e = blockIdx.x * 256 + threadIdx.x;
    if (e >= kB * kC * kSpec) return;
    int ch = e / kSpec; int j = e - ch * kSpec; int c = ch & 255;
    float2 a = ((float2*)fV)[e];
    float2 w = ((const float2*)cw)[(long)c * kSpec + j];
    ((float2*)fV)[e] = make_float2(a.x * w.x - a.y * w.y, a.x * w.y + a.y * w.x);
}

// ---------------------------------------------------------------------------
// spre / add
// ---------------------------------------------------------------------------
__global__ __launch_bounds__(256)
void spre_kernel(float* __restrict__ vloc, const float* __restrict__ amap,
                 const float* __restrict__ skv)
{
    long e = (long)blockIdx.x * 256 + threadIdx.x;
    if (e >= (long)kB * kCN) return;
    long b = e / kCN, r = e - b * kCN;
    float sv = skv[b * 2 * kCN + kCN + r];
    vloc[e] = fmaf(amap[e], sv, vloc[e]);
}

__global__ __launch_bounds__(256)
void add_kernel(float* __restrict__ a, const float* __restrict__ b)
{
    long e = (long)blockIdx.x * 256 + threadIdx.x;
    if (e >= (long)kB * kCN) return;
    a[e] += b[e];
}

// ---------------------------------------------------------------------------
// Token attention via MFMA bf16 (unchanged from round 2)
// ---------------------------------------------------------------------------
__global__ __launch_bounds__(256)
void attn_mfma_kernel(const float* __restrict__ tq, const float* __restrict__ tkv,
                      float* __restrict__ xo)
{
    const int b = blockIdx.z, h = blockIdx.y;
    const int q0 = blockIdx.x * 128;
    const int tid = threadIdx.x;
    const int wave = tid >> 6, lane = tid & 63;
    const int qd = lane >> 4, ln = lane & 15;

    const float* qb = tq  + (long)b * kCN + (long)h * kHD * kN;
    const float* kb = tkv + (long)b * 2 * kCN + (long)h * kHD * kN;
    const float* vb = kb + kCN;

    __shared__ __align__(16) char smem[19712];
    unsigned short (*Kt)[36] = (unsigned short(*)[36])smem;
    unsigned short (*VT)[68] = (unsigned short(*)[68])(smem + 4608);
    unsigned short* Ps = (unsigned short*)(smem + 8960);
    float* lbuf = (float*)(smem + 19200);
    float (*Os)[133] = (float(*)[133])smem;

    unsigned short* PsW = Ps + wave * (32 * 40);

    Frag qf[2];
#pragma unroll
    for (int qt = 0; qt < 2; ++qt) {
        int qg = q0 + wave * 32 + qt * 16 + ln;
        bool qv = qg < kN;
#pragma unroll
        for (int j = 0; j < 8; ++j) {
            int d = qd * 8 + j;
            float v = qv ? qb[(long)d * kN + qg] * kAttScale : 0.f;
            qf[qt].u[j] = f2b(v);
        }
    }

    float4v o[2][2];
#pragma unroll
    for (int qt = 0; qt < 2; ++qt)
#pragma unroll
        for (int dh = 0; dh < 2; ++dh) o[qt][dh] = (float4v){0.f, 0.f, 0.f, 0.f};
    float lsum[2] = {0.f, 0.f};

    const int nst = tid & 63, dst = tid >> 6;

    float kreg[8], vreg[8];
#pragma unroll
    for (int i = 0; i < 8; ++i) {
        int dd = dst + i * 4;
        kreg[i] = kb[(long)dd * kN + nst];
        vreg[i] = vb[(long)dd * kN + nst];
    }

    for (int k0 = 0; k0 < kN; k0 += 64) {
#pragma unroll
        for (int i = 0; i < 8; ++i) {
            int dd = dst + i * 4;
            Kt[nst][dd] = f2b(kreg[i]);
            VT[dd][nst] = f2b(vreg[i]);
        }
        __syncthreads();

        if (k0 + 64 < kN) {
#pragma unroll
            for (int i = 0; i < 8; ++i) {
                int dd = dst + i * 4;
                kreg[i] = kb[(long)dd * kN + (k0 + 64) + nst];
                vreg[i] = vb[(long)dd * kN + (k0 + 64) + nst];
            }
        }

        Frag ka[4];
#pragma unroll
        for (int m = 0; m < 4; ++m) {
            const unsigned short* p = &Kt[m * 16 + ln][qd * 8];
            ka[m].u2[0] = *(const uint2*)p;
            ka[m].u2[1] = *(const uint2*)(p + 4);
        }
        float4v st[4][2];
#pragma unroll
        for (int m = 0; m < 4; ++m)
#pragma unroll
            for (int qt = 0; qt < 2; ++qt)
                st[m][qt] = __builtin_amdgcn_mfma_f32_16x16x32_bf16(
                    ka[m].s, qf[qt].s, (float4v){0.f, 0.f, 0.f, 0.f}, 0, 0, 0);

#pragma unroll
        for (int m = 0; m < 4; ++m)
#pragma unroll
            for (int qt = 0; qt < 2; ++qt) {
                float e0 = __expf(st[m][qt][0]);
                float e1 = __expf(st[m][qt][1]);
                float e2 = __expf(st[m][qt][2]);
                float e3 = __expf(st[m][qt][3]);
                lsum[qt] += (e0 + e1) + (e2 + e3);
                uint2 w = make_uint2(f2b_pk(e0, e1), f2b_pk(e2, e3));
                *(uint2*)&PsW[(qt * 16 + ln) * 40 + m * 16 + qd * 4] = w;
            }

#pragma unroll
        for (int g = 0; g < 2; ++g) {
            Frag pa[2], va[2];
#pragma unroll
            for (int qt = 0; qt < 2; ++qt)
                pa[qt].u4 = *(const uint4*)&PsW[(qt * 16 + ln) * 40 + g * 32 + qd * 8];
#pragma unroll
            for (int dh = 0; dh < 2; ++dh) {
                const unsigned short* p = &VT[dh * 16 + ln][g * 32 + qd * 8];
                va[dh].u2[0] = *(const uint2*)p;
                va[dh].u2[1] = *(const uint2*)(p + 4);
            }
#pragma unroll
            for (int qt = 0; qt < 2; ++qt)
#pragma unroll
                for (int dh = 0; dh < 2; ++dh)
                    o[qt][dh] = __builtin_amdgcn_mfma_f32_16x16x32_bf16(
                        pa[qt].s, va[dh].s, o[qt][dh], 0, 0, 0);
        }
        __syncthreads();
    }

#pragma unroll
    for (int qt = 0; qt < 2; ++qt) {
        lsum[qt] += __shfl_xor(lsum[qt], 16, 64);
        lsum[qt] += __shfl_xor(lsum[qt], 32, 64);
        if (qd == 0) lbuf[wave * 32 + qt * 16 + ln] = lsum[qt];
    }
    __syncthreads();

#pragma unroll
    for (int qt = 0; qt < 2; ++qt)
#pragma unroll
        for (int dh = 0; dh < 2; ++dh)
#pragma unroll
            for (int r = 0; r < 4; ++r) {
                float l = lbuf[wave * 32 + qt * 16 + qd * 4 + r];
                Os[dh * 16 + ln][wave * 32 + qt * 16 + qd * 4 + r] = o[qt][dh][r] / l;
            }
    __syncthreads();

    for (int i = tid; i < 32 * 128; i += 256) {
        int d = i >> 7, qq = i & 127;
        if (q0 + qq < kN)
            xo[(long)b * kCN + (long)(h * kHD + d) * kN + q0 + qq] = Os[d][qq];
    }
}

// ---------------------------------------------------------------------------
// Gate + blend
// ---------------------------------------------------------------------------
__global__ __launch_bounds__(256)
void gate_kernel(const float* __restrict__ hbuf, const float* __restrict__ w2,
                 const float* __restrict__ b2, float* __restrict__ gate)
{
    const int wave = threadIdx.x >> 6;
    const int lane = threadIdx.x & 63;
    const int p = blockIdx.x * 4 + wave;
    if (p >= kB * kN) return;
    const int b = p / kN, n = p - b * kN;
    const float* hb = hbuf + (long)b * kCN + n;
    float s = 0.f;
#pragma unroll
    for (int c0 = 0; c0 < kC; c0 += 64) {
        int c = c0 + lane;
        s = fmaf(w2[c], hb[(long)c * kN], s);
    }
#pragma unroll
    for (int off = 32; off > 0; off >>= 1) s += __shfl_down(s, off, 64);
    if (lane == 0) gate[p] = 1.f / (1.f + __expf(-(s + b2[0])));
}

__global__ __launch_bounds__(256)
void blend_kernel(const float* __restrict__ gcat, const float* __restrict__ gate,
                  float* __restrict__ out)
{
    long e = (long)blockIdx.x * 256 + threadIdx.x;
    if (e >= (long)kB * kCN) return;
    long b = e / kCN, r = e - b * kCN;
    long n = r % kN;
    float g = gate[b * kN + n];
    float os = gcat[b * 2 * kCN + r];
    float ot = gcat[b * 2 * kCN + kCN + r];
    out[e] = g * os + (1.f - g) * ot;
}

// ---------------------------------------------------------------------------
extern "C" void kernel_launch(void* const* d_in, const int* in_sizes, int n_in,
                              void* d_out, int out_size, void* d_ws, size_t ws_size,
                              hipStream_t stream)
{
    const float* x      = (const float*)d_in[0];
    const float* ctx    = (const float*)d_in[1];
    const float* s_q_w  = (const float*)d_in[2];
    const float* s_kv_w = (const float*)d_in[3];
    const float* s_p_w  = (const float*)d_in[4];
    const float* s_p_b  = (const float*)d_in[5];
    const float* s_dw_w = (const float*)d_in[6];
    const float* s_dw_b = (const float*)d_in[7];
    const float* t_q_w  = (const float*)d_in[8];
    const float* t_kv_w = (const float*)d_in[9];
    const float* t_p_w  = (const float*)d_in[10];
    const float* t_p_b  = (const float*)d_in[11];
    const float* t_cw   = (const float*)d_in[12];
    const float* g_w1   = (const float*)d_in[13];
    const float* g_bn_g = (const float*)d_in[14];
    const float* g_bn_b = (const float*)d_in[15];
    const float* g_w2   = (const float*)d_in[16];
    const float* g_b2   = (const float*)d_in[17];
    float* out = (float*)d_out;

    float* ws = (float*)d_ws;
    const long SPEC2 = (long)kB * kC * kSpec * 2;
    float* sq   = ws;                    // B*C*N   (later: amap, then xattn+tpre)
    float* skv  = sq   + kB * kCN;       // B*2C*N
    float* tq   = skv  + kB * 2 * kCN;   // B*C*N   (later: vres)
    float* tkv  = tq   + kB * kCN;       // B*2C*N  (later: h)
    float* vloc = tkv  + kB * 2 * kCN;   // B*C*N   (later: spre)
    float* fQ   = vloc + kB * kCN;
    float* fK   = fQ   + SPEC2;
    float* fV   = fK   + SPEC2;
    float* gcat = fV   + SPEC2;          // B*2C*N : [os ; ot]
    float* gate = gcat + kB * 2 * kCN;   // B*N
    unsigned short* tw = (unsigned short*)(gate + kB * kN);  // twiddles (49 KB)

    dim3 blk(256, 1, 1);
    const int EW = (int)((long)kB * kCN / 256);
    const int ES = (kB * kC * kSpec + 255) / 256;

    twiddle_init_kernel<<<dim3(TWTOT / 256), blk, 0, stream>>>(tw);

    gemm_kernel<<<dim3(25, 4, kB), blk, 0, stream>>>(s_q_w,  x,   nullptr, nullptr, nullptr, sq,  kC,     kCN, kCN,     0);
    gemm_kernel<<<dim3(25, 8, kB), blk, 0, stream>>>(s_kv_w, ctx, nullptr, nullptr, nullptr, skv, kC,     kCN, 2 * kCN, 0);
    gemm_kernel<<<dim3(25, 4, kB), blk, 0, stream>>>(t_q_w,  x,   nullptr, nullptr, nullptr, tq,  kC,     kCN, kCN,     0);
    gemm_kernel<<<dim3(25, 8, kB), blk, 0, stream>>>(t_kv_w, ctx, nullptr, nullptr, nullptr, tkv, kC,     kCN, 2 * kCN, 0);

    dwconv_kernel<<<dim3(EW), blk, 0, stream>>>(skv, s_dw_w, s_dw_b, vloc);
    dft_fwd_mfma<<<dim3(kB * kC), blk, 0, stream>>>(sq,        kCN,     fQ, tw);
    dft_fwd_mfma<<<dim3(kB * kC), blk, 0, stream>>>(skv,       2 * kCN, fK, tw);
    dft_fwd_mfma<<<dim3(kB * kC), blk, 0, stream>>>(tkv + kCN, 2 * kCN, fV, tw);
    cmul_spec_kernel<<<dim3(ES), blk, 0, stream>>>(fQ, fK);
    dft_inv_mfma<<<dim3(kB * kC), blk, 0, stream>>>(fQ, sq, 1.0f / 175616.0f, tw); // amap
    spre_kernel<<<dim3(EW), blk, 0, stream>>>(vloc, sq, skv);
    gemm_kernel<<<dim3(25, 4, kB), blk, 0, stream>>>(s_p_w, vloc, s_p_b, nullptr, nullptr, gcat, kC, kCN, 2 * kCN, 0); // os

    attn_mfma_kernel<<<dim3(25, kNH, kB), blk, 0, stream>>>(tq, tkv, sq);        // xattn
    cmul_tok_kernel<<<dim3(ES), blk, 0, stream>>>(fV, t_cw);
    dft_inv_mfma<<<dim3(kB * kC), blk, 0, stream>>>(fV, tq, 1.0f / 3136.0f, tw); // vres
    add_kernel<<<dim3(EW), blk, 0, stream>>>(sq, tq);                            // tpre
    gemm_kernel<<<dim3(25, 4, kB), blk, 0, stream>>>(t_p_w, sq, t_p_b, nullptr, nullptr, gcat + kCN, kC, kCN, 2 * kCN, 0); // ot

    gemm_kernel<<<dim3(25, 4, kB), blk, 0, stream>>>(g_w1, gcat, nullptr, g_bn_g, g_bn_b, tkv, 2 * kC, 2 * kCN, kCN, 1); // h
    gate_kernel<<<dim3(kB * kN / 4), blk, 0, stream>>>(tkv, g_w2, g_b2, gate);
    blend_kernel<<<dim3(EW), blk, 0, stream>>>(gcat, gate, out);
}

// Round 5
// 365.200 us; speedup vs baseline: 3.6853x; 1.0713x over previous
//
#include <hip/hip_runtime.h>

namespace {
constexpr int kB = 2;
constexpr int kC = 256;
constexpr int kH = 56;
constexpr int kW = 56;
constexpr int kN = kH * kW;        // 3136
constexpr int kNH = 8;
constexpr int kHD = 32;
constexpr int kNF = kW / 2 + 1;    // 29
constexpr int kSpec = kH * kNF;    // 1624
constexpr long kCN = (long)kC * kN;        // 802816
constexpr float kAttScale = 0.17677669529663687f;   // 32^-0.5
constexpr float kAng = 6.283185307179586f / 56.0f;  // 2*pi/56
// twiddle table offsets in u16 units
constexpr int TW1F = 0;            // [128][64]
constexpr int TW2F = 8192;         // [64][64]
constexpr int TW1I = 12288;        // [128][64]
constexpr int TW2I = 20480;        // [64][64]
constexpr int TWTOT = 24576;
}

typedef __attribute__((ext_vector_type(8))) short short8;
typedef __attribute__((ext_vector_type(4))) float float4v;

union Frag {
    short8 s;
    unsigned short u[8];
    uint2 u2[2];
    uint4 u4;
};

__device__ __forceinline__ unsigned short f2b(float f) {
    unsigned u = __float_as_uint(f);
    return (unsigned short)((u + 0x7FFFu + ((u >> 16) & 1u)) >> 16);
}
__device__ __forceinline__ unsigned f2b_pk(float a, float b) {
    unsigned ua = __float_as_uint(a); ua = (ua + 0x7FFFu + ((ua >> 16) & 1u)) >> 16;
    unsigned ub = __float_as_uint(b); ub = (ub + 0x7FFFu + ((ub >> 16) & 1u)) >> 16;
    return ua | (ub << 16);
}
__device__ __forceinline__ uint4 pk8(const float* v) {
    return make_uint4(f2b_pk(v[0], v[1]), f2b_pk(v[2], v[3]),
                      f2b_pk(v[4], v[5]), f2b_pk(v[6], v[7]));
}

// ---------------------------------------------------------------------------
// Twiddle tables (bf16), built fresh every launch into d_ws.
// ---------------------------------------------------------------------------
__global__ __launch_bounds__(256)
void twiddle_init_kernel(unsigned short* __restrict__ tw)
{
    int idx = blockIdx.x * 256 + threadIdx.x;
    if (idx >= TWTOT) return;
    float val = 0.f;
    if (idx < TW2F) {                       // TW1F
        int r = idx >> 6, c = idx & 63;
        if (c < 56) {
            if (r < 56)       val = cosf(kAng * (float)((r * c) % 56));
            else if (r < 112) val = sinf(kAng * (float)(((r - 56) * c) % 56));
        }
    } else if (idx < TW1I) {                // TW2F
        int t = idx - TW2F; int r = t >> 6, c = t & 63;
        if (c < 56) {
            if (r < 29)                  val = cosf(kAng * (float)((r * c) % 56));
            else if (r >= 32 && r < 61)  val = sinf(kAng * (float)(((r - 32) * c) % 56));
        }
    } else if (idx < TW2I) {                // TW1I
        int t = idx - TW1I; int r = t >> 6, c = t & 63;
        if (c < 56) {
            if (r < 56)                  val = cosf(kAng * (float)((r * c) % 56));
            else if (r >= 64 && r < 120) val = sinf(kAng * (float)(((r - 64) * c) % 56));
        }
    } else {                                // TW2I
        int t = idx - TW2I; int x = t >> 6, c = t & 63;
        if (x < 56 && c < 58) {
            int v = c >> 1;
            float wv = ((v == 0) || (v == 28)) ? 1.f : 2.f;
            float a = kAng * (float)((v * x) % 56);
            val = (c & 1) ? (-wv * sinf(a)) : (wv * cosf(a));
        }
    }
    tw[idx] = f2b(val);
}

// ---------------------------------------------------------------------------
// Forward 2D DFT via MFMA (unchanged from round 4)
// ---------------------------------------------------------------------------
__global__ __launch_bounds__(256)
void dft_fwd_mfma(const float* __restrict__ src, long batchStride,
                  float* __restrict__ spec, const unsigned short* __restrict__ tw)
{
    const int ch = blockIdx.x;
    const int b = ch >> 8, c = ch & 255;
    const float* img = src + (long)b * batchStride + (long)c * kN;

    __shared__ __align__(16) char smem[48128];
    unsigned short (*Gb)[72]   = (unsigned short(*)[72])smem;            // 18432
    unsigned short (*imgT)[72] = (unsigned short(*)[72])(smem + 18432);  // 9216
    float (*Yb)[116]           = (float(*)[116])(smem + 18432);          // overlays imgT after F1

    const int tid = threadIdx.x;
    const int wave = tid >> 6, lane = tid & 63;
    const int ln = lane & 15, qd = lane >> 4;

    for (int i = tid; i < 64 * 72; i += 256) {
        int r = i / 72, cc = i - r * 72;
        if (r >= 56 || cc >= 56) imgT[r][cc] = 0;
    }
    for (int i = tid; i < kN; i += 256) {
        int y = i / 56, x = i - y * 56;
        imgT[x][y] = f2b(img[i]);
    }
    __syncthreads();

    float4v acc1[2][4];
#pragma unroll
    for (int m = 0; m < 2; ++m)
#pragma unroll
        for (int n = 0; n < 4; ++n) acc1[m][n] = (float4v){0.f, 0.f, 0.f, 0.f};
#pragma unroll
    for (int ks = 0; ks < 2; ++ks) {
        Frag a[2], bf[4];
#pragma unroll
        for (int m = 0; m < 2; ++m)
            a[m].u4 = *(const uint4*)(tw + TW1F + ((2 * wave + m) * 16 + ln) * 64 + ks * 32 + qd * 8);
#pragma unroll
        for (int n = 0; n < 4; ++n)
            bf[n].u4 = *(const uint4*)&imgT[n * 16 + ln][ks * 32 + qd * 8];
#pragma unroll
        for (int m = 0; m < 2; ++m)
#pragma unroll
            for (int n = 0; n < 4; ++n)
                acc1[m][n] = __builtin_amdgcn_mfma_f32_16x16x32_bf16(a[m].s, bf[n].s, acc1[m][n], 0, 0, 0);
    }
#pragma unroll
    for (int m = 0; m < 2; ++m)
#pragma unroll
        for (int n = 0; n < 4; ++n)
#pragma unroll
            for (int r = 0; r < 4; ++r)
                Gb[(2 * wave + m) * 16 + qd * 4 + r][n * 16 + ln] = f2b(acc1[m][n][r]);
    __syncthreads();

    float4v acc2[7];
#pragma unroll
    for (int n = 0; n < 7; ++n) acc2[n] = (float4v){0.f, 0.f, 0.f, 0.f};
#pragma unroll
    for (int ks = 0; ks < 2; ++ks) {
        Frag a;
        a.u4 = *(const uint4*)(tw + TW2F + (wave * 16 + ln) * 64 + ks * 32 + qd * 8);
#pragma unroll
        for (int n = 0; n < 7; ++n) {
            Frag bb;
            bb.u4 = *(const uint4*)&Gb[n * 16 + ln][ks * 32 + qd * 8];
            acc2[n] = __builtin_amdgcn_mfma_f32_16x16x32_bf16(a.s, bb.s, acc2[n], 0, 0, 0);
        }
    }
#pragma unroll
    for (int n = 0; n < 7; ++n)
#pragma unroll
        for (int r = 0; r < 4; ++r)
            Yb[wave * 16 + qd * 4 + r][n * 16 + ln] = acc2[n][r];
    __syncthreads();

    float2* outp = (float2*)spec + (long)ch * kSpec;
    for (int i = tid; i < kSpec; i += 256) {
        int u = i / kNF, v = i - u * kNF;
        float Qr = Yb[v][u] - Yb[32 + v][56 + u];
        float Qi = -Yb[32 + v][u] - Yb[v][56 + u];
        outp[i] = make_float2(Qr, Qi);
    }
}

// ---------------------------------------------------------------------------
// Inverse 2D DFT via MFMA, with fused input complex-multiply and epilogue.
// mode 1 (spectral): P = spec*mul2, epilogue dst += acc * sv  (sv = skv V row)
// mode 2 (token):    P = spec*cw[c], epilogue dst += acc
// ---------------------------------------------------------------------------
__global__ __launch_bounds__(256)
void dft_inv_mfma(const float* __restrict__ spec, const float* __restrict__ mul2,
                  const float* __restrict__ cw, float* __restrict__ dst,
                  const float* __restrict__ skvp, int mode, float scale,
                  const unsigned short* __restrict__ tw)
{
    const int ch = blockIdx.x;
    const int b = ch >> 8, c = ch & 255;
    __shared__ __align__(16) char smem[41984];
    unsigned short (*Pb)[72] = (unsigned short(*)[72])smem;           // 9216
    float (*Yb)[64]          = (float(*)[64])(smem + 9216);           // 32768
    unsigned short (*T2)[72] = (unsigned short(*)[72])smem;           // overlays Pb after I1

    const int tid = threadIdx.x;
    const int wave = tid >> 6, lane = tid & 63;
    const int ln = lane & 15, qd = lane >> 4;

    const float2* Pin = (const float2*)spec + (long)ch * kSpec;
    const float2* Min = (mode == 1) ? ((const float2*)mul2 + (long)ch * kSpec)
                                    : ((const float2*)cw + (long)c * kSpec);
    for (int i = tid; i < 64 * 72; i += 256) {
        int r = i / 72, cc = i - r * 72;
        if (r >= 58 || cc >= 56) Pb[r][cc] = 0;
    }
    for (int i = tid; i < kSpec; i += 256) {
        int u = i / kNF, v = i - u * kNF;
        float2 p = Pin[i];
        float2 m = Min[i];
        float pr = (p.x * m.x - p.y * m.y) * scale;
        float pi = (p.x * m.y + p.y * m.x) * scale;
        Pb[2 * v][u]     = f2b(pr);
        Pb[2 * v + 1][u] = f2b(pi);
    }
    __syncthreads();

    float4v acc1[2][4];
#pragma unroll
    for (int m = 0; m < 2; ++m)
#pragma unroll
        for (int n = 0; n < 4; ++n) acc1[m][n] = (float4v){0.f, 0.f, 0.f, 0.f};
#pragma unroll
    for (int ks = 0; ks < 2; ++ks) {
        Frag a[2], bf[4];
#pragma unroll
        for (int m = 0; m < 2; ++m)
            a[m].u4 = *(const uint4*)(tw + TW1I + ((2 * wave + m) * 16 + ln) * 64 + ks * 32 + qd * 8);
#pragma unroll
        for (int n = 0; n < 4; ++n)
            bf[n].u4 = *(const uint4*)&Pb[n * 16 + ln][ks * 32 + qd * 8];
#pragma unroll
        for (int m = 0; m < 2; ++m)
#pragma unroll
            for (int n = 0; n < 4; ++n)
                acc1[m][n] = __builtin_amdgcn_mfma_f32_16x16x32_bf16(a[m].s, bf[n].s, acc1[m][n], 0, 0, 0);
    }
#pragma unroll
    for (int m = 0; m < 2; ++m)
#pragma unroll
        for (int n = 0; n < 4; ++n)
#pragma unroll
            for (int r = 0; r < 4; ++r)
                Yb[(2 * wave + m) * 16 + qd * 4 + r][n * 16 + ln] = acc1[m][n][r];
    __syncthreads();

    for (int i = tid; i < 64 * 72; i += 256) {
        int r = i / 72, cc = i - r * 72;
        if (r >= 56 || cc >= 58) T2[r][cc] = 0;
    }
    __syncthreads();
    for (int i = tid; i < 56 * kNF; i += 256) {
        int y = i / kNF, v = i - y * kNF;
        float Tr = Yb[y][2 * v]     - Yb[64 + y][2 * v + 1];
        float Ti = Yb[y][2 * v + 1] + Yb[64 + y][2 * v];
        T2[y][2 * v]     = f2b(Tr);
        T2[y][2 * v + 1] = f2b(Ti);
    }
    __syncthreads();

    float4v acc2[4];
#pragma unroll
    for (int n = 0; n < 4; ++n) acc2[n] = (float4v){0.f, 0.f, 0.f, 0.f};
#pragma unroll
    for (int ks = 0; ks < 2; ++ks) {
        Frag a;
        a.u4 = *(const uint4*)(tw + TW2I + (wave * 16 + ln) * 64 + ks * 32 + qd * 8);
#pragma unroll
        for (int n = 0; n < 4; ++n) {
            Frag bb;
            bb.u4 = *(const uint4*)&T2[n * 16 + ln][ks * 32 + qd * 8];
            acc2[n] = __builtin_amdgcn_mfma_f32_16x16x32_bf16(a.s, bb.s, acc2[n], 0, 0, 0);
        }
    }
    float* outd = dst + (long)ch * kN;
    const float* svp = (mode == 1)
        ? (skvp + (long)b * 2 * kCN + kCN + (long)c * kN) : nullptr;
#pragma unroll
    for (int n = 0; n < 4; ++n) {
        int y = n * 16 + ln;
        if (y < 56) {
#pragma unroll
            for (int r = 0; r < 4; ++r) {
                int x = wave * 16 + qd * 4 + r;
                if (x < 56) {
                    int e = y * 56 + x;
                    if (mode == 1) outd[e] = fmaf(acc2[n][r], svp[e], outd[e]);
                    else           outd[e] += acc2[n][r];
                }
            }
        }
    }
}

// ---------------------------------------------------------------------------
// MFMA GEMM (unchanged from round 4)
// ---------------------------------------------------------------------------
__global__ __launch_bounds__(256)
void gemm_kernel(const float* __restrict__ Wm, const float* __restrict__ X,
                 const float* __restrict__ bias, const float* __restrict__ gamma,
                 const float* __restrict__ beta, float* __restrict__ Y,
                 int CI, long xbs, long ybs, int mode)
{
    const int b  = blockIdx.z;
    const int o0 = blockIdx.y * 64;
    const int n0 = blockIdx.x * 128;
    const float* Xb = X + (long)b * xbs;
    float* Yb = Y + (long)b * ybs;

    __shared__ __align__(16) unsigned short Wt[64][40];
    __shared__ __align__(16) unsigned short Xt[128][40];

    const int tid = threadIdx.x;
    const int wave = tid >> 6, lane = tid & 63;
    const int ln = lane & 15, qd = lane >> 4;
    const int wy = wave >> 1, wx = wave & 1;

    const int ow = tid >> 2, kcw = tid & 3;
    const int nx = tid & 127, kcx = tid >> 7;
    const bool xvalid = (n0 + nx) < kN;

    float4v acc[2][4];
#pragma unroll
    for (int i = 0; i < 2; ++i)
#pragma unroll
        for (int j = 0; j < 4; ++j) acc[i][j] = (float4v){0.f, 0.f, 0.f, 0.f};

    float wpre[8], xpre[16];
    {
        const float* ws = Wm + (long)(o0 + ow) * CI + kcw * 8;
        *(float4*)&wpre[0] = *(const float4*)ws;
        *(float4*)&wpre[4] = *(const float4*)(ws + 4);
#pragma unroll
        for (int j = 0; j < 16; ++j)
            xpre[j] = xvalid ? Xb[(long)(kcx * 16 + j) * kN + n0 + nx] : 0.f;
    }

    for (int k0 = 0; k0 < CI; k0 += 32) {
        *(uint4*)&Wt[ow][kcw * 8]      = pk8(wpre);
        *(uint4*)&Xt[nx][kcx * 16]     = pk8(xpre);
        *(uint4*)&Xt[nx][kcx * 16 + 8] = pk8(xpre + 8);
        __syncthreads();

        if (k0 + 32 < CI) {
            const float* ws = Wm + (long)(o0 + ow) * CI + k0 + 32 + kcw * 8;
            *(float4*)&wpre[0] = *(const float4*)ws;
            *(float4*)&wpre[4] = *(const float4*)(ws + 4);
#pragma unroll
            for (int j = 0; j < 16; ++j)
                xpre[j] = xvalid ? Xb[(long)(k0 + 32 + kcx * 16 + j) * kN + n0 + nx] : 0.f;
        }

        Frag af[2], bf4[4];
#pragma unroll
        for (int mt = 0; mt < 2; ++mt)
            af[mt].u4 = *(const uint4*)&Wt[wy * 32 + mt * 16 + ln][qd * 8];
#pragma unroll
        for (int nt = 0; nt < 4; ++nt)
            bf4[nt].u4 = *(const uint4*)&Xt[wx * 64 + nt * 16 + ln][qd * 8];
#pragma unroll
        for (int mt = 0; mt < 2; ++mt)
#pragma unroll
            for (int nt = 0; nt < 4; ++nt)
                acc[mt][nt] = __builtin_amdgcn_mfma_f32_16x16x32_bf16(
                    af[mt].s, bf4[nt].s, acc[mt][nt], 0, 0, 0);
        __syncthreads();
    }

    const float rs = rsqrtf(1.0f + 1e-5f);
#pragma unroll
    for (int mt = 0; mt < 2; ++mt) {
        const int ob = o0 + wy * 32 + mt * 16 + qd * 4;
#pragma unroll
        for (int nt = 0; nt < 4; ++nt) {
            const int n = n0 + wx * 64 + nt * 16 + ln;
            if (n < kN) {
#pragma unroll
                for (int r = 0; r < 4; ++r) {
                    const int o = ob + r;
                    float v = acc[mt][nt][r];
                    if (mode == 0) { if (bias) v += bias[o]; }
                    else v = fmaxf(fmaf(v, gamma[o] * rs, beta[o]), 0.f);
                    Yb[(long)o * kN + n] = v;
                }
            }
        }
    }
}

// ---------------------------------------------------------------------------
// Depthwise 3x3
// ---------------------------------------------------------------------------
__global__ __launch_bounds__(256)
void dwconv_kernel(const float* __restrict__ skv, const float* __restrict__ wgt,
                   const float* __restrict__ bias, float* __restrict__ out)
{
    int e = blockIdx.x * 256 + threadIdx.x;
    if (e >= kB * kC * kN) return;
    int n = e % kN; int bc = e / kN; int c = bc % kC; int b = bc / kC;
    int y = n / kW, x = n - y * kW;
    const float* src = skv + (long)b * (2 * kCN) + (long)(kC + c) * kN;
    float s = bias[c];
#pragma unroll
    for (int ky = 0; ky < 3; ++ky) {
        int yy = y + ky - 1;
        if (yy < 0 || yy >= kH) continue;
#pragma unroll
        for (int kx = 0; kx < 3; ++kx) {
            int xx = x + kx - 1;
            if (xx < 0 || xx >= kW) continue;
            s = fmaf(src[yy * kW + xx], wgt[c * 9 + ky * 3 + kx], s);
        }
    }
    out[(long)b * kCN + (long)c * kN + n] = s;
}

// ---------------------------------------------------------------------------
// Attention K/V prepack: fp32 [d][n] -> bf16 MFMA-fragment order.
// Kp: per (b,h), 196 tiles of 16 keys: [ln(key%16)][qd][8d]      (512 u16/tile)
// Vp: per (b,h), 49 tiles of 64 keys: [g][dh][ln(d%16)][qd][8keys] (2048 u16/tile)
// One block per (b,h,64-key chunk i). kN = 49*64 exactly.
// ---------------------------------------------------------------------------
__global__ __launch_bounds__(256)
void attn_prepack_kernel(const float* __restrict__ tkv,
                         unsigned short* __restrict__ Kp,
                         unsigned short* __restrict__ Vp)
{
    const int blk = blockIdx.x;
    const int i = blk % 49;
    const int h = (blk / 49) & 7;
    const int b = blk / (49 * 8);
    const float* kb = tkv + (long)b * 2 * kCN + (long)h * kHD * kN;
    const float* vb = kb + kCN;
    const int tid = threadIdx.x;

    __shared__ float Ks[32][72];
#pragma unroll
    for (int j = 0; j < 8; ++j) {
        int e = tid + j * 256;
        int d = e >> 6, c = e & 63;
        Ks[d][c] = kb[(long)d * kN + i * 64 + c];
    }
    __syncthreads();
    {
        int tl = tid >> 6, lnn = (tid >> 2) & 15, qdd = tid & 3;
        float v[8];
#pragma unroll
        for (int j = 0; j < 8; ++j) v[j] = Ks[qdd * 8 + j][tl * 16 + lnn];
        unsigned short* dst = Kp + ((long)(b * 8 + h) * 196 + 4 * i + tl) * 512 + lnn * 32 + qdd * 8;
        *(uint4*)dst = pk8(v);
    }
    {
        int g = tid >> 7, dh = (tid >> 6) & 1, lnn = (tid >> 2) & 15, qdd = tid & 3;
        int d = dh * 16 + lnn;
        const float* src = vb + (long)d * kN + i * 64 + g * 32 + qdd * 8;
        float v[8];
        *(float4*)&v[0] = *(const float4*)src;
        *(float4*)&v[4] = *(const float4*)(src + 4);
        unsigned short* dst = Vp + ((long)(b * 8 + h) * 49 + i) * 2048 + ((g * 2 + dh) * 16 + lnn) * 32 + qdd * 8;
        *(uint4*)dst = pk8(v);
    }
}

// ---------------------------------------------------------------------------
// Token attention: barrier-free K-loop, fragments direct from global (L2-hot).
// Block = 4 waves x 32 queries. Only LDS in loop: per-wave P round-trip.
// ---------------------------------------------------------------------------
__global__ __launch_bounds__(256)
void attn_mfma_kernel(const float* __restrict__ tq,
                      const unsigned short* __restrict__ Kp,
                      const unsigned short* __restrict__ Vp,
                      float* __restrict__ xo)
{
    const int b = blockIdx.z, h = blockIdx.y;
    const int q0 = blockIdx.x * 128;
    const int tid = threadIdx.x;
    const int wave = tid >> 6, lane = tid & 63;
    const int qd = lane >> 4, ln = lane & 15;

    const float* qb = tq + (long)b * kCN + (long)h * kHD * kN;
    const unsigned short* KpB = Kp + (long)(b * 8 + h) * 196 * 512 + ln * 32 + qd * 8;
    const unsigned short* VpB = Vp + (long)(b * 8 + h) * 49 * 2048 + ln * 32 + qd * 8;

    __shared__ __align__(16) char smem[17536];
    unsigned short* PsW = (unsigned short*)smem + wave * (32 * 40);  // per-wave P
    float* lbuf = (float*)(smem + 17024);                            // 4*32 floats
    float (*Os)[133] = (float(*)[133])smem;                          // epilogue overlay

    // Q fragments (B-operand): B[k=d=qd*8+j][n=q=ln]; scale folded in.
    Frag qf[2];
#pragma unroll
    for (int qt = 0; qt < 2; ++qt) {
        int qg = q0 + wave * 32 + qt * 16 + ln;
        bool qv = qg < kN;
#pragma unroll
        for (int j = 0; j < 8; ++j) {
            int d = qd * 8 + j;
            float v = qv ? qb[(long)d * kN + qg] * kAttScale : 0.f;
            qf[qt].u[j] = f2b(v);
        }
    }

    float4v o[2][2];
#pragma unroll
    for (int qt = 0; qt < 2; ++qt)
#pragma unroll
        for (int dh = 0; dh < 2; ++dh) o[qt][dh] = (float4v){0.f, 0.f, 0.f, 0.f};
    float lsum[2] = {0.f, 0.f};

    Frag ka[4];
#pragma unroll
    for (int m = 0; m < 4; ++m)
        ka[m].u4 = *(const uint4*)(KpB + (long)m * 512);

    for (int i = 0; i < 49; ++i) {
        // V fragments for this 64-key tile
        Frag va[2][2];
#pragma unroll
        for (int g = 0; g < 2; ++g)
#pragma unroll
            for (int dh = 0; dh < 2; ++dh)
                va[g][dh].u4 = *(const uint4*)(VpB + (long)i * 2048 + (g * 2 + dh) * 512);

        // S^T = K * Q^T
        float4v st[4][2];
#pragma unroll
        for (int m = 0; m < 4; ++m)
#pragma unroll
            for (int qt = 0; qt < 2; ++qt)
                st[m][qt] = __builtin_amdgcn_mfma_f32_16x16x32_bf16(
                    ka[m].s, qf[qt].s, (float4v){0.f, 0.f, 0.f, 0.f}, 0, 0, 0);

        // prefetch next K tile
        if (i < 48) {
#pragma unroll
            for (int m = 0; m < 4; ++m)
                ka[m].u4 = *(const uint4*)(KpB + (long)(4 * (i + 1) + m) * 512);
        }

        // exp, denominator, pack P -> per-wave LDS [q][key]
#pragma unroll
        for (int m = 0; m < 4; ++m)
#pragma unroll
            for (int qt = 0; qt < 2; ++qt) {
                float e0 = __expf(st[m][qt][0]);
                float e1 = __expf(st[m][qt][1]);
                float e2 = __expf(st[m][qt][2]);
                float e3 = __expf(st[m][qt][3]);
                lsum[qt] += (e0 + e1) + (e2 + e3);
                uint2 w = make_uint2(f2b_pk(e0, e1), f2b_pk(e2, e3));
                *(uint2*)&PsW[(qt * 16 + ln) * 40 + m * 16 + qd * 4] = w;
            }

        // O += P * V
#pragma unroll
        for (int g = 0; g < 2; ++g) {
            Frag pa[2];
#pragma unroll
            for (int qt = 0; qt < 2; ++qt)
                pa[qt].u4 = *(const uint4*)&PsW[(qt * 16 + ln) * 40 + g * 32 + qd * 8];
#pragma unroll
            for (int qt = 0; qt < 2; ++qt)
#pragma unroll
                for (int dh = 0; dh < 2; ++dh)
                    o[qt][dh] = __builtin_amdgcn_mfma_f32_16x16x32_bf16(
                        pa[qt].s, va[g][dh].s, o[qt][dh], 0, 0, 0);
        }
    }

    // denominators: reduce over quads
#pragma unroll
    for (int qt = 0; qt < 2; ++qt) {
        lsum[qt] += __shfl_xor(lsum[qt], 16, 64);
        lsum[qt] += __shfl_xor(lsum[qt], 32, 64);
        if (qd == 0) lbuf[wave * 32 + qt * 16 + ln] = lsum[qt];
    }
    __syncthreads();

    // normalize + transpose through LDS (P regions dead after barrier)
#pragma unroll
    for (int qt = 0; qt < 2; ++qt)
#pragma unroll
        for (int dh = 0; dh < 2; ++dh)
#pragma unroll
            for (int r = 0; r < 4; ++r) {
                float l = lbuf[wave * 32 + qt * 16 + qd * 4 + r];
                Os[dh * 16 + ln][wave * 32 + qt * 16 + qd * 4 + r] = o[qt][dh][r] / l;
            }
    __syncthreads();

    for (int i = tid; i < 32 * 128; i += 256) {
        int d = i >> 7, qq = i & 127;
        if (q0 + qq < kN)
            xo[(long)b * kCN + (long)(h * kHD + d) * kN + q0 + qq] = Os[d][qq];
    }
}

// ---------------------------------------------------------------------------
// Gate + blend
// ---------------------------------------------------------------------------
__global__ __launch_bounds__(256)
void gate_kernel(const float* __restrict__ hbuf, const float* __restrict__ w2,
                 const float* __restrict__ b2, float* __restrict__ gate)
{
    const int wave = threadIdx.x >> 6;
    const int lane = threadIdx.x & 63;
    const int p = blockIdx.x * 4 + wave;
    if (p >= kB * kN) return;
    const int b = p / kN, n = p - b * kN;
    const float* hb = hbuf + (long)b * kCN + n;
    float s = 0.f;
#pragma unroll
    for (int c0 = 0; c0 < kC; c0 += 64) {
        int c = c0 + lane;
        s = fmaf(w2[c], hb[(long)c * kN], s);
    }
#pragma unroll
    for (int off = 32; off > 0; off >>= 1) s += __shfl_down(s, off, 64);
    if (lane == 0) gate[p] = 1.f / (1.f + __expf(-(s + b2[0])));
}

__global__ __launch_bounds__(256)
void blend_kernel(const float* __restrict__ gcat, const float* __restrict__ gate,
                  float* __restrict__ out)
{
    long e = (long)blockIdx.x * 256 + threadIdx.x;
    if (e >= (long)kB * kCN) return;
    long b = e / kCN, r = e - b * kCN;
    long n = r % kN;
    float g = gate[b * kN + n];
    float os = gcat[b * 2 * kCN + r];
    float ot = gcat[b * 2 * kCN + kCN + r];
    out[e] = g * os + (1.f - g) * ot;
}

// ---------------------------------------------------------------------------
extern "C" void kernel_launch(void* const* d_in, const int* in_sizes, int n_in,
                              void* d_out, int out_size, void* d_ws, size_t ws_size,
                              hipStream_t stream)
{
    const float* x      = (const float*)d_in[0];
    const float* ctx    = (const float*)d_in[1];
    const float* s_q_w  = (const float*)d_in[2];
    const float* s_kv_w = (const float*)d_in[3];
    const float* s_p_w  = (const float*)d_in[4];
    const float* s_p_b  = (const float*)d_in[5];
    const float* s_dw_w = (const float*)d_in[6];
    const float* s_dw_b = (const float*)d_in[7];
    const float* t_q_w  = (const float*)d_in[8];
    const float* t_kv_w = (const float*)d_in[9];
    const float* t_p_w  = (const float*)d_in[10];
    const float* t_p_b  = (const float*)d_in[11];
    const float* t_cw   = (const float*)d_in[12];
    const float* g_w1   = (const float*)d_in[13];
    const float* g_bn_g = (const float*)d_in[14];
    const float* g_bn_b = (const float*)d_in[15];
    const float* g_w2   = (const float*)d_in[16];
    const float* g_b2   = (const float*)d_in[17];
    float* out = (float*)d_out;

    float* ws = (float*)d_ws;
    const long SPEC2 = (long)kB * kC * kSpec * 2;
    float* sq   = ws;                    // B*C*N   (xattn + vres accum)
    float* skv  = sq   + kB * kCN;       // B*2C*N
    float* tq   = skv  + kB * 2 * kCN;   // B*C*N
    float* tkv  = tq   + kB * kCN;       // B*2C*N  (later: h)
    float* vloc = tkv  + kB * 2 * kCN;   // B*C*N   (spre accum)
    float* fQ   = vloc + kB * kCN;
    float* fK   = fQ   + SPEC2;
    float* fV   = fK   + SPEC2;
    float* gcat = fV   + SPEC2;          // B*2C*N : [os ; ot]
    float* gate = gcat + kB * 2 * kCN;   // B*N
    unsigned short* tw = (unsigned short*)(gate + kB * kN);  // twiddles
    unsigned short* Kp = tw + TWTOT;                         // 16*196*512 u16
    unsigned short* Vp = Kp + (long)16 * 196 * 512;          // 16*49*2048 u16

    dim3 blk(256, 1, 1);
    const int EW = (int)((long)kB * kCN / 256);

    twiddle_init_kernel<<<dim3(TWTOT / 256), blk, 0, stream>>>(tw);

    gemm_kernel<<<dim3(25, 4, kB), blk, 0, stream>>>(s_q_w,  x,   nullptr, nullptr, nullptr, sq,  kC,     kCN, kCN,     0);
    gemm_kernel<<<dim3(25, 8, kB), blk, 0, stream>>>(s_kv_w, ctx, nullptr, nullptr, nullptr, skv, kC,     kCN, 2 * kCN, 0);
    gemm_kernel<<<dim3(25, 4, kB), blk, 0, stream>>>(t_q_w,  x,   nullptr, nullptr, nullptr, tq,  kC,     kCN, kCN,     0);
    gemm_kernel<<<dim3(25, 8, kB), blk, 0, stream>>>(t_kv_w, ctx, nullptr, nullptr, nullptr, tkv, kC,     kCN, 2 * kCN, 0);

    dwconv_kernel<<<dim3(EW), blk, 0, stream>>>(skv, s_dw_w, s_dw_b, vloc);
    dft_fwd_mfma<<<dim3(kB * kC), blk, 0, stream>>>(sq,        kCN,     fQ, tw);
    dft_fwd_mfma<<<dim3(kB * kC), blk, 0, stream>>>(skv,       2 * kCN, fK, tw);
    dft_fwd_mfma<<<dim3(kB * kC), blk, 0, stream>>>(tkv + kCN, 2 * kCN, fV, tw);
    // amap*sv + vloc -> vloc  (cmul + irfft + spre fused)
    dft_inv_mfma<<<dim3(kB * kC), blk, 0, stream>>>(fQ, fK, nullptr, vloc, skv, 1, 1.0f / 175616.0f, tw);
    gemm_kernel<<<dim3(25, 4, kB), blk, 0, stream>>>(s_p_w, vloc, s_p_b, nullptr, nullptr, gcat, kC, kCN, 2 * kCN, 0); // os

    attn_prepack_kernel<<<dim3(kB * kNH * 49), blk, 0, stream>>>(tkv, Kp, Vp);
    attn_mfma_kernel<<<dim3(25, kNH, kB), blk, 0, stream>>>(tq, Kp, Vp, sq);     // xattn -> sq
    // vres = irfft(fV*cw); sq += vres  (cmul + irfft + add fused)
    dft_inv_mfma<<<dim3(kB * kC), blk, 0, stream>>>(fV, nullptr, t_cw, sq, nullptr, 2, 1.0f / 3136.0f, tw);
    gemm_kernel<<<dim3(25, 4, kB), blk, 0, stream>>>(t_p_w, sq, t_p_b, nullptr, nullptr, gcat + kCN, kC, kCN, 2 * kCN, 0); // ot

    gemm_kernel<<<dim3(25, 4, kB), blk, 0, stream>>>(g_w1, gcat, nullptr, g_bn_g, g_bn_b, tkv, 2 * kC, 2 * kCN, kCN, 1); // h
    gate_kernel<<<dim3(kB * kN / 4), blk, 0, stream>>>(tkv, g_w2, g_b2, gate);
    blend_kernel<<<dim3(EW), blk, 0, stream>>>(gcat, gate, out);
}

// Round 7
// 336.189 us; speedup vs baseline: 4.0033x; 1.0863x over previous
//
#include <hip/hip_runtime.h>

namespace {
constexpr int kB = 2;
constexpr int kC = 256;
constexpr int kH = 56;
constexpr int kW = 56;
constexpr int kN = kH * kW;        // 3136
constexpr int kNH = 8;
constexpr int kHD = 32;
constexpr int kNF = kW / 2 + 1;    // 29
constexpr int kSpec = kH * kNF;    // 1624
constexpr long kCN = (long)kC * kN;        // 802816
constexpr float kAttScale = 0.17677669529663687f;   // 32^-0.5
constexpr float kLog2e = 1.4426950408889634f;
constexpr float kAng = 6.283185307179586f / 56.0f;  // 2*pi/56
// twiddle table offsets in u16 units
constexpr int TW1F = 0;            // [128][64]
constexpr int TW2F = 8192;         // [64][64]
constexpr int TW1I = 12288;        // [128][64]
constexpr int TW2I = 20480;        // [64][64]
constexpr int TWTOT = 24576;
}

typedef __attribute__((ext_vector_type(8))) short short8;
typedef __attribute__((ext_vector_type(4))) float float4v;

union Frag {
    short8 s;
    unsigned short u[8];
    uint2 u2[2];
    uint4 u4;
};

__device__ __forceinline__ unsigned short f2b(float f) {
    unsigned u = __float_as_uint(f);
    return (unsigned short)((u + 0x7FFFu + ((u >> 16) & 1u)) >> 16);
}
__device__ __forceinline__ unsigned f2b_pk(float a, float b) {
    unsigned ua = __float_as_uint(a); ua = (ua + 0x7FFFu + ((ua >> 16) & 1u)) >> 16;
    unsigned ub = __float_as_uint(b); ub = (ub + 0x7FFFu + ((ub >> 16) & 1u)) >> 16;
    return ua | (ub << 16);
}
__device__ __forceinline__ unsigned pk_trunc(float a, float b) {
    return (__float_as_uint(a) >> 16) | (__float_as_uint(b) & 0xFFFF0000u);
}
__device__ __forceinline__ uint4 pk8(const float* v) {
    return make_uint4(f2b_pk(v[0], v[1]), f2b_pk(v[2], v[3]),
                      f2b_pk(v[4], v[5]), f2b_pk(v[6], v[7]));
}

// ---------------------------------------------------------------------------
// Twiddle tables (bf16), built fresh every launch into d_ws.
// ---------------------------------------------------------------------------
__global__ __launch_bounds__(256)
void twiddle_init_kernel(unsigned short* __restrict__ tw)
{
    int idx = blockIdx.x * 256 + threadIdx.x;
    if (idx >= TWTOT) return;
    float val = 0.f;
    if (idx < TW2F) {                       // TW1F
        int r = idx >> 6, c = idx & 63;
        if (c < 56) {
            if (r < 56)       val = cosf(kAng * (float)((r * c) % 56));
            else if (r < 112) val = sinf(kAng * (float)(((r - 56) * c) % 56));
        }
    } else if (idx < TW1I) {                // TW2F
        int t = idx - TW2F; int r = t >> 6, c = t & 63;
        if (c < 56) {
            if (r < 29)                  val = cosf(kAng * (float)((r * c) % 56));
            else if (r >= 32 && r < 61)  val = sinf(kAng * (float)(((r - 32) * c) % 56));
        }
    } else if (idx < TW2I) {                // TW1I
        int t = idx - TW1I; int r = t >> 6, c = t & 63;
        if (c < 56) {
            if (r < 56)                  val = cosf(kAng * (float)((r * c) % 56));
            else if (r >= 64 && r < 120) val = sinf(kAng * (float)(((r - 64) * c) % 56));
        }
    } else {                                // TW2I
        int t = idx - TW2I; int x = t >> 6, c = t & 63;
        if (x < 56 && c < 58) {
            int v = c >> 1;
            float wv = ((v == 0) || (v == 28)) ? 1.f : 2.f;
            float a = kAng * (float)((v * x) % 56);
            val = (c & 1) ? (-wv * sinf(a)) : (wv * cosf(a));
        }
    }
    tw[idx] = f2b(val);
}

// ---------------------------------------------------------------------------
// Forward 2D DFT via MFMA — 3 tensors in one dispatch (1536 blocks).
// ---------------------------------------------------------------------------
__global__ __launch_bounds__(256)
void dft_fwd_mfma3(const float* __restrict__ s0, const float* __restrict__ s1,
                   const float* __restrict__ s2, float* __restrict__ d0,
                   float* __restrict__ d1, float* __restrict__ d2,
                   const unsigned short* __restrict__ tw)
{
    const int bx = blockIdx.x;
    const int which = bx >> 9, ch = bx & 511;
    const int b = ch >> 8, c = ch & 255;
    const float* src; long stride; float* spec;
    if (which == 0)      { src = s0; stride = kCN;     spec = d0; }
    else if (which == 1) { src = s1; stride = 2 * kCN; spec = d1; }
    else                 { src = s2; stride = 2 * kCN; spec = d2; }
    const float* img = src + (long)b * stride + (long)c * kN;

    __shared__ __align__(16) char smem[48128];
    unsigned short (*Gb)[72]   = (unsigned short(*)[72])smem;            // 18432
    unsigned short (*imgT)[72] = (unsigned short(*)[72])(smem + 18432);  // 9216
    float (*Yb)[116]           = (float(*)[116])(smem + 18432);          // overlays imgT after F1

    const int tid = threadIdx.x;
    const int wave = tid >> 6, lane = tid & 63;
    const int ln = lane & 15, qd = lane >> 4;

    for (int i = tid; i < 64 * 72; i += 256) {
        int r = i / 72, cc = i - r * 72;
        if (r >= 56 || cc >= 56) imgT[r][cc] = 0;
    }
    for (int i = tid; i < kN; i += 256) {
        int y = i / 56, x = i - y * 56;
        imgT[x][y] = f2b(img[i]);
    }
    __syncthreads();

    float4v acc1[2][4];
#pragma unroll
    for (int m = 0; m < 2; ++m)
#pragma unroll
        for (int n = 0; n < 4; ++n) acc1[m][n] = (float4v){0.f, 0.f, 0.f, 0.f};
#pragma unroll
    for (int ks = 0; ks < 2; ++ks) {
        Frag a[2], bf[4];
#pragma unroll
        for (int m = 0; m < 2; ++m)
            a[m].u4 = *(const uint4*)(tw + TW1F + ((2 * wave + m) * 16 + ln) * 64 + ks * 32 + qd * 8);
#pragma unroll
        for (int n = 0; n < 4; ++n)
            bf[n].u4 = *(const uint4*)&imgT[n * 16 + ln][ks * 32 + qd * 8];
#pragma unroll
        for (int m = 0; m < 2; ++m)
#pragma unroll
            for (int n = 0; n < 4; ++n)
                acc1[m][n] = __builtin_amdgcn_mfma_f32_16x16x32_bf16(a[m].s, bf[n].s, acc1[m][n], 0, 0, 0);
    }
#pragma unroll
    for (int m = 0; m < 2; ++m)
#pragma unroll
        for (int n = 0; n < 4; ++n)
#pragma unroll
            for (int r = 0; r < 4; ++r)
                Gb[(2 * wave + m) * 16 + qd * 4 + r][n * 16 + ln] = f2b(acc1[m][n][r]);
    __syncthreads();

    float4v acc2[7];
#pragma unroll
    for (int n = 0; n < 7; ++n) acc2[n] = (float4v){0.f, 0.f, 0.f, 0.f};
#pragma unroll
    for (int ks = 0; ks < 2; ++ks) {
        Frag a;
        a.u4 = *(const uint4*)(tw + TW2F + (wave * 16 + ln) * 64 + ks * 32 + qd * 8);
#pragma unroll
        for (int n = 0; n < 7; ++n) {
            Frag bb;
            bb.u4 = *(const uint4*)&Gb[n * 16 + ln][ks * 32 + qd * 8];
            acc2[n] = __builtin_amdgcn_mfma_f32_16x16x32_bf16(a.s, bb.s, acc2[n], 0, 0, 0);
        }
    }
#pragma unroll
    for (int n = 0; n < 7; ++n)
#pragma unroll
        for (int r = 0; r < 4; ++r)
            Yb[wave * 16 + qd * 4 + r][n * 16 + ln] = acc2[n][r];
    __syncthreads();

    float2* outp = (float2*)spec + (long)ch * kSpec;
    for (int i = tid; i < kSpec; i += 256) {
        int u = i / kNF, v = i - u * kNF;
        float Qr = Yb[v][u] - Yb[32 + v][56 + u];
        float Qi = -Yb[32 + v][u] - Yb[v][56 + u];
        outp[i] = make_float2(Qr, Qi);
    }
}

// ---------------------------------------------------------------------------
// Inverse 2D DFT via MFMA, fused input complex-multiply and epilogue.
// mode 1 (spectral): P = spec*mul2; epilogue dst = dwconv3(sv) + amap*sv
// mode 2 (token):    P = spec*cw[c]; epilogue dst += acc
// ---------------------------------------------------------------------------
__global__ __launch_bounds__(256)
void dft_inv_mfma(const float* __restrict__ spec, const float* __restrict__ mul2,
                  const float* __restrict__ cw, float* __restrict__ dst,
                  const float* __restrict__ skvp, const float* __restrict__ dww,
                  const float* __restrict__ dwb, int mode, float scale,
                  const unsigned short* __restrict__ tw)
{
    const int ch = blockIdx.x;
    const int b = ch >> 8, c = ch & 255;
    __shared__ __align__(16) char smem[41984];
    unsigned short (*Pb)[72] = (unsigned short(*)[72])smem;           // 9216
    float (*Yb)[64]          = (float(*)[64])(smem + 9216);           // 32768
    unsigned short (*T2)[72] = (unsigned short(*)[72])smem;           // overlays Pb after I1
    float (*svs)[65]         = (float(*)[65])(smem + 9216);           // overlays Yb after T2 built

    const int tid = threadIdx.x;
    const int wave = tid >> 6, lane = tid & 63;
    const int ln = lane & 15, qd = lane >> 4;

    const float2* Pin = (const float2*)spec + (long)ch * kSpec;
    const float2* Min = (mode == 1) ? ((const float2*)mul2 + (long)ch * kSpec)
                                    : ((const float2*)cw + (long)c * kSpec);
    for (int i = tid; i < 64 * 72; i += 256) {
        int r = i / 72, cc = i - r * 72;
        if (r >= 58 || cc >= 56) Pb[r][cc] = 0;
    }
    for (int i = tid; i < kSpec; i += 256) {
        int u = i / kNF, v = i - u * kNF;
        float2 p = Pin[i];
        float2 m = Min[i];
        float pr = (p.x * m.x - p.y * m.y) * scale;
        float pi = (p.x * m.y + p.y * m.x) * scale;
        Pb[2 * v][u]     = f2b(pr);
        Pb[2 * v + 1][u] = f2b(pi);
    }
    __syncthreads();

    float4v acc1[2][4];
#pragma unroll
    for (int m = 0; m < 2; ++m)
#pragma unroll
        for (int n = 0; n < 4; ++n) acc1[m][n] = (float4v){0.f, 0.f, 0.f, 0.f};
#pragma unroll
    for (int ks = 0; ks < 2; ++ks) {
        Frag a[2], bf[4];
#pragma unroll
        for (int m = 0; m < 2; ++m)
            a[m].u4 = *(const uint4*)(tw + TW1I + ((2 * wave + m) * 16 + ln) * 64 + ks * 32 + qd * 8);
#pragma unroll
        for (int n = 0; n < 4; ++n)
            bf[n].u4 = *(const uint4*)&Pb[n * 16 + ln][ks * 32 + qd * 8];
#pragma unroll
        for (int m = 0; m < 2; ++m)
#pragma unroll
            for (int n = 0; n < 4; ++n)
                acc1[m][n] = __builtin_amdgcn_mfma_f32_16x16x32_bf16(a[m].s, bf[n].s, acc1[m][n], 0, 0, 0);
    }
#pragma unroll
    for (int m = 0; m < 2; ++m)
#pragma unroll
        for (int n = 0; n < 4; ++n)
#pragma unroll
            for (int r = 0; r < 4; ++r)
                Yb[(2 * wave + m) * 16 + qd * 4 + r][n * 16 + ln] = acc1[m][n][r];
    __syncthreads();

    for (int i = tid; i < 64 * 72; i += 256) {
        int r = i / 72, cc = i - r * 72;
        if (r >= 56 || cc >= 58) T2[r][cc] = 0;
    }
    __syncthreads();
    for (int i = tid; i < 56 * kNF; i += 256) {
        int y = i / kNF, v = i - y * kNF;
        float Tr = Yb[y][2 * v]     - Yb[64 + y][2 * v + 1];
        float Ti = Yb[y][2 * v + 1] + Yb[64 + y][2 * v];
        T2[y][2 * v]     = f2b(Tr);
        T2[y][2 * v + 1] = f2b(Ti);
    }
    __syncthreads();   // Yb dead from here; svs region free

    float wreg[9]; float bias = 0.f;
    const float* svp = nullptr;
    if (mode == 1) {
        svp = skvp + (long)b * 2 * kCN + kCN + (long)c * kN;
        for (int i = tid; i < 58 * 65; i += 256) {
            int y = i / 65, x = i - y * 65;
            if (y == 0 || y == 57 || x == 0 || x >= 57) ((float*)svs)[i] = 0.f;
        }
        for (int i = tid; i < kN; i += 256) {
            int y = i / 56, x = i - y * 56;
            svs[y + 1][x + 1] = svp[i];
        }
#pragma unroll
        for (int j = 0; j < 9; ++j) wreg[j] = dww[c * 9 + j];
        bias = dwb[c];
    }

    float4v acc2[4];
#pragma unroll
    for (int n = 0; n < 4; ++n) acc2[n] = (float4v){0.f, 0.f, 0.f, 0.f};
#pragma unroll
    for (int ks = 0; ks < 2; ++ks) {
        Frag a;
        a.u4 = *(const uint4*)(tw + TW2I + (wave * 16 + ln) * 64 + ks * 32 + qd * 8);
#pragma unroll
        for (int n = 0; n < 4; ++n) {
            Frag bb;
            bb.u4 = *(const uint4*)&T2[n * 16 + ln][ks * 32 + qd * 8];
            acc2[n] = __builtin_amdgcn_mfma_f32_16x16x32_bf16(a.s, bb.s, acc2[n], 0, 0, 0);
        }
    }
    __syncthreads();   // svs visible to all

    float* outd = dst + (long)ch * kN;
#pragma unroll
    for (int n = 0; n < 4; ++n) {
        int y = n * 16 + ln;
        if (y < 56) {
#pragma unroll
            for (int r = 0; r < 4; ++r) {
                int x = wave * 16 + qd * 4 + r;
                if (x < 56) {
                    int e = y * 56 + x;
                    if (mode == 1) {
                        float s = bias;
                        s = fmaf(wreg[0], svs[y][x],     s);
                        s = fmaf(wreg[1], svs[y][x + 1], s);
                        s = fmaf(wreg[2], svs[y][x + 2], s);
                        s = fmaf(wreg[3], svs[y + 1][x],     s);
                        s = fmaf(wreg[4], svs[y + 1][x + 1], s);
                        s = fmaf(wreg[5], svs[y + 1][x + 2], s);
                        s = fmaf(wreg[6], svs[y + 2][x],     s);
                        s = fmaf(wreg[7], svs[y + 2][x + 1], s);
                        s = fmaf(wreg[8], svs[y + 2][x + 2], s);
                        outd[e] = fmaf(acc2[n][r], svs[y + 1][x + 1], s);
                    } else {
                        outd[e] += acc2[n][r];
                    }
                }
            }
        }
    }
}

// ---------------------------------------------------------------------------
// MFMA GEMM (unchanged)
// ---------------------------------------------------------------------------
__global__ __launch_bounds__(256)
void gemm_kernel(const float* __restrict__ Wm, const float* __restrict__ X,
                 const float* __restrict__ bias, const float* __restrict__ gamma,
                 const float* __restrict__ beta, float* __restrict__ Y,
                 int CI, long xbs, long ybs, int mode)
{
    const int b  = blockIdx.z;
    const int o0 = blockIdx.y * 64;
    const int n0 = blockIdx.x * 128;
    const float* Xb = X + (long)b * xbs;
    float* Yb = Y + (long)b * ybs;

    __shared__ __align__(16) unsigned short Wt[64][40];
    __shared__ __align__(16) unsigned short Xt[128][40];

    const int tid = threadIdx.x;
    const int wave = tid >> 6, lane = tid & 63;
    const int ln = lane & 15, qd = lane >> 4;
    const int wy = wave >> 1, wx = wave & 1;

    const int ow = tid >> 2, kcw = tid & 3;
    const int nx = tid & 127, kcx = tid >> 7;
    const bool xvalid = (n0 + nx) < kN;

    float4v acc[2][4];
#pragma unroll
    for (int i = 0; i < 2; ++i)
#pragma unroll
        for (int j = 0; j < 4; ++j) acc[i][j] = (float4v){0.f, 0.f, 0.f, 0.f};

    float wpre[8], xpre[16];
    {
        const float* ws = Wm + (long)(o0 + ow) * CI + kcw * 8;
        *(float4*)&wpre[0] = *(const float4*)ws;
        *(float4*)&wpre[4] = *(const float4*)(ws + 4);
#pragma unroll
        for (int j = 0; j < 16; ++j)
            xpre[j] = xvalid ? Xb[(long)(kcx * 16 + j) * kN + n0 + nx] : 0.f;
    }

    for (int k0 = 0; k0 < CI; k0 += 32) {
        *(uint4*)&Wt[ow][kcw * 8]      = pk8(wpre);
        *(uint4*)&Xt[nx][kcx * 16]     = pk8(xpre);
        *(uint4*)&Xt[nx][kcx * 16 + 8] = pk8(xpre + 8);
        __syncthreads();

        if (k0 + 32 < CI) {
            const float* ws = Wm + (long)(o0 + ow) * CI + k0 + 32 + kcw * 8;
            *(float4*)&wpre[0] = *(const float4*)ws;
            *(float4*)&wpre[4] = *(const float4*)(ws + 4);
#pragma unroll
            for (int j = 0; j < 16; ++j)
                xpre[j] = xvalid ? Xb[(long)(k0 + 32 + kcx * 16 + j) * kN + n0 + nx] : 0.f;
        }

        Frag af[2], bf4[4];
#pragma unroll
        for (int mt = 0; mt < 2; ++mt)
            af[mt].u4 = *(const uint4*)&Wt[wy * 32 + mt * 16 + ln][qd * 8];
#pragma unroll
        for (int nt = 0; nt < 4; ++nt)
            bf4[nt].u4 = *(const uint4*)&Xt[wx * 64 + nt * 16 + ln][qd * 8];
#pragma unroll
        for (int mt = 0; mt < 2; ++mt)
#pragma unroll
            for (int nt = 0; nt < 4; ++nt)
                acc[mt][nt] = __builtin_amdgcn_mfma_f32_16x16x32_bf16(
                    af[mt].s, bf4[nt].s, acc[mt][nt], 0, 0, 0);
        __syncthreads();
    }

    const float rs = rsqrtf(1.0f + 1e-5f);
#pragma unroll
    for (int mt = 0; mt < 2; ++mt) {
        const int ob = o0 + wy * 32 + mt * 16 + qd * 4;
#pragma unroll
        for (int nt = 0; nt < 4; ++nt) {
            const int n = n0 + wx * 64 + nt * 16 + ln;
            if (n < kN) {
#pragma unroll
                for (int r = 0; r < 4; ++r) {
                    const int o = ob + r;
                    float v = acc[mt][nt][r];
                    if (mode == 0) { if (bias) v += bias[o]; }
                    else v = fmaxf(fmaf(v, gamma[o] * rs, beta[o]), 0.f);
                    Yb[(long)o * kN + n] = v;
                }
            }
        }
    }
}

// ---------------------------------------------------------------------------
// Attention K/V prepack (unchanged)
// ---------------------------------------------------------------------------
__global__ __launch_bounds__(256)
void attn_prepack_kernel(const float* __restrict__ tkv,
                         unsigned short* __restrict__ Kp,
                         unsigned short* __restrict__ Vp)
{
    const int blk = blockIdx.x;
    const int i = blk % 49;
    const int h = (blk / 49) & 7;
    const int b = blk / (49 * 8);
    const float* kb = tkv + (long)b * 2 * kCN + (long)h * kHD * kN;
    const float* vb = kb + kCN;
    const int tid = threadIdx.x;

    __shared__ float Ks[32][72];
#pragma unroll
    for (int j = 0; j < 8; ++j) {
        int e = tid + j * 256;
        int d = e >> 6, c = e & 63;
        Ks[d][c] = kb[(long)d * kN + i * 64 + c];
    }
    __syncthreads();
    {
        int tl = tid >> 6, lnn = (tid >> 2) & 15, qdd = tid & 3;
        float v[8];
#pragma unroll
        for (int j = 0; j < 8; ++j) v[j] = Ks[qdd * 8 + j][tl * 16 + lnn];
        unsigned short* dst = Kp + ((long)(b * 8 + h) * 196 + 4 * i + tl) * 512 + lnn * 32 + qdd * 8;
        *(uint4*)dst = pk8(v);
    }
    {
        int g = tid >> 7, dh = (tid >> 6) & 1, lnn = (tid >> 2) & 15, qdd = tid & 3;
        int d = dh * 16 + lnn;
        const float* src = vb + (long)d * kN + i * 64 + g * 32 + qdd * 8;
        float v[8];
        *(float4*)&v[0] = *(const float4*)src;
        *(float4*)&v[4] = *(const float4*)(src + 4);
        unsigned short* dst = Vp + ((long)(b * 8 + h) * 49 + i) * 2048 + ((g * 2 + dh) * 16 + lnn) * 32 + qdd * 8;
        *(uint4*)dst = pk8(v);
    }
}

// ---------------------------------------------------------------------------
// Token attention, k-split x2: unnormalized O-partials + l-partials.
// grid (25, 8, 4): z = b*2 + split. No barriers in loop.
// ---------------------------------------------------------------------------
__global__ __launch_bounds__(256)
void attn_mfma_kernel(const float* __restrict__ tq,
                      const unsigned short* __restrict__ Kp,
                      const unsigned short* __restrict__ Vp,
                      float* __restrict__ Op, float* __restrict__ lp)
{
    const int b = blockIdx.z >> 1, sp = blockIdx.z & 1;
    const int h = blockIdx.y;
    const int q0 = blockIdx.x * 128;
    const int tid = threadIdx.x;
    const int wave = tid >> 6, lane = tid & 63;
    const int qd = lane >> 4, ln = lane & 15;
    const int i0 = sp * 25, i1 = (sp == 0) ? 25 : 49;

    const float* qb = tq + (long)b * kCN + (long)h * kHD * kN;
    const unsigned short* KpB = Kp + (long)(b * 8 + h) * 196 * 512 + ln * 32 + qd * 8;
    const unsigned short* VpB = Vp + (long)(b * 8 + h) * 49 * 2048 + ln * 32 + qd * 8;

    __shared__ __align__(16) unsigned short Ps[4][32 * 40];
    unsigned short* PsW = Ps[wave];

    // Q fragments; attn scale * log2(e) folded in -> bare v_exp in loop
    const float qscale = kAttScale * kLog2e;
    Frag qf[2];
#pragma unroll
    for (int qt = 0; qt < 2; ++qt) {
        int qg = q0 + wave * 32 + qt * 16 + ln;
        bool qv = qg < kN;
#pragma unroll
        for (int j = 0; j < 8; ++j) {
            int d = qd * 8 + j;
            float v = qv ? qb[(long)d * kN + qg] * qscale : 0.f;
            qf[qt].u[j] = f2b(v);
        }
    }

    float4v o[2][2];
#pragma unroll
    for (int qt = 0; qt < 2; ++qt)
#pragma unroll
        for (int dh = 0; dh < 2; ++dh) o[qt][dh] = (float4v){0.f, 0.f, 0.f, 0.f};
    float lsum[2] = {0.f, 0.f};

    Frag ka[4];
#pragma unroll
    for (int m = 0; m < 4; ++m)
        ka[m].u4 = *(const uint4*)(KpB + (long)(4 * i0 + m) * 512);

    for (int i = i0; i < i1; ++i) {
        Frag va[2][2];
#pragma unroll
        for (int g = 0; g < 2; ++g)
#pragma unroll
            for (int dh = 0; dh < 2; ++dh)
                va[g][dh].u4 = *(const uint4*)(VpB + (long)i * 2048 + (g * 2 + dh) * 512);

        float4v st[4][2];
#pragma unroll
        for (int m = 0; m < 4; ++m)
#pragma unroll
            for (int qt = 0; qt < 2; ++qt)
                st[m][qt] = __builtin_amdgcn_mfma_f32_16x16x32_bf16(
                    ka[m].s, qf[qt].s, (float4v){0.f, 0.f, 0.f, 0.f}, 0, 0, 0);

        if (i + 1 < i1) {
#pragma unroll
            for (int m = 0; m < 4; ++m)
                ka[m].u4 = *(const uint4*)(KpB + (long)(4 * (i + 1) + m) * 512);
        }

#pragma unroll
        for (int m = 0; m < 4; ++m)
#pragma unroll
            for (int qt = 0; qt < 2; ++qt) {
                float e0 = __builtin_amdgcn_exp2f(st[m][qt][0]);
                float e1 = __builtin_amdgcn_exp2f(st[m][qt][1]);
                float e2 = __builtin_amdgcn_exp2f(st[m][qt][2]);
                float e3 = __builtin_amdgcn_exp2f(st[m][qt][3]);
                lsum[qt] += (e0 + e1) + (e2 + e3);
                uint2 w = make_uint2(pk_trunc(e0, e1), pk_trunc(e2, e3));
                *(uint2*)&PsW[(qt * 16 + ln) * 40 + m * 16 + qd * 4] = w;
            }

#pragma unroll
        for (int g = 0; g < 2; ++g) {
            Frag pa[2];
#pragma unroll
            for (int qt = 0; qt < 2; ++qt)
                pa[qt].u4 = *(const uint4*)&PsW[(qt * 16 + ln) * 40 + g * 32 + qd * 8];
#pragma unroll
            for (int qt = 0; qt < 2; ++qt)
#pragma unroll
                for (int dh = 0; dh < 2; ++dh)
                    o[qt][dh] = __builtin_amdgcn_mfma_f32_16x16x32_bf16(
                        pa[qt].s, va[g][dh].s, o[qt][dh], 0, 0, 0);
        }
    }

    const long grp = (long)(sp * 16 + b * 8 + h);
#pragma unroll
    for (int qt = 0; qt < 2; ++qt) {
        lsum[qt] += __shfl_xor(lsum[qt], 16, 64);
        lsum[qt] += __shfl_xor(lsum[qt], 32, 64);
        if (qd == 0)
            lp[grp * 3200 + q0 + wave * 32 + qt * 16 + ln] = lsum[qt];
#pragma unroll
        for (int dh = 0; dh < 2; ++dh)
#pragma unroll
            for (int r = 0; r < 4; ++r) {
                int q = q0 + wave * 32 + qt * 16 + qd * 4 + r;
                Op[(grp * 3200 + q) * 32 + dh * 16 + ln] = o[qt][dh][r];
            }
    }
}

// ---------------------------------------------------------------------------
// Combine k-split partials, normalize, transpose to xo[d][q] layout.
// grid (49, 16): 64 q per block.
// ---------------------------------------------------------------------------
__global__ __launch_bounds__(256)
void attn_combine_kernel(const float* __restrict__ Op, const float* __restrict__ lp,
                         float* __restrict__ xo)
{
    const int qc = blockIdx.x, bh = blockIdx.y;
    const int b = bh >> 3, h = bh & 7;
    const int q0 = qc * 64;
    __shared__ float T[32][65];
    const int tid = threadIdx.x;

    for (int i = tid; i < 64 * 32; i += 256) {
        int ql = i >> 5, d = i & 31;
        long e0 = ((long)bh * 3200 + q0 + ql) * 32 + d;
        long e1 = ((long)(16 + bh) * 3200 + q0 + ql) * 32 + d;
        float ov = Op[e0] + Op[e1];
        float l  = lp[(long)bh * 3200 + q0 + ql] + lp[(long)(16 + bh) * 3200 + q0 + ql];
        T[d][ql] = ov / l;
    }
    __syncthreads();
    for (int i = tid; i < 32 * 64; i += 256) {
        int d = i >> 6, ql = i & 63;
        xo[(long)b * kCN + (long)(h * kHD + d) * kN + q0 + ql] = T[d][ql];
    }
}

// ---------------------------------------------------------------------------
// Gate + blend
// ---------------------------------------------------------------------------
__global__ __launch_bounds__(256)
void gate_kernel(const float* __restrict__ hbuf, const float* __restrict__ w2,
                 const float* __restrict__ b2, float* __restrict__ gate)
{
    const int wave = threadIdx.x >> 6;
    const int lane = threadIdx.x & 63;
    const int p = blockIdx.x * 4 + wave;
    if (p >= kB * kN) return;
    const int b = p / kN, n = p - b * kN;
    const float* hb = hbuf + (long)b * kCN + n;
    float s = 0.f;
#pragma unroll
    for (int c0 = 0; c0 < kC; c0 += 64) {
        int c = c0 + lane;
        s = fmaf(w2[c], hb[(long)c * kN], s);
    }
#pragma unroll
    for (int off = 32; off > 0; off >>= 1) s += __shfl_down(s, off, 64);
    if (lane == 0) gate[p] = 1.f / (1.f + __expf(-(s + b2[0])));
}

__global__ __launch_bounds__(256)
void blend_kernel(const float* __restrict__ gcat, const float* __restrict__ gate,
                  float* __restrict__ out)
{
    long e = (long)blockIdx.x * 256 + threadIdx.x;
    if (e >= (long)kB * kCN) return;
    long b = e / kCN, r = e - b * kCN;
    long n = r % kN;
    float g = gate[b * kN + n];
    float os = gcat[b * 2 * kCN + r];
    float ot = gcat[b * 2 * kCN + kCN + r];
    out[e] = g * os + (1.f - g) * ot;
}

// ---------------------------------------------------------------------------
extern "C" void kernel_launch(void* const* d_in, const int* in_sizes, int n_in,
                              void* d_out, int out_size, void* d_ws, size_t ws_size,
                              hipStream_t stream)
{
    const float* x      = (const float*)d_in[0];
    const float* ctx    = (const float*)d_in[1];
    const float* s_q_w  = (const float*)d_in[2];
    const float* s_kv_w = (const float*)d_in[3];
    const float* s_p_w  = (const float*)d_in[4];
    const float* s_p_b  = (const float*)d_in[5];
    const float* s_dw_w = (const float*)d_in[6];
    const float* s_dw_b = (const float*)d_in[7];
    const float* t_q_w  = (const float*)d_in[8];
    const float* t_kv_w = (const float*)d_in[9];
    const float* t_p_w  = (const float*)d_in[10];
    const float* t_p_b  = (const float*)d_in[11];
    const float* t_cw   = (const float*)d_in[12];
    const float* g_w1   = (const float*)d_in[13];
    const float* g_bn_g = (const float*)d_in[14];
    const float* g_bn_b = (const float*)d_in[15];
    const float* g_w2   = (const float*)d_in[16];
    const float* g_b2   = (const float*)d_in[17];
    float* out = (float*)d_out;

    float* ws = (float*)d_ws;
    const long SPEC2 = (long)kB * kC * kSpec * 2;
    float* sq   = ws;                    // B*C*N   (xattn + vres accum)
    float* skv  = sq   + kB * kCN;       // B*2C*N
    float* tq   = skv  + kB * 2 * kCN;   // B*C*N
    float* tkv  = tq   + kB * kCN;       // B*2C*N  (later: h)
    float* vloc = tkv  + kB * 2 * kCN;   // B*C*N   (spre result)
    float* fQ   = vloc + kB * kCN;
    float* fK   = fQ   + SPEC2;
    float* fV   = fK   + SPEC2;
    float* gcat = fV   + SPEC2;          // B*2C*N : [os ; ot]
    float* gate = gcat + kB * 2 * kCN;   // B*N
    unsigned short* tw = (unsigned short*)(gate + kB * kN);  // twiddles
    unsigned short* Kp = tw + TWTOT;                         // 16*196*512 u16
    unsigned short* Vp = Kp + (long)16 * 196 * 512;          // 16*49*2048 u16
    float* Opart = (float*)(Vp + (long)16 * 49 * 2048);      // 32*3200*32 f32
    float* lpart = Opart + (long)32 * 3200 * 32;             // 32*3200 f32

    dim3 blk(256, 1, 1);
    const int EW = (int)((long)kB * kCN / 256);

    twiddle_init_kernel<<<dim3(TWTOT / 256), blk, 0, stream>>>(tw);

    gemm_kernel<<<dim3(25, 4, kB), blk, 0, stream>>>(s_q_w,  x,   nullptr, nullptr, nullptr, sq,  kC,     kCN, kCN,     0);
    gemm_kernel<<<dim3(25, 8, kB), blk, 0, stream>>>(s_kv_w, ctx, nullptr, nullptr, nullptr, skv, kC,     kCN, 2 * kCN, 0);
    gemm_kernel<<<dim3(25, 4, kB), blk, 0, stream>>>(t_q_w,  x,   nullptr, nullptr, nullptr, tq,  kC,     kCN, kCN,     0);
    gemm_kernel<<<dim3(25, 8, kB), blk, 0, stream>>>(t_kv_w, ctx, nullptr, nullptr, nullptr, tkv, kC,     kCN, 2 * kCN, 0);

    // all three forward DFTs in one dispatch
    dft_fwd_mfma3<<<dim3(3 * kB * kC), blk, 0, stream>>>(sq, skv, tkv + kCN, fQ, fK, fV, tw);

    // vloc = dwconv3(sv) + irfft(fQ*fK)*sv   (cmul + irfft + dwconv + spre fused)
    dft_inv_mfma<<<dim3(kB * kC), blk, 0, stream>>>(fQ, fK, nullptr, vloc, skv, s_dw_w, s_dw_b, 1, 1.0f / 175616.0f, tw);
    gemm_kernel<<<dim3(25, 4, kB), blk, 0, stream>>>(s_p_w, vloc, s_p_b, nullptr, nullptr, gcat, kC, kCN, 2 * kCN, 0); // os

    attn_prepack_kernel<<<dim3(kB * kNH * 49), blk, 0, stream>>>(tkv, Kp, Vp);
    attn_mfma_kernel<<<dim3(25, kNH, 2 * kB), blk, 0, stream>>>(tq, Kp, Vp, Opart, lpart);
    attn_combine_kernel<<<dim3(49, 16), blk, 0, stream>>>(Opart, lpart, sq);     // xattn -> sq
    // sq += irfft(fV*cw)
    dft_inv_mfma<<<dim3(kB * kC), blk, 0, stream>>>(fV, nullptr, t_cw, sq, nullptr, nullptr, nullptr, 2, 1.0f / 3136.0f, tw);
    gemm_kernel<<<dim3(25, 4, kB), blk, 0, stream>>>(t_p_w, sq, t_p_b, nullptr, nullptr, gcat + kCN, kC, kCN, 2 * kCN, 0); // ot

    gemm_kernel<<<dim3(25, 4, kB), blk, 0, stream>>>(g_w1, gcat, nullptr, g_bn_g, g_bn_b, tkv, 2 * kC, 2 * kCN, kCN, 1); // h
    gate_kernel<<<dim3(kB * kN / 4), blk, 0, stream>>>(tkv, g_w2, g_b2, gate);
    blend_kernel<<<dim3(EW), blk, 0, stream>>>(gcat, gate, out);
}

// Round 9
// 285.696 us; speedup vs baseline: 4.7109x; 1.1767x over previous
//
#include <hip/hip_runtime.h>

namespace {
constexpr int kB = 2;
constexpr int kC = 256;
constexpr int kH = 56;
constexpr int kW = 56;
constexpr int kN = kH * kW;        // 3136
constexpr int kNH = 8;
constexpr int kHD = 32;
constexpr int kNF = kW / 2 + 1;    // 29
constexpr int kSpec = kH * kNF;    // 1624
constexpr long kCN = (long)kC * kN;        // 802816
constexpr float kAttScale = 0.17677669529663687f;   // 32^-0.5
constexpr float kLog2e = 1.4426950408889634f;
constexpr float kAng = 6.283185307179586f / 56.0f;  // 2*pi/56
// twiddle table offsets in u16 units
constexpr int TW1F = 0;            // [128][64]
constexpr int TW2F = 8192;         // [64][64]
constexpr int TW1I = 12288;        // [128][64]
constexpr int TW2I = 20480;        // [64][64]
constexpr int TWTOT = 24576;
}

typedef __attribute__((ext_vector_type(8))) short short8;
typedef __attribute__((ext_vector_type(4))) float float4v;

union Frag {
    short8 s;
    unsigned short u[8];
    uint2 u2[2];
    uint4 u4;
};

__device__ __forceinline__ unsigned short f2b(float f) {
    unsigned u = __float_as_uint(f);
    return (unsigned short)((u + 0x7FFFu + ((u >> 16) & 1u)) >> 16);
}
__device__ __forceinline__ unsigned f2b_pk(float a, float b) {
    unsigned ua = __float_as_uint(a); ua = (ua + 0x7FFFu + ((ua >> 16) & 1u)) >> 16;
    unsigned ub = __float_as_uint(b); ub = (ub + 0x7FFFu + ((ub >> 16) & 1u)) >> 16;
    return ua | (ub << 16);
}
__device__ __forceinline__ unsigned pk_trunc(float a, float b) {
    return (__float_as_uint(a) >> 16) | (__float_as_uint(b) & 0xFFFF0000u);
}
__device__ __forceinline__ uint4 pk8(const float* v) {
    return make_uint4(f2b_pk(v[0], v[1]), f2b_pk(v[2], v[3]),
                      f2b_pk(v[4], v[5]), f2b_pk(v[6], v[7]));
}

// ---------------------------------------------------------------------------
// Twiddle tables (bf16), built fresh every launch into d_ws.
// ---------------------------------------------------------------------------
__global__ __launch_bounds__(256)
void twiddle_init_kernel(unsigned short* __restrict__ tw)
{
    int idx = blockIdx.x * 256 + threadIdx.x;
    if (idx >= TWTOT) return;
    float val = 0.f;
    if (idx < TW2F) {                       // TW1F
        int r = idx >> 6, c = idx & 63;
        if (c < 56) {
            if (r < 56)       val = cosf(kAng * (float)((r * c) % 56));
            else if (r < 112) val = sinf(kAng * (float)(((r - 56) * c) % 56));
        }
    } else if (idx < TW1I) {                // TW2F
        int t = idx - TW2F; int r = t >> 6, c = t & 63;
        if (c < 56) {
            if (r < 29)                  val = cosf(kAng * (float)((r * c) % 56));
            else if (r >= 32 && r < 61)  val = sinf(kAng * (float)(((r - 32) * c) % 56));
        }
    } else if (idx < TW2I) {                // TW1I
        int t = idx - TW1I; int r = t >> 6, c = t & 63;
        if (c < 56) {
            if (r < 56)                  val = cosf(kAng * (float)((r * c) % 56));
            else if (r >= 64 && r < 120) val = sinf(kAng * (float)(((r - 64) * c) % 56));
        }
    } else {                                // TW2I
        int t = idx - TW2I; int x = t >> 6, c = t & 63;
        if (x < 56 && c < 58) {
            int v = c >> 1;
            float wv = ((v == 0) || (v == 28)) ? 1.f : 2.f;
            float a = kAng * (float)((v * x) % 56);
            val = (c & 1) ? (-wv * sinf(a)) : (wv * cosf(a));
        }
    }
    tw[idx] = f2b(val);
}

// ---------------------------------------------------------------------------
// Forward 2D DFT via MFMA — 3 tensors in one dispatch (1536 blocks).
// ---------------------------------------------------------------------------
__global__ __launch_bounds__(256)
void dft_fwd_mfma3(const float* __restrict__ s0, const float* __restrict__ s1,
                   const float* __restrict__ s2, float* __restrict__ d0,
                   float* __restrict__ d1, float* __restrict__ d2,
                   const unsigned short* __restrict__ tw)
{
    const int bx = blockIdx.x;
    const int which = bx >> 9, ch = bx & 511;
    const int b = ch >> 8, c = ch & 255;
    const float* src; long stride; float* spec;
    if (which == 0)      { src = s0; stride = kCN;     spec = d0; }
    else if (which == 1) { src = s1; stride = 2 * kCN; spec = d1; }
    else                 { src = s2; stride = 2 * kCN; spec = d2; }
    const float* img = src + (long)b * stride + (long)c * kN;

    __shared__ __align__(16) char smem[48128];
    unsigned short (*Gb)[72]   = (unsigned short(*)[72])smem;            // 18432
    unsigned short (*imgT)[72] = (unsigned short(*)[72])(smem + 18432);  // 9216
    float (*Yb)[116]           = (float(*)[116])(smem + 18432);          // overlays imgT after F1

    const int tid = threadIdx.x;
    const int wave = tid >> 6, lane = tid & 63;
    const int ln = lane & 15, qd = lane >> 4;

    for (int i = tid; i < 64 * 72; i += 256) {
        int r = i / 72, cc = i - r * 72;
        if (r >= 56 || cc >= 56) imgT[r][cc] = 0;
    }
    for (int i = tid; i < kN; i += 256) {
        int y = i / 56, x = i - y * 56;
        imgT[x][y] = f2b(img[i]);
    }
    __syncthreads();

    float4v acc1[2][4];
#pragma unroll
    for (int m = 0; m < 2; ++m)
#pragma unroll
        for (int n = 0; n < 4; ++n) acc1[m][n] = (float4v){0.f, 0.f, 0.f, 0.f};
#pragma unroll
    for (int ks = 0; ks < 2; ++ks) {
        Frag a[2], bf[4];
#pragma unroll
        for (int m = 0; m < 2; ++m)
            a[m].u4 = *(const uint4*)(tw + TW1F + ((2 * wave + m) * 16 + ln) * 64 + ks * 32 + qd * 8);
#pragma unroll
        for (int n = 0; n < 4; ++n)
            bf[n].u4 = *(const uint4*)&imgT[n * 16 + ln][ks * 32 + qd * 8];
#pragma unroll
        for (int m = 0; m < 2; ++m)
#pragma unroll
            for (int n = 0; n < 4; ++n)
                acc1[m][n] = __builtin_amdgcn_mfma_f32_16x16x32_bf16(a[m].s, bf[n].s, acc1[m][n], 0, 0, 0);
    }
#pragma unroll
    for (int m = 0; m < 2; ++m)
#pragma unroll
        for (int n = 0; n < 4; ++n)
#pragma unroll
            for (int r = 0; r < 4; ++r)
                Gb[(2 * wave + m) * 16 + qd * 4 + r][n * 16 + ln] = f2b(acc1[m][n][r]);
    __syncthreads();

    float4v acc2[7];
#pragma unroll
    for (int n = 0; n < 7; ++n) acc2[n] = (float4v){0.f, 0.f, 0.f, 0.f};
#pragma unroll
    for (int ks = 0; ks < 2; ++ks) {
        Frag a;
        a.u4 = *(const uint4*)(tw + TW2F + (wave * 16 + ln) * 64 + ks * 32 + qd * 8);
#pragma unroll
        for (int n = 0; n < 7; ++n) {
            Frag bb;
            bb.u4 = *(const uint4*)&Gb[n * 16 + ln][ks * 32 + qd * 8];
            acc2[n] = __builtin_amdgcn_mfma_f32_16x16x32_bf16(a.s, bb.s, acc2[n], 0, 0, 0);
        }
    }
#pragma unroll
    for (int n = 0; n < 7; ++n)
#pragma unroll
        for (int r = 0; r < 4; ++r)
            Yb[wave * 16 + qd * 4 + r][n * 16 + ln] = acc2[n][r];
    __syncthreads();

    float2* outp = (float2*)spec + (long)ch * kSpec;
    for (int i = tid; i < kSpec; i += 256) {
        int u = i / kNF, v = i - u * kNF;
        float Qr = Yb[v][u] - Yb[32 + v][56 + u];
        float Qi = -Yb[32 + v][u] - Yb[v][56 + u];
        outp[i] = make_float2(Qr, Qi);
    }
}

// ---------------------------------------------------------------------------
// Inverse 2D DFT via MFMA, both branches in one dispatch (1024 blocks).
// unit 0 (spectral): P = fQ*fK * s1; epilogue dst1 = dwconv3(sv) + acc*sv
// unit 1 (token):    P = fV*cw[c] * s2; epilogue dst2 = acc (pure store)
// ---------------------------------------------------------------------------
__global__ __launch_bounds__(256)
void dft_inv_mfma2(const float* __restrict__ fQ, const float* __restrict__ fK,
                   const float* __restrict__ fV, const float* __restrict__ cw,
                   float* __restrict__ dst1, float* __restrict__ dst2,
                   const float* __restrict__ skvp, const float* __restrict__ dww,
                   const float* __restrict__ dwb, const unsigned short* __restrict__ tw)
{
    const int unit = blockIdx.x >> 9;
    const int ch = blockIdx.x & 511;
    const int b = ch >> 8, c = ch & 255;
    __shared__ __align__(16) char smem[41984];
    unsigned short (*Pb)[72] = (unsigned short(*)[72])smem;           // 9216
    float (*Yb)[64]          = (float(*)[64])(smem + 9216);           // 32768
    unsigned short (*T2)[72] = (unsigned short(*)[72])smem;           // overlays Pb after I1
    float (*svs)[65]         = (float(*)[65])(smem + 9216);           // overlays Yb after T2 built

    const int tid = threadIdx.x;
    const int wave = tid >> 6, lane = tid & 63;
    const int ln = lane & 15, qd = lane >> 4;

    const float2* Pin; const float2* Min; float scale; float* dst;
    if (unit == 0) {
        Pin = (const float2*)fQ + (long)ch * kSpec;
        Min = (const float2*)fK + (long)ch * kSpec;
        scale = 1.0f / 175616.0f; dst = dst1;
    } else {
        Pin = (const float2*)fV + (long)ch * kSpec;
        Min = (const float2*)cw + (long)c * kSpec;
        scale = 1.0f / 3136.0f; dst = dst2;
    }

    for (int i = tid; i < 64 * 72; i += 256) {
        int r = i / 72, cc = i - r * 72;
        if (r >= 58 || cc >= 56) Pb[r][cc] = 0;
    }
    for (int i = tid; i < kSpec; i += 256) {
        int u = i / kNF, v = i - u * kNF;
        float2 p = Pin[i];
        float2 m = Min[i];
        float pr = (p.x * m.x - p.y * m.y) * scale;
        float pi = (p.x * m.y + p.y * m.x) * scale;
        Pb[2 * v][u]     = f2b(pr);
        Pb[2 * v + 1][u] = f2b(pi);
    }
    __syncthreads();

    float4v acc1[2][4];
#pragma unroll
    for (int m = 0; m < 2; ++m)
#pragma unroll
        for (int n = 0; n < 4; ++n) acc1[m][n] = (float4v){0.f, 0.f, 0.f, 0.f};
#pragma unroll
    for (int ks = 0; ks < 2; ++ks) {
        Frag a[2], bf[4];
#pragma unroll
        for (int m = 0; m < 2; ++m)
            a[m].u4 = *(const uint4*)(tw + TW1I + ((2 * wave + m) * 16 + ln) * 64 + ks * 32 + qd * 8);
#pragma unroll
        for (int n = 0; n < 4; ++n)
            bf[n].u4 = *(const uint4*)&Pb[n * 16 + ln][ks * 32 + qd * 8];
#pragma unroll
        for (int m = 0; m < 2; ++m)
#pragma unroll
            for (int n = 0; n < 4; ++n)
                acc1[m][n] = __builtin_amdgcn_mfma_f32_16x16x32_bf16(a[m].s, bf[n].s, acc1[m][n], 0, 0, 0);
    }
#pragma unroll
    for (int m = 0; m < 2; ++m)
#pragma unroll
        for (int n = 0; n < 4; ++n)
#pragma unroll
            for (int r = 0; r < 4; ++r)
                Yb[(2 * wave + m) * 16 + qd * 4 + r][n * 16 + ln] = acc1[m][n][r];
    __syncthreads();

    for (int i = tid; i < 64 * 72; i += 256) {
        int r = i / 72, cc = i - r * 72;
        if (r >= 56 || cc >= 58) T2[r][cc] = 0;
    }
    __syncthreads();
    for (int i = tid; i < 56 * kNF; i += 256) {
        int y = i / kNF, v = i - y * kNF;
        float Tr = Yb[y][2 * v]     - Yb[64 + y][2 * v + 1];
        float Ti = Yb[y][2 * v + 1] + Yb[64 + y][2 * v];
        T2[y][2 * v]     = f2b(Tr);
        T2[y][2 * v + 1] = f2b(Ti);
    }
    __syncthreads();   // Yb dead from here; svs region free

    float wreg[9]; float bias = 0.f;
    if (unit == 0) {
        const float* svp = skvp + (long)b * 2 * kCN + kCN + (long)c * kN;
        for (int i = tid; i < 58 * 65; i += 256) {
            int y = i / 65, x = i - y * 65;
            if (y == 0 || y == 57 || x == 0 || x >= 57) ((float*)svs)[i] = 0.f;
        }
        for (int i = tid; i < kN; i += 256) {
            int y = i / 56, x = i - y * 56;
            svs[y + 1][x + 1] = svp[i];
        }
#pragma unroll
        for (int j = 0; j < 9; ++j) wreg[j] = dww[c * 9 + j];
        bias = dwb[c];
    }

    float4v acc2[4];
#pragma unroll
    for (int n = 0; n < 4; ++n) acc2[n] = (float4v){0.f, 0.f, 0.f, 0.f};
#pragma unroll
    for (int ks = 0; ks < 2; ++ks) {
        Frag a;
        a.u4 = *(const uint4*)(tw + TW2I + (wave * 16 + ln) * 64 + ks * 32 + qd * 8);
#pragma unroll
        for (int n = 0; n < 4; ++n) {
            Frag bb;
            bb.u4 = *(const uint4*)&T2[n * 16 + ln][ks * 32 + qd * 8];
            acc2[n] = __builtin_amdgcn_mfma_f32_16x16x32_bf16(a.s, bb.s, acc2[n], 0, 0, 0);
        }
    }
    __syncthreads();   // svs visible to all

    float* outd = dst + (long)ch * kN;
#pragma unroll
    for (int n = 0; n < 4; ++n) {
        int y = n * 16 + ln;
        if (y < 56) {
#pragma unroll
            for (int r = 0; r < 4; ++r) {
                int x = wave * 16 + qd * 4 + r;
                if (x < 56) {
                    int e = y * 56 + x;
                    if (unit == 0) {
                        float s = bias;
                        s = fmaf(wreg[0], svs[y][x],     s);
                        s = fmaf(wreg[1], svs[y][x + 1], s);
                        s = fmaf(wreg[2], svs[y][x + 2], s);
                        s = fmaf(wreg[3], svs[y + 1][x],     s);
                        s = fmaf(wreg[4], svs[y + 1][x + 1], s);
                        s = fmaf(wreg[5], svs[y + 1][x + 2], s);
                        s = fmaf(wreg[6], svs[y + 2][x],     s);
                        s = fmaf(wreg[7], svs[y + 2][x + 1], s);
                        s = fmaf(wreg[8], svs[y + 2][x + 2], s);
                        outd[e] = fmaf(acc2[n][r], svs[y + 1][x + 1], s);
                    } else {
                        outd[e] = acc2[n][r];     // pure store (vres), combine adds xattn
                    }
                }
            }
        }
    }
}

// ---------------------------------------------------------------------------
// Fused dual-GEMM (bias epilogue). Weight/bias rows use o0 (local space);
// output rows use oY = o0 + sel*oOffset. *** Fixed from round 8: weight
// staging previously used the offset row and read OOB. ***
// ---------------------------------------------------------------------------
__global__ __launch_bounds__(256)
void gemm_fused(const float* __restrict__ W0, const float* __restrict__ W1,
                const float* __restrict__ X0, const float* __restrict__ X1,
                const float* __restrict__ b0, const float* __restrict__ b1,
                float* __restrict__ Y0, float* __restrict__ Y1,
                int oHalf, int CI, long xbs, long ybs, int oOffset)
{
    const int b  = blockIdx.z;
    const int sel = blockIdx.y >= oHalf;
    const int o0 = (sel ? blockIdx.y - oHalf : blockIdx.y) * 64;   // weight/bias row base
    const int oY = o0 + (sel ? oOffset : 0);                       // output row base
    const int n0 = blockIdx.x * 128;
    const float* Wm = sel ? W1 : W0;
    const float* bias = sel ? b1 : b0;
    const float* Xb = (sel ? X1 : X0) + (long)b * xbs;
    float* Yb = (sel ? Y1 : Y0) + (long)b * ybs;

    __shared__ __align__(16) unsigned short Wt[64][40];
    __shared__ __align__(16) unsigned short Xt[128][40];

    const int tid = threadIdx.x;
    const int wave = tid >> 6, lane = tid & 63;
    const int ln = lane & 15, qd = lane >> 4;
    const int wy = wave >> 1, wx = wave & 1;

    const int ow = tid >> 2, kcw = tid & 3;
    const int nx = tid & 127, kcx = tid >> 7;
    const bool xvalid = (n0 + nx) < kN;

    float4v acc[2][4];
#pragma unroll
    for (int i = 0; i < 2; ++i)
#pragma unroll
        for (int j = 0; j < 4; ++j) acc[i][j] = (float4v){0.f, 0.f, 0.f, 0.f};

    float wpre[8], xpre[16];
    {
        const float* ws = Wm + (long)(o0 + ow) * CI + kcw * 8;
        *(float4*)&wpre[0] = *(const float4*)ws;
        *(float4*)&wpre[4] = *(const float4*)(ws + 4);
#pragma unroll
        for (int j = 0; j < 16; ++j)
            xpre[j] = xvalid ? Xb[(long)(kcx * 16 + j) * kN + n0 + nx] : 0.f;
    }

    for (int k0 = 0; k0 < CI; k0 += 32) {
        *(uint4*)&Wt[ow][kcw * 8]      = pk8(wpre);
        *(uint4*)&Xt[nx][kcx * 16]     = pk8(xpre);
        *(uint4*)&Xt[nx][kcx * 16 + 8] = pk8(xpre + 8);
        __syncthreads();

        if (k0 + 32 < CI) {
            const float* ws = Wm + (long)(o0 + ow) * CI + k0 + 32 + kcw * 8;
            *(float4*)&wpre[0] = *(const float4*)ws;
            *(float4*)&wpre[4] = *(const float4*)(ws + 4);
#pragma unroll
            for (int j = 0; j < 16; ++j)
                xpre[j] = xvalid ? Xb[(long)(k0 + 32 + kcx * 16 + j) * kN + n0 + nx] : 0.f;
        }

        Frag af[2], bf4[4];
#pragma unroll
        for (int mt = 0; mt < 2; ++mt)
            af[mt].u4 = *(const uint4*)&Wt[wy * 32 + mt * 16 + ln][qd * 8];
#pragma unroll
        for (int nt = 0; nt < 4; ++nt)
            bf4[nt].u4 = *(const uint4*)&Xt[wx * 64 + nt * 16 + ln][qd * 8];
#pragma unroll
        for (int mt = 0; mt < 2; ++mt)
#pragma unroll
            for (int nt = 0; nt < 4; ++nt)
                acc[mt][nt] = __builtin_amdgcn_mfma_f32_16x16x32_bf16(
                    af[mt].s, bf4[nt].s, acc[mt][nt], 0, 0, 0);
        __syncthreads();
    }

#pragma unroll
    for (int mt = 0; mt < 2; ++mt) {
        const int obL = o0 + wy * 32 + mt * 16 + qd * 4;   // bias row
        const int obY = oY + wy * 32 + mt * 16 + qd * 4;   // output row
#pragma unroll
        for (int nt = 0; nt < 4; ++nt) {
            const int n = n0 + wx * 64 + nt * 16 + ln;
            if (n < kN) {
#pragma unroll
                for (int r = 0; r < 4; ++r) {
                    float v = acc[mt][nt][r];
                    if (bias) v += bias[obL + r];
                    Yb[(long)(obY + r) * kN + n] = v;
                }
            }
        }
    }
}

// ---------------------------------------------------------------------------
// BN+ReLU GEMM for the gate hidden layer (CI=512)
// ---------------------------------------------------------------------------
__global__ __launch_bounds__(256)
void gemm_bn_kernel(const float* __restrict__ Wm, const float* __restrict__ X,
                    const float* __restrict__ gamma, const float* __restrict__ beta,
                    float* __restrict__ Y, int CI, long xbs, long ybs)
{
    const int b  = blockIdx.z;
    const int o0 = blockIdx.y * 64;
    const int n0 = blockIdx.x * 128;
    const float* Xb = X + (long)b * xbs;
    float* Yb = Y + (long)b * ybs;

    __shared__ __align__(16) unsigned short Wt[64][40];
    __shared__ __align__(16) unsigned short Xt[128][40];

    const int tid = threadIdx.x;
    const int wave = tid >> 6, lane = tid & 63;
    const int ln = lane & 15, qd = lane >> 4;
    const int wy = wave >> 1, wx = wave & 1;

    const int ow = tid >> 2, kcw = tid & 3;
    const int nx = tid & 127, kcx = tid >> 7;
    const bool xvalid = (n0 + nx) < kN;

    float4v acc[2][4];
#pragma unroll
    for (int i = 0; i < 2; ++i)
#pragma unroll
        for (int j = 0; j < 4; ++j) acc[i][j] = (float4v){0.f, 0.f, 0.f, 0.f};

    float wpre[8], xpre[16];
    {
        const float* ws = Wm + (long)(o0 + ow) * CI + kcw * 8;
        *(float4*)&wpre[0] = *(const float4*)ws;
        *(float4*)&wpre[4] = *(const float4*)(ws + 4);
#pragma unroll
        for (int j = 0; j < 16; ++j)
            xpre[j] = xvalid ? Xb[(long)(kcx * 16 + j) * kN + n0 + nx] : 0.f;
    }

    for (int k0 = 0; k0 < CI; k0 += 32) {
        *(uint4*)&Wt[ow][kcw * 8]      = pk8(wpre);
        *(uint4*)&Xt[nx][kcx * 16]     = pk8(xpre);
        *(uint4*)&Xt[nx][kcx * 16 + 8] = pk8(xpre + 8);
        __syncthreads();

        if (k0 + 32 < CI) {
            const float* ws = Wm + (long)(o0 + ow) * CI + k0 + 32 + kcw * 8;
            *(float4*)&wpre[0] = *(const float4*)ws;
            *(float4*)&wpre[4] = *(const float4*)(ws + 4);
#pragma unroll
            for (int j = 0; j < 16; ++j)
                xpre[j] = xvalid ? Xb[(long)(k0 + 32 + kcx * 16 + j) * kN + n0 + nx] : 0.f;
        }

        Frag af[2], bf4[4];
#pragma unroll
        for (int mt = 0; mt < 2; ++mt)
            af[mt].u4 = *(const uint4*)&Wt[wy * 32 + mt * 16 + ln][qd * 8];
#pragma unroll
        for (int nt = 0; nt < 4; ++nt)
            bf4[nt].u4 = *(const uint4*)&Xt[wx * 64 + nt * 16 + ln][qd * 8];
#pragma unroll
        for (int mt = 0; mt < 2; ++mt)
#pragma unroll
            for (int nt = 0; nt < 4; ++nt)
                acc[mt][nt] = __builtin_amdgcn_mfma_f32_16x16x32_bf16(
                    af[mt].s, bf4[nt].s, acc[mt][nt], 0, 0, 0);
        __syncthreads();
    }

    const float rs = rsqrtf(1.0f + 1e-5f);
#pragma unroll
    for (int mt = 0; mt < 2; ++mt) {
        const int ob = o0 + wy * 32 + mt * 16 + qd * 4;
#pragma unroll
        for (int nt = 0; nt < 4; ++nt) {
            const int n = n0 + wx * 64 + nt * 16 + ln;
            if (n < kN) {
#pragma unroll
                for (int r = 0; r < 4; ++r) {
                    const int o = ob + r;
                    float v = fmaxf(fmaf(acc[mt][nt][r], gamma[o] * rs, beta[o]), 0.f);
                    Yb[(long)o * kN + n] = v;
                }
            }
        }
    }
}

// ---------------------------------------------------------------------------
// Attention K/V prepack (unchanged)
// ---------------------------------------------------------------------------
__global__ __launch_bounds__(256)
void attn_prepack_kernel(const float* __restrict__ tkv,
                         unsigned short* __restrict__ Kp,
                         unsigned short* __restrict__ Vp)
{
    const int blk = blockIdx.x;
    const int i = blk % 49;
    const int h = (blk / 49) & 7;
    const int b = blk / (49 * 8);
    const float* kb = tkv + (long)b * 2 * kCN + (long)h * kHD * kN;
    const float* vb = kb + kCN;
    const int tid = threadIdx.x;

    __shared__ float Ks[32][72];
#pragma unroll
    for (int j = 0; j < 8; ++j) {
        int e = tid + j * 256;
        int d = e >> 6, c = e & 63;
        Ks[d][c] = kb[(long)d * kN + i * 64 + c];
    }
    __syncthreads();
    {
        int tl = tid >> 6, lnn = (tid >> 2) & 15, qdd = tid & 3;
        float v[8];
#pragma unroll
        for (int j = 0; j < 8; ++j) v[j] = Ks[qdd * 8 + j][tl * 16 + lnn];
        unsigned short* dst = Kp + ((long)(b * 8 + h) * 196 + 4 * i + tl) * 512 + lnn * 32 + qdd * 8;
        *(uint4*)dst = pk8(v);
    }
    {
        int g = tid >> 7, dh = (tid >> 6) & 1, lnn = (tid >> 2) & 15, qdd = tid & 3;
        int d = dh * 16 + lnn;
        const float* src = vb + (long)d * kN + i * 64 + g * 32 + qdd * 8;
        float v[8];
        *(float4*)&v[0] = *(const float4*)src;
        *(float4*)&v[4] = *(const float4*)(src + 4);
        unsigned short* dst = Vp + ((long)(b * 8 + h) * 49 + i) * 2048 + ((g * 2 + dh) * 16 + lnn) * 32 + qdd * 8;
        *(uint4*)dst = pk8(v);
    }
}

// ---------------------------------------------------------------------------
// Token attention, k-split x4: unnormalized O-partials + l-partials.
// grid (25, 8, 8): z = b*4 + split. Splits: 13,12,12,12 tiles.
// ---------------------------------------------------------------------------
__global__ __launch_bounds__(256)
void attn_mfma_kernel(const float* __restrict__ tq,
                      const unsigned short* __restrict__ Kp,
                      const unsigned short* __restrict__ Vp,
                      float* __restrict__ Op, float* __restrict__ lp)
{
    const int b = blockIdx.z >> 2, sp = blockIdx.z & 3;
    const int h = blockIdx.y;
    const int q0 = blockIdx.x * 128;
    const int tid = threadIdx.x;
    const int wave = tid >> 6, lane = tid & 63;
    const int qd = lane >> 4, ln = lane & 15;
    const int i0 = (sp == 0) ? 0 : (12 * sp + 1);
    const int i1 = 12 * sp + 13;

    const float* qb = tq + (long)b * kCN + (long)h * kHD * kN;
    const unsigned short* KpB = Kp + (long)(b * 8 + h) * 196 * 512 + ln * 32 + qd * 8;
    const unsigned short* VpB = Vp + (long)(b * 8 + h) * 49 * 2048 + ln * 32 + qd * 8;

    __shared__ __align__(16) unsigned short Ps[4][32 * 40];
    unsigned short* PsW = Ps[wave];

    const float qscale = kAttScale * kLog2e;
    Frag qf[2];
#pragma unroll
    for (int qt = 0; qt < 2; ++qt) {
        int qg = q0 + wave * 32 + qt * 16 + ln;
        bool qv = qg < kN;
#pragma unroll
        for (int j = 0; j < 8; ++j) {
            int d = qd * 8 + j;
            float v = qv ? qb[(long)d * kN + qg] * qscale : 0.f;
            qf[qt].u[j] = f2b(v);
        }
    }

    float4v o[2][2];
#pragma unroll
    for (int qt = 0; qt < 2; ++qt)
#pragma unroll
        for (int dh = 0; dh < 2; ++dh) o[qt][dh] = (float4v){0.f, 0.f, 0.f, 0.f};
    float lsum[2] = {0.f, 0.f};

    Frag ka[4];
#pragma unroll
    for (int m = 0; m < 4; ++m)
        ka[m].u4 = *(const uint4*)(KpB + (long)(4 * i0 + m) * 512);

    for (int i = i0; i < i1; ++i) {
        Frag va[2][2];
#pragma unroll
        for (int g = 0; g < 2; ++g)
#pragma unroll
            for (int dh = 0; dh < 2; ++dh)
                va[g][dh].u4 = *(const uint4*)(VpB + (long)i * 2048 + (g * 2 + dh) * 512);

        float4v st[4][2];
#pragma unroll
        for (int m = 0; m < 4; ++m)
#pragma unroll
            for (int qt = 0; qt < 2; ++qt)
                st[m][qt] = __builtin_amdgcn_mfma_f32_16x16x32_bf16(
                    ka[m].s, qf[qt].s, (float4v){0.f, 0.f, 0.f, 0.f}, 0, 0, 0);

        if (i + 1 < i1) {
#pragma unroll
            for (int m = 0; m < 4; ++m)
                ka[m].u4 = *(const uint4*)(KpB + (long)(4 * (i + 1) + m) * 512);
        }

#pragma unroll
        for (int m = 0; m < 4; ++m)
#pragma unroll
            for (int qt = 0; qt < 2; ++qt) {
                float e0 = __builtin_amdgcn_exp2f(st[m][qt][0]);
                float e1 = __builtin_amdgcn_exp2f(st[m][qt][1]);
                float e2 = __builtin_amdgcn_exp2f(st[m][qt][2]);
                float e3 = __builtin_amdgcn_exp2f(st[m][qt][3]);
                lsum[qt] += (e0 + e1) + (e2 + e3);
                uint2 w = make_uint2(pk_trunc(e0, e1), pk_trunc(e2, e3));
                *(uint2*)&PsW[(qt * 16 + ln) * 40 + m * 16 + qd * 4] = w;
            }

#pragma unroll
        for (int g = 0; g < 2; ++g) {
            Frag pa[2];
#pragma unroll
            for (int qt = 0; qt < 2; ++qt)
                pa[qt].u4 = *(const uint4*)&PsW[(qt * 16 + ln) * 40 + g * 32 + qd * 8];
#pragma unroll
            for (int qt = 0; qt < 2; ++qt)
#pragma unroll
                for (int dh = 0; dh < 2; ++dh)
                    o[qt][dh] = __builtin_amdgcn_mfma_f32_16x16x32_bf16(
                        pa[qt].s, va[g][dh].s, o[qt][dh], 0, 0, 0);
        }
    }

    const long grp = (long)(sp * 16 + b * 8 + h);
#pragma unroll
    for (int qt = 0; qt < 2; ++qt) {
        lsum[qt] += __shfl_xor(lsum[qt], 16, 64);
        lsum[qt] += __shfl_xor(lsum[qt], 32, 64);
        if (qd == 0)
            lp[grp * 3200 + q0 + wave * 32 + qt * 16 + ln] = lsum[qt];
#pragma unroll
        for (int dh = 0; dh < 2; ++dh)
#pragma unroll
            for (int r = 0; r < 4; ++r) {
                int q = q0 + wave * 32 + qt * 16 + qd * 4 + r;
                Op[(grp * 3200 + q) * 32 + dh * 16 + ln] = o[qt][dh][r];
            }
    }
}

// ---------------------------------------------------------------------------
// Combine 4 k-split partials, normalize, transpose, ADD into xo (holds vres).
// grid (49, 16): 64 q per block.
// ---------------------------------------------------------------------------
__global__ __launch_bounds__(256)
void attn_combine_kernel(const float* __restrict__ Op, const float* __restrict__ lp,
                         float* __restrict__ xo)
{
    const int qc = blockIdx.x, bh = blockIdx.y;
    const int b = bh >> 3, h = bh & 7;
    const int q0 = qc * 64;
    __shared__ float T[32][65];
    const int tid = threadIdx.x;

    for (int i = tid; i < 64 * 32; i += 256) {
        int ql = i >> 5, d = i & 31;
        float ov = 0.f, l = 0.f;
#pragma unroll
        for (int s = 0; s < 4; ++s) {
            long g = (long)(s * 16 + bh);
            ov += Op[(g * 3200 + q0 + ql) * 32 + d];
            l  += lp[g * 3200 + q0 + ql];
        }
        T[d][ql] = ov / l;
    }
    __syncthreads();
    for (int i = tid; i < 32 * 64; i += 256) {
        int d = i >> 6, ql = i & 63;
        xo[(long)b * kCN + (long)(h * kHD + d) * kN + q0 + ql] += T[d][ql];
    }
}

// ---------------------------------------------------------------------------
// Gate: coalesced. Block = (64 n, b); 4 c-groups of 64; LDS reduce.
// ---------------------------------------------------------------------------
__global__ __launch_bounds__(256)
void gate_kernel(const float* __restrict__ hbuf, const float* __restrict__ w2,
                 const float* __restrict__ b2, float* __restrict__ gate)
{
    const int n0 = blockIdx.x * 64;
    const int b = blockIdx.y;
    const int lane = threadIdx.x & 63;
    const int g = threadIdx.x >> 6;
    const float* hb = hbuf + (long)b * kCN + n0 + lane;
    float s = 0.f;
#pragma unroll 8
    for (int c = g * 64; c < g * 64 + 64; ++c)
        s = fmaf(w2[c], hb[(long)c * kN], s);
    __shared__ float red[4][64];
    red[g][lane] = s;
    __syncthreads();
    if (g == 0) {
        float t = red[0][lane] + red[1][lane] + red[2][lane] + red[3][lane];
        gate[(long)b * kN + n0 + lane] = 1.f / (1.f + __expf(-(t + b2[0])));
    }
}

__global__ __launch_bounds__(256)
void blend_kernel(const float* __restrict__ gcat, const float* __restrict__ gate,
                  float* __restrict__ out)
{
    long e = (long)blockIdx.x * 256 + threadIdx.x;
    if (e >= (long)kB * kCN) return;
    long b = e / kCN, r = e - b * kCN;
    long n = r % kN;
    float g = gate[b * kN + n];
    float os = gcat[b * 2 * kCN + r];
    float ot = gcat[b * 2 * kCN + kCN + r];
    out[e] = g * os + (1.f - g) * ot;
}

// ---------------------------------------------------------------------------
extern "C" void kernel_launch(void* const* d_in, const int* in_sizes, int n_in,
                              void* d_out, int out_size, void* d_ws, size_t ws_size,
                              hipStream_t stream)
{
    const float* x      = (const float*)d_in[0];
    const float* ctx    = (const float*)d_in[1];
    const float* s_q_w  = (const float*)d_in[2];
    const float* s_kv_w = (const float*)d_in[3];
    const float* s_p_w  = (const float*)d_in[4];
    const float* s_p_b  = (const float*)d_in[5];
    const float* s_dw_w = (const float*)d_in[6];
    const float* s_dw_b = (const float*)d_in[7];
    const float* t_q_w  = (const float*)d_in[8];
    const float* t_kv_w = (const float*)d_in[9];
    const float* t_p_w  = (const float*)d_in[10];
    const float* t_p_b  = (const float*)d_in[11];
    const float* t_cw   = (const float*)d_in[12];
    const float* g_w1   = (const float*)d_in[13];
    const float* g_bn_g = (const float*)d_in[14];
    const float* g_bn_b = (const float*)d_in[15];
    const float* g_w2   = (const float*)d_in[16];
    const float* g_b2   = (const float*)d_in[17];
    float* out = (float*)d_out;

    float* ws = (float*)d_ws;
    const long SPEC2 = (long)kB * kC * kSpec * 2;
    float* sq   = ws;                    // B*C*N   (sq -> vres -> tpre)
    float* skv  = sq   + kB * kCN;       // B*2C*N
    float* tq   = skv  + kB * 2 * kCN;   // B*C*N
    float* tkv  = tq   + kB * kCN;       // B*2C*N  (later: h)
    float* vloc = tkv  + kB * 2 * kCN;   // B*C*N   (spre result)
    float* fQ   = vloc + kB * kCN;
    float* fK   = fQ   + SPEC2;
    float* fV   = fK   + SPEC2;
    float* gcat = fV   + SPEC2;          // B*2C*N : [os ; ot]
    float* gate = gcat + kB * 2 * kCN;   // B*N
    unsigned short* tw = (unsigned short*)(gate + kB * kN);  // twiddles
    unsigned short* Kp = tw + TWTOT;                         // 16*196*512 u16
    unsigned short* Vp = Kp + (long)16 * 196 * 512;          // 16*49*2048 u16
    float* Opart = (float*)(Vp + (long)16 * 49 * 2048);      // 64*3200*32 f32
    float* lpart = Opart + (long)64 * 3200 * 32;             // 64*3200 f32

    dim3 blk(256, 1, 1);
    const int EW = (int)((long)kB * kCN / 256);

    twiddle_init_kernel<<<dim3(TWTOT / 256), blk, 0, stream>>>(tw);

    // q projections (both branches share input x); kv projections (share ctx)
    gemm_fused<<<dim3(25, 8, kB), blk, 0, stream>>>(
        s_q_w, t_q_w, x, x, nullptr, nullptr, sq, tq, 4, kC, kCN, kCN, 0);
    gemm_fused<<<dim3(25, 16, kB), blk, 0, stream>>>(
        s_kv_w, t_kv_w, ctx, ctx, nullptr, nullptr, skv, tkv, 8, kC, kCN, 2 * kCN, 0);

    // all three forward DFTs in one dispatch
    dft_fwd_mfma3<<<dim3(3 * kB * kC), blk, 0, stream>>>(sq, skv, tkv + kCN, fQ, fK, fV, tw);

    // both inverse DFTs in one dispatch:
    //   unit0: vloc = dwconv3(sv) + irfft(fQ*fK)*sv ; unit1: sq = irfft(fV*cw)
    dft_inv_mfma2<<<dim3(2 * kB * kC), blk, 0, stream>>>(
        fQ, fK, fV, t_cw, vloc, sq, skv, s_dw_w, s_dw_b, tw);

    attn_prepack_kernel<<<dim3(kB * kNH * 49), blk, 0, stream>>>(tkv, Kp, Vp);
    attn_mfma_kernel<<<dim3(25, kNH, 4 * kB), blk, 0, stream>>>(tq, Kp, Vp, Opart, lpart);
    attn_combine_kernel<<<dim3(49, 16), blk, 0, stream>>>(Opart, lpart, sq);  // sq += xattn

    // both output projections (different inputs) in one dispatch -> gcat
    gemm_fused<<<dim3(25, 8, kB), blk, 0, stream>>>(
        s_p_w, t_p_w, vloc, sq, s_p_b, t_p_b, gcat, gcat, 4, kC, kCN, 2 * kCN, 256);

    gemm_bn_kernel<<<dim3(25, 4, kB), blk, 0, stream>>>(g_w1, gcat, g_bn_g, g_bn_b, tkv, 2 * kC, 2 * kCN, kCN); // h
    gate_kernel<<<dim3(49, kB), blk, 0, stream>>>(tkv, g_w2, g_b2, gate);
    blend_kernel<<<dim3(EW), blk, 0, stream>>>(gcat, gate, out);
}

// Round 10
// 281.467 us; speedup vs baseline: 4.7816x; 1.0150x over previous
//
#include <hip/hip_runtime.h>

namespace {
constexpr int kB = 2;
constexpr int kC = 256;
constexpr int kH = 56;
constexpr int kW = 56;
constexpr int kN = kH * kW;        // 3136
constexpr int kNH = 8;
constexpr int kHD = 32;
constexpr int kNF = kW / 2 + 1;    // 29
constexpr int kSpec = kH * kNF;    // 1624
constexpr long kCN = (long)kC * kN;        // 802816
constexpr float kAttScale = 0.17677669529663687f;   // 32^-0.5
constexpr float kLog2e = 1.4426950408889634f;
constexpr float kAng = 6.283185307179586f / 56.0f;  // 2*pi/56
// twiddle table offsets in u16 units
constexpr int TW1F = 0;            // [128][64]
constexpr int TW2F = 8192;         // [64][64]
constexpr int TW1I = 12288;        // [128][64]
constexpr int TW2I = 20480;        // [64][64]
constexpr int TWTOT = 24576;
}

typedef __attribute__((ext_vector_type(8))) short short8;
typedef __attribute__((ext_vector_type(4))) float float4v;

union Frag {
    short8 s;
    unsigned short u[8];
    uint2 u2[2];
    uint4 u4;
};

__device__ __forceinline__ unsigned short f2b(float f) {
    unsigned u = __float_as_uint(f);
    return (unsigned short)((u + 0x7FFFu + ((u >> 16) & 1u)) >> 16);
}
__device__ __forceinline__ unsigned f2b_pk(float a, float b) {
    unsigned ua = __float_as_uint(a); ua = (ua + 0x7FFFu + ((ua >> 16) & 1u)) >> 16;
    unsigned ub = __float_as_uint(b); ub = (ub + 0x7FFFu + ((ub >> 16) & 1u)) >> 16;
    return ua | (ub << 16);
}
__device__ __forceinline__ unsigned pk_trunc(float a, float b) {
    return (__float_as_uint(a) >> 16) | (__float_as_uint(b) & 0xFFFF0000u);
}
__device__ __forceinline__ uint4 pk8(const float* v) {
    return make_uint4(f2b_pk(v[0], v[1]), f2b_pk(v[2], v[3]),
                      f2b_pk(v[4], v[5]), f2b_pk(v[6], v[7]));
}

// ---------------------------------------------------------------------------
// Twiddle tables (bf16), built fresh every launch into d_ws.
// ---------------------------------------------------------------------------
__global__ __launch_bounds__(256)
void twiddle_init_kernel(unsigned short* __restrict__ tw)
{
    int idx = blockIdx.x * 256 + threadIdx.x;
    if (idx >= TWTOT) return;
    float val = 0.f;
    if (idx < TW2F) {                       // TW1F
        int r = idx >> 6, c = idx & 63;
        if (c < 56) {
            if (r < 56)       val = cosf(kAng * (float)((r * c) % 56));
            else if (r < 112) val = sinf(kAng * (float)(((r - 56) * c) % 56));
        }
    } else if (idx < TW1I) {                // TW2F
        int t = idx - TW2F; int r = t >> 6, c = t & 63;
        if (c < 56) {
            if (r < 29)                  val = cosf(kAng * (float)((r * c) % 56));
            else if (r >= 32 && r < 61)  val = sinf(kAng * (float)(((r - 32) * c) % 56));
        }
    } else if (idx < TW2I) {                // TW1I
        int t = idx - TW1I; int r = t >> 6, c = t & 63;
        if (c < 56) {
            if (r < 56)                  val = cosf(kAng * (float)((r * c) % 56));
            else if (r >= 64 && r < 120) val = sinf(kAng * (float)(((r - 64) * c) % 56));
        }
    } else {                                // TW2I
        int t = idx - TW2I; int x = t >> 6, c = t & 63;
        if (x < 56 && c < 58) {
            int v = c >> 1;
            float wv = ((v == 0) || (v == 28)) ? 1.f : 2.f;
            float a = kAng * (float)((v * x) % 56);
            val = (c & 1) ? (-wv * sinf(a)) : (wv * cosf(a));
        }
    }
    tw[idx] = f2b(val);
}

// ---------------------------------------------------------------------------
// Forward 2D DFT body (one channel image per block)
// ---------------------------------------------------------------------------
__device__ void dft_fwd_body(char* smem, int bx,
                             const float* __restrict__ s0, const float* __restrict__ s1,
                             const float* __restrict__ s2, float* __restrict__ d0,
                             float* __restrict__ d1, float* __restrict__ d2,
                             const unsigned short* __restrict__ tw)
{
    const int which = bx >> 9, ch = bx & 511;
    const int b = ch >> 8, c = ch & 255;
    const float* src; long stride; float* spec;
    if (which == 0)      { src = s0; stride = kCN;     spec = d0; }
    else if (which == 1) { src = s1; stride = 2 * kCN; spec = d1; }
    else                 { src = s2; stride = 2 * kCN; spec = d2; }
    const float* img = src + (long)b * stride + (long)c * kN;

    unsigned short (*Gb)[72]   = (unsigned short(*)[72])smem;            // 18432
    unsigned short (*imgT)[72] = (unsigned short(*)[72])(smem + 18432);  // 9216
    float (*Yb)[116]           = (float(*)[116])(smem + 18432);          // overlays imgT after F1

    const int tid = threadIdx.x;
    const int wave = tid >> 6, lane = tid & 63;
    const int ln = lane & 15, qd = lane >> 4;

    for (int i = tid; i < 64 * 72; i += 256) {
        int r = i / 72, cc = i - r * 72;
        if (r >= 56 || cc >= 56) imgT[r][cc] = 0;
    }
    for (int i = tid; i < kN; i += 256) {
        int y = i / 56, x = i - y * 56;
        imgT[x][y] = f2b(img[i]);
    }
    __syncthreads();

    float4v acc1[2][4];
#pragma unroll
    for (int m = 0; m < 2; ++m)
#pragma unroll
        for (int n = 0; n < 4; ++n) acc1[m][n] = (float4v){0.f, 0.f, 0.f, 0.f};
#pragma unroll
    for (int ks = 0; ks < 2; ++ks) {
        Frag a[2], bf[4];
#pragma unroll
        for (int m = 0; m < 2; ++m)
            a[m].u4 = *(const uint4*)(tw + TW1F + ((2 * wave + m) * 16 + ln) * 64 + ks * 32 + qd * 8);
#pragma unroll
        for (int n = 0; n < 4; ++n)
            bf[n].u4 = *(const uint4*)&imgT[n * 16 + ln][ks * 32 + qd * 8];
#pragma unroll
        for (int m = 0; m < 2; ++m)
#pragma unroll
            for (int n = 0; n < 4; ++n)
                acc1[m][n] = __builtin_amdgcn_mfma_f32_16x16x32_bf16(a[m].s, bf[n].s, acc1[m][n], 0, 0, 0);
    }
#pragma unroll
    for (int m = 0; m < 2; ++m)
#pragma unroll
        for (int n = 0; n < 4; ++n)
#pragma unroll
            for (int r = 0; r < 4; ++r)
                Gb[(2 * wave + m) * 16 + qd * 4 + r][n * 16 + ln] = f2b(acc1[m][n][r]);
    __syncthreads();

    float4v acc2[7];
#pragma unroll
    for (int n = 0; n < 7; ++n) acc2[n] = (float4v){0.f, 0.f, 0.f, 0.f};
#pragma unroll
    for (int ks = 0; ks < 2; ++ks) {
        Frag a;
        a.u4 = *(const uint4*)(tw + TW2F + (wave * 16 + ln) * 64 + ks * 32 + qd * 8);
#pragma unroll
        for (int n = 0; n < 7; ++n) {
            Frag bb;
            bb.u4 = *(const uint4*)&Gb[n * 16 + ln][ks * 32 + qd * 8];
            acc2[n] = __builtin_amdgcn_mfma_f32_16x16x32_bf16(a.s, bb.s, acc2[n], 0, 0, 0);
        }
    }
#pragma unroll
    for (int n = 0; n < 7; ++n)
#pragma unroll
        for (int r = 0; r < 4; ++r)
            Yb[wave * 16 + qd * 4 + r][n * 16 + ln] = acc2[n][r];
    __syncthreads();

    float2* outp = (float2*)spec + (long)ch * kSpec;
    for (int i = tid; i < kSpec; i += 256) {
        int u = i / kNF, v = i - u * kNF;
        float Qr = Yb[v][u] - Yb[32 + v][56 + u];
        float Qi = -Yb[32 + v][u] - Yb[v][56 + u];
        outp[i] = make_float2(Qr, Qi);
    }
}

// ---------------------------------------------------------------------------
// Attention K/V prepack body
// ---------------------------------------------------------------------------
__device__ void prepack_body(char* smem, int blk, const float* __restrict__ tkv,
                             unsigned short* __restrict__ Kp,
                             unsigned short* __restrict__ Vp)
{
    const int i = blk % 49;
    const int h = (blk / 49) & 7;
    const int b = blk / (49 * 8);
    const float* kb = tkv + (long)b * 2 * kCN + (long)h * kHD * kN;
    const float* vb = kb + kCN;
    const int tid = threadIdx.x;

    float (*Ks)[72] = (float(*)[72])smem;   // 32*72*4 = 9216 B
#pragma unroll
    for (int j = 0; j < 8; ++j) {
        int e = tid + j * 256;
        int d = e >> 6, c = e & 63;
        Ks[d][c] = kb[(long)d * kN + i * 64 + c];
    }
    __syncthreads();
    {
        int tl = tid >> 6, lnn = (tid >> 2) & 15, qdd = tid & 3;
        float v[8];
#pragma unroll
        for (int j = 0; j < 8; ++j) v[j] = Ks[qdd * 8 + j][tl * 16 + lnn];
        unsigned short* dst = Kp + ((long)(b * 8 + h) * 196 + 4 * i + tl) * 512 + lnn * 32 + qdd * 8;
        *(uint4*)dst = pk8(v);
    }
    {
        int g = tid >> 7, dh = (tid >> 6) & 1, lnn = (tid >> 2) & 15, qdd = tid & 3;
        int d = dh * 16 + lnn;
        const float* src = vb + (long)d * kN + i * 64 + g * 32 + qdd * 8;
        float v[8];
        *(float4*)&v[0] = *(const float4*)src;
        *(float4*)&v[4] = *(const float4*)(src + 4);
        unsigned short* dst = Vp + ((long)(b * 8 + h) * 49 + i) * 2048 + ((g * 2 + dh) * 16 + lnn) * 32 + qdd * 8;
        *(uint4*)dst = pk8(v);
    }
}

// ---------------------------------------------------------------------------
// Merged dispatch: blocks [0,1536) forward DFTs; [1536,2320) K/V prepack.
// Both depend only on the projection GEMMs — independent of each other.
// ---------------------------------------------------------------------------
__global__ __launch_bounds__(256)
void fwd3_prepack_kernel(const float* __restrict__ s0, const float* __restrict__ s1,
                         const float* __restrict__ s2, float* __restrict__ d0,
                         float* __restrict__ d1, float* __restrict__ d2,
                         const unsigned short* __restrict__ tw,
                         const float* __restrict__ tkv,
                         unsigned short* __restrict__ Kp, unsigned short* __restrict__ Vp)
{
    __shared__ __align__(16) char smem[48128];
    if (blockIdx.x < 1536)
        dft_fwd_body(smem, blockIdx.x, s0, s1, s2, d0, d1, d2, tw);
    else
        prepack_body(smem, blockIdx.x - 1536, tkv, Kp, Vp);
}

// ---------------------------------------------------------------------------
// Inverse 2D DFT via MFMA, both branches in one dispatch (1024 blocks).
// unit 0 (spectral): P = fQ*fK * s1; epilogue dst1 = dwconv3(sv) + acc*sv
// unit 1 (token):    P = fV*cw[c] * s2; epilogue dst2 = acc (pure store)
// ---------------------------------------------------------------------------
__global__ __launch_bounds__(256)
void dft_inv_mfma2(const float* __restrict__ fQ, const float* __restrict__ fK,
                   const float* __restrict__ fV, const float* __restrict__ cw,
                   float* __restrict__ dst1, float* __restrict__ dst2,
                   const float* __restrict__ skvp, const float* __restrict__ dww,
                   const float* __restrict__ dwb, const unsigned short* __restrict__ tw)
{
    const int unit = blockIdx.x >> 9;
    const int ch = blockIdx.x & 511;
    const int b = ch >> 8, c = ch & 255;
    __shared__ __align__(16) char smem[41984];
    unsigned short (*Pb)[72] = (unsigned short(*)[72])smem;           // 9216
    float (*Yb)[64]          = (float(*)[64])(smem + 9216);           // 32768
    unsigned short (*T2)[72] = (unsigned short(*)[72])smem;           // overlays Pb after I1
    float (*svs)[65]         = (float(*)[65])(smem + 9216);           // overlays Yb after T2 built

    const int tid = threadIdx.x;
    const int wave = tid >> 6, lane = tid & 63;
    const int ln = lane & 15, qd = lane >> 4;

    const float2* Pin; const float2* Min; float scale; float* dst;
    if (unit == 0) {
        Pin = (const float2*)fQ + (long)ch * kSpec;
        Min = (const float2*)fK + (long)ch * kSpec;
        scale = 1.0f / 175616.0f; dst = dst1;
    } else {
        Pin = (const float2*)fV + (long)ch * kSpec;
        Min = (const float2*)cw + (long)c * kSpec;
        scale = 1.0f / 3136.0f; dst = dst2;
    }

    for (int i = tid; i < 64 * 72; i += 256) {
        int r = i / 72, cc = i - r * 72;
        if (r >= 58 || cc >= 56) Pb[r][cc] = 0;
    }
    for (int i = tid; i < kSpec; i += 256) {
        int u = i / kNF, v = i - u * kNF;
        float2 p = Pin[i];
        float2 m = Min[i];
        float pr = (p.x * m.x - p.y * m.y) * scale;
        float pi = (p.x * m.y + p.y * m.x) * scale;
        Pb[2 * v][u]     = f2b(pr);
        Pb[2 * v + 1][u] = f2b(pi);
    }
    __syncthreads();

    float4v acc1[2][4];
#pragma unroll
    for (int m = 0; m < 2; ++m)
#pragma unroll
        for (int n = 0; n < 4; ++n) acc1[m][n] = (float4v){0.f, 0.f, 0.f, 0.f};
#pragma unroll
    for (int ks = 0; ks < 2; ++ks) {
        Frag a[2], bf[4];
#pragma unroll
        for (int m = 0; m < 2; ++m)
            a[m].u4 = *(const uint4*)(tw + TW1I + ((2 * wave + m) * 16 + ln) * 64 + ks * 32 + qd * 8);
#pragma unroll
        for (int n = 0; n < 4; ++n)
            bf[n].u4 = *(const uint4*)&Pb[n * 16 + ln][ks * 32 + qd * 8];
#pragma unroll
        for (int m = 0; m < 2; ++m)
#pragma unroll
            for (int n = 0; n < 4; ++n)
                acc1[m][n] = __builtin_amdgcn_mfma_f32_16x16x32_bf16(a[m].s, bf[n].s, acc1[m][n], 0, 0, 0);
    }
#pragma unroll
    for (int m = 0; m < 2; ++m)
#pragma unroll
        for (int n = 0; n < 4; ++n)
#pragma unroll
            for (int r = 0; r < 4; ++r)
                Yb[(2 * wave + m) * 16 + qd * 4 + r][n * 16 + ln] = acc1[m][n][r];
    __syncthreads();

    for (int i = tid; i < 64 * 72; i += 256) {
        int r = i / 72, cc = i - r * 72;
        if (r >= 56 || cc >= 58) T2[r][cc] = 0;
    }
    __syncthreads();
    for (int i = tid; i < 56 * kNF; i += 256) {
        int y = i / kNF, v = i - y * kNF;
        float Tr = Yb[y][2 * v]     - Yb[64 + y][2 * v + 1];
        float Ti = Yb[y][2 * v + 1] + Yb[64 + y][2 * v];
        T2[y][2 * v]     = f2b(Tr);
        T2[y][2 * v + 1] = f2b(Ti);
    }
    __syncthreads();   // Yb dead from here; svs region free

    float wreg[9]; float bias = 0.f;
    if (unit == 0) {
        const float* svp = skvp + (long)b * 2 * kCN + kCN + (long)c * kN;
        for (int i = tid; i < 58 * 65; i += 256) {
            int y = i / 65, x = i - y * 65;
            if (y == 0 || y == 57 || x == 0 || x >= 57) ((float*)svs)[i] = 0.f;
        }
        for (int i = tid; i < kN; i += 256) {
            int y = i / 56, x = i - y * 56;
            svs[y + 1][x + 1] = svp[i];
        }
#pragma unroll
        for (int j = 0; j < 9; ++j) wreg[j] = dww[c * 9 + j];
        bias = dwb[c];
    }

    float4v acc2[4];
#pragma unroll
    for (int n = 0; n < 4; ++n) acc2[n] = (float4v){0.f, 0.f, 0.f, 0.f};
#pragma unroll
    for (int ks = 0; ks < 2; ++ks) {
        Frag a;
        a.u4 = *(const uint4*)(tw + TW2I + (wave * 16 + ln) * 64 + ks * 32 + qd * 8);
#pragma unroll
        for (int n = 0; n < 4; ++n) {
            Frag bb;
            bb.u4 = *(const uint4*)&T2[n * 16 + ln][ks * 32 + qd * 8];
            acc2[n] = __builtin_amdgcn_mfma_f32_16x16x32_bf16(a.s, bb.s, acc2[n], 0, 0, 0);
        }
    }
    __syncthreads();   // svs visible to all

    float* outd = dst + (long)ch * kN;
#pragma unroll
    for (int n = 0; n < 4; ++n) {
        int y = n * 16 + ln;
        if (y < 56) {
#pragma unroll
            for (int r = 0; r < 4; ++r) {
                int x = wave * 16 + qd * 4 + r;
                if (x < 56) {
                    int e = y * 56 + x;
                    if (unit == 0) {
                        float s = bias;
                        s = fmaf(wreg[0], svs[y][x],     s);
                        s = fmaf(wreg[1], svs[y][x + 1], s);
                        s = fmaf(wreg[2], svs[y][x + 2], s);
                        s = fmaf(wreg[3], svs[y + 1][x],     s);
                        s = fmaf(wreg[4], svs[y + 1][x + 1], s);
                        s = fmaf(wreg[5], svs[y + 1][x + 2], s);
                        s = fmaf(wreg[6], svs[y + 2][x],     s);
                        s = fmaf(wreg[7], svs[y + 2][x + 1], s);
                        s = fmaf(wreg[8], svs[y + 2][x + 2], s);
                        outd[e] = fmaf(acc2[n][r], svs[y + 1][x + 1], s);
                    } else {
                        outd[e] = acc2[n][r];     // pure store (vres), combine adds xattn
                    }
                }
            }
        }
    }
}

// ---------------------------------------------------------------------------
// Fused dual-GEMM (bias epilogue). Weight/bias rows: local o0; output rows:
// oY = o0 + sel*oOffset.
// ---------------------------------------------------------------------------
__global__ __launch_bounds__(256)
void gemm_fused(const float* __restrict__ W0, const float* __restrict__ W1,
                const float* __restrict__ X0, const float* __restrict__ X1,
                const float* __restrict__ b0, const float* __restrict__ b1,
                float* __restrict__ Y0, float* __restrict__ Y1,
                int oHalf, int CI, long xbs, long ybs, int oOffset)
{
    const int b  = blockIdx.z;
    const int sel = blockIdx.y >= oHalf;
    const int o0 = (sel ? blockIdx.y - oHalf : blockIdx.y) * 64;   // weight/bias row base
    const int oY = o0 + (sel ? oOffset : 0);                       // output row base
    const int n0 = blockIdx.x * 128;
    const float* Wm = sel ? W1 : W0;
    const float* bias = sel ? b1 : b0;
    const float* Xb = (sel ? X1 : X0) + (long)b * xbs;
    float* Yb = (sel ? Y1 : Y0) + (long)b * ybs;

    __shared__ __align__(16) unsigned short Wt[64][40];
    __shared__ __align__(16) unsigned short Xt[128][40];

    const int tid = threadIdx.x;
    const int wave = tid >> 6, lane = tid & 63;
    const int ln = lane & 15, qd = lane >> 4;
    const int wy = wave >> 1, wx = wave & 1;

    const int ow = tid >> 2, kcw = tid & 3;
    const int nx = tid & 127, kcx = tid >> 7;
    const bool xvalid = (n0 + nx) < kN;

    float4v acc[2][4];
#pragma unroll
    for (int i = 0; i < 2; ++i)
#pragma unroll
        for (int j = 0; j < 4; ++j) acc[i][j] = (float4v){0.f, 0.f, 0.f, 0.f};

    float wpre[8], xpre[16];
    {
        const float* ws = Wm + (long)(o0 + ow) * CI + kcw * 8;
        *(float4*)&wpre[0] = *(const float4*)ws;
        *(float4*)&wpre[4] = *(const float4*)(ws + 4);
#pragma unroll
        for (int j = 0; j < 16; ++j)
            xpre[j] = xvalid ? Xb[(long)(kcx * 16 + j) * kN + n0 + nx] : 0.f;
    }

    for (int k0 = 0; k0 < CI; k0 += 32) {
        *(uint4*)&Wt[ow][kcw * 8]      = pk8(wpre);
        *(uint4*)&Xt[nx][kcx * 16]     = pk8(xpre);
        *(uint4*)&Xt[nx][kcx * 16 + 8] = pk8(xpre + 8);
        __syncthreads();

        if (k0 + 32 < CI) {
            const float* ws = Wm + (long)(o0 + ow) * CI + k0 + 32 + kcw * 8;
            *(float4*)&wpre[0] = *(const float4*)ws;
            *(float4*)&wpre[4] = *(const float4*)(ws + 4);
#pragma unroll
            for (int j = 0; j < 16; ++j)
                xpre[j] = xvalid ? Xb[(long)(k0 + 32 + kcx * 16 + j) * kN + n0 + nx] : 0.f;
        }

        Frag af[2], bf4[4];
#pragma unroll
        for (int mt = 0; mt < 2; ++mt)
            af[mt].u4 = *(const uint4*)&Wt[wy * 32 + mt * 16 + ln][qd * 8];
#pragma unroll
        for (int nt = 0; nt < 4; ++nt)
            bf4[nt].u4 = *(const uint4*)&Xt[wx * 64 + nt * 16 + ln][qd * 8];
#pragma unroll
        for (int mt = 0; mt < 2; ++mt)
#pragma unroll
            for (int nt = 0; nt < 4; ++nt)
                acc[mt][nt] = __builtin_amdgcn_mfma_f32_16x16x32_bf16(
                    af[mt].s, bf4[nt].s, acc[mt][nt], 0, 0, 0);
        __syncthreads();
    }

#pragma unroll
    for (int mt = 0; mt < 2; ++mt) {
        const int obL = o0 + wy * 32 + mt * 16 + qd * 4;   // bias row
        const int obY = oY + wy * 32 + mt * 16 + qd * 4;   // output row
#pragma unroll
        for (int nt = 0; nt < 4; ++nt) {
            const int n = n0 + wx * 64 + nt * 16 + ln;
            if (n < kN) {
#pragma unroll
                for (int r = 0; r < 4; ++r) {
                    float v = acc[mt][nt][r];
                    if (bias) v += bias[obL + r];
                    Yb[(long)(obY + r) * kN + n] = v;
                }
            }
        }
    }
}

// ---------------------------------------------------------------------------
// BN+ReLU GEMM for the gate hidden layer (CI=512)
// ---------------------------------------------------------------------------
__global__ __launch_bounds__(256)
void gemm_bn_kernel(const float* __restrict__ Wm, const float* __restrict__ X,
                    const float* __restrict__ gamma, const float* __restrict__ beta,
                    float* __restrict__ Y, int CI, long xbs, long ybs)
{
    const int b  = blockIdx.z;
    const int o0 = blockIdx.y * 64;
    const int n0 = blockIdx.x * 128;
    const float* Xb = X + (long)b * xbs;
    float* Yb = Y + (long)b * ybs;

    __shared__ __align__(16) unsigned short Wt[64][40];
    __shared__ __align__(16) unsigned short Xt[128][40];

    const int tid = threadIdx.x;
    const int wave = tid >> 6, lane = tid & 63;
    const int ln = lane & 15, qd = lane >> 4;
    const int wy = wave >> 1, wx = wave & 1;

    const int ow = tid >> 2, kcw = tid & 3;
    const int nx = tid & 127, kcx = tid >> 7;
    const bool xvalid = (n0 + nx) < kN;

    float4v acc[2][4];
#pragma unroll
    for (int i = 0; i < 2; ++i)
#pragma unroll
        for (int j = 0; j < 4; ++j) acc[i][j] = (float4v){0.f, 0.f, 0.f, 0.f};

    float wpre[8], xpre[16];
    {
        const float* ws = Wm + (long)(o0 + ow) * CI + kcw * 8;
        *(float4*)&wpre[0] = *(const float4*)ws;
        *(float4*)&wpre[4] = *(const float4*)(ws + 4);
#pragma unroll
        for (int j = 0; j < 16; ++j)
            xpre[j] = xvalid ? Xb[(long)(kcx * 16 + j) * kN + n0 + nx] : 0.f;
    }

    for (int k0 = 0; k0 < CI; k0 += 32) {
        *(uint4*)&Wt[ow][kcw * 8]      = pk8(wpre);
        *(uint4*)&Xt[nx][kcx * 16]     = pk8(xpre);
        *(uint4*)&Xt[nx][kcx * 16 + 8] = pk8(xpre + 8);
        __syncthreads();

        if (k0 + 32 < CI) {
            const float* ws = Wm + (long)(o0 + ow) * CI + k0 + 32 + kcw * 8;
            *(float4*)&wpre[0] = *(const float4*)ws;
            *(float4*)&wpre[4] = *(const float4*)(ws + 4);
#pragma unroll
            for (int j = 0; j < 16; ++j)
                xpre[j] = xvalid ? Xb[(long)(k0 + 32 + kcx * 16 + j) * kN + n0 + nx] : 0.f;
        }

        Frag af[2], bf4[4];
#pragma unroll
        for (int mt = 0; mt < 2; ++mt)
            af[mt].u4 = *(const uint4*)&Wt[wy * 32 + mt * 16 + ln][qd * 8];
#pragma unroll
        for (int nt = 0; nt < 4; ++nt)
            bf4[nt].u4 = *(const uint4*)&Xt[wx * 64 + nt * 16 + ln][qd * 8];
#pragma unroll
        for (int mt = 0; mt < 2; ++mt)
#pragma unroll
            for (int nt = 0; nt < 4; ++nt)
                acc[mt][nt] = __builtin_amdgcn_mfma_f32_16x16x32_bf16(
                    af[mt].s, bf4[nt].s, acc[mt][nt], 0, 0, 0);
        __syncthreads();
    }

    const float rs = rsqrtf(1.0f + 1e-5f);
#pragma unroll
    for (int mt = 0; mt < 2; ++mt) {
        const int ob = o0 + wy * 32 + mt * 16 + qd * 4;
#pragma unroll
        for (int nt = 0; nt < 4; ++nt) {
            const int n = n0 + wx * 64 + nt * 16 + ln;
            if (n < kN) {
#pragma unroll
                for (int r = 0; r < 4; ++r) {
                    const int o = ob + r;
                    float v = fmaxf(fmaf(acc[mt][nt][r], gamma[o] * rs, beta[o]), 0.f);
                    Yb[(long)o * kN + n] = v;
                }
            }
        }
    }
}

// ---------------------------------------------------------------------------
// Token attention, k-split x4, software-pipelined:
//   W_{i+1} (S-MFMA + exp + pack) computed BETWEEN the LDS write of P_i and
//   its read, hiding the lgkm latency; ka prefetched one full iter ahead.
// __launch_bounds__(256,4) caps regs at 128/wave for 4 waves/SIMD residency.
// ---------------------------------------------------------------------------
__global__ __launch_bounds__(256, 4)
void attn_mfma_kernel(const float* __restrict__ tq,
                      const unsigned short* __restrict__ Kp,
                      const unsigned short* __restrict__ Vp,
                      float* __restrict__ Op, float* __restrict__ lp)
{
    const int b = blockIdx.z >> 2, sp = blockIdx.z & 3;
    const int h = blockIdx.y;
    const int q0 = blockIdx.x * 128;
    const int tid = threadIdx.x;
    const int wave = tid >> 6, lane = tid & 63;
    const int qd = lane >> 4, ln = lane & 15;
    const int i0 = (sp == 0) ? 0 : (12 * sp + 1);
    const int i1 = 12 * sp + 13;

    const float* qb = tq + (long)b * kCN + (long)h * kHD * kN;
    const unsigned short* KpB = Kp + (long)(b * 8 + h) * 196 * 512 + ln * 32 + qd * 8;
    const unsigned short* VpB = Vp + (long)(b * 8 + h) * 49 * 2048 + ln * 32 + qd * 8;

    __shared__ __align__(16) unsigned short Ps[4][32 * 40];
    unsigned short* PsW = Ps[wave];

    const float qscale = kAttScale * kLog2e;
    Frag qf[2];
#pragma unroll
    for (int qt = 0; qt < 2; ++qt) {
        int qg = q0 + wave * 32 + qt * 16 + ln;
        bool qv = qg < kN;
#pragma unroll
        for (int j = 0; j < 8; ++j) {
            int d = qd * 8 + j;
            float v = qv ? qb[(long)d * kN + qg] * qscale : 0.f;
            qf[qt].u[j] = f2b(v);
        }
    }

    float4v o[2][2];
#pragma unroll
    for (int qt = 0; qt < 2; ++qt)
#pragma unroll
        for (int dh = 0; dh < 2; ++dh) o[qt][dh] = (float4v){0.f, 0.f, 0.f, 0.f};
    float lsum[2] = {0.f, 0.f};

    unsigned W[4][2][2];
    Frag ka[4];
#pragma unroll
    for (int m = 0; m < 4; ++m)
        ka[m].u4 = *(const uint4*)(KpB + (long)(4 * i0 + m) * 512);

    // S-MFMA + exp + pack for the tile currently in ka -> W (per-m lifetimes)
    auto computeW = [&]() {
#pragma unroll
        for (int m = 0; m < 4; ++m) {
            float4v s0 = __builtin_amdgcn_mfma_f32_16x16x32_bf16(
                ka[m].s, qf[0].s, (float4v){0.f, 0.f, 0.f, 0.f}, 0, 0, 0);
            float4v s1 = __builtin_amdgcn_mfma_f32_16x16x32_bf16(
                ka[m].s, qf[1].s, (float4v){0.f, 0.f, 0.f, 0.f}, 0, 0, 0);
            float a0 = __builtin_amdgcn_exp2f(s0[0]);
            float a1 = __builtin_amdgcn_exp2f(s0[1]);
            float a2 = __builtin_amdgcn_exp2f(s0[2]);
            float a3 = __builtin_amdgcn_exp2f(s0[3]);
            lsum[0] += (a0 + a1) + (a2 + a3);
            W[m][0][0] = pk_trunc(a0, a1);
            W[m][0][1] = pk_trunc(a2, a3);
            float b0 = __builtin_amdgcn_exp2f(s1[0]);
            float b1 = __builtin_amdgcn_exp2f(s1[1]);
            float b2 = __builtin_amdgcn_exp2f(s1[2]);
            float b3 = __builtin_amdgcn_exp2f(s1[3]);
            lsum[1] += (b0 + b1) + (b2 + b3);
            W[m][1][0] = pk_trunc(b0, b1);
            W[m][1][1] = pk_trunc(b2, b3);
        }
    };

    computeW();                    // W = W_{i0}
    if (i0 + 1 < i1) {
#pragma unroll
        for (int m = 0; m < 4; ++m)
            ka[m].u4 = *(const uint4*)(KpB + (long)(4 * (i0 + 1) + m) * 512);
    }

    for (int i = i0; i < i1; ++i) {
        // V fragments for this tile (global, L2-hot) — issue early
        Frag va[2][2];
#pragma unroll
        for (int g = 0; g < 2; ++g)
#pragma unroll
            for (int dh = 0; dh < 2; ++dh)
                va[g][dh].u4 = *(const uint4*)(VpB + (long)i * 2048 + (g * 2 + dh) * 512);

        // write P_i to per-wave LDS
#pragma unroll
        for (int m = 0; m < 4; ++m)
#pragma unroll
            for (int qt = 0; qt < 2; ++qt)
                *(uint2*)&PsW[(qt * 16 + ln) * 40 + m * 16 + qd * 4] =
                    make_uint2(W[m][qt][0], W[m][qt][1]);

        // middle phase: S_{i+1} + exp + pack (hides the LDS write->read latency)
        if (i + 1 < i1) {
            computeW();            // uses ka = frags(i+1), loaded one iter ago
            if (i + 2 < i1) {
#pragma unroll
                for (int m = 0; m < 4; ++m)
                    ka[m].u4 = *(const uint4*)(KpB + (long)(4 * (i + 2) + m) * 512);
            }
        }

        // read P_i, PV MFMAs
#pragma unroll
        for (int g = 0; g < 2; ++g) {
            Frag pa[2];
#pragma unroll
            for (int qt = 0; qt < 2; ++qt)
                pa[qt].u4 = *(const uint4*)&PsW[(qt * 16 + ln) * 40 + g * 32 + qd * 8];
#pragma unroll
            for (int qt = 0; qt < 2; ++qt)
#pragma unroll
                for (int dh = 0; dh < 2; ++dh)
                    o[qt][dh] = __builtin_amdgcn_mfma_f32_16x16x32_bf16(
                        pa[qt].s, va[g][dh].s, o[qt][dh], 0, 0, 0);
        }
    }

    const long grp = (long)(sp * 16 + b * 8 + h);
#pragma unroll
    for (int qt = 0; qt < 2; ++qt) {
        lsum[qt] += __shfl_xor(lsum[qt], 16, 64);
        lsum[qt] += __shfl_xor(lsum[qt], 32, 64);
        if (qd == 0)
            lp[grp * 3200 + q0 + wave * 32 + qt * 16 + ln] = lsum[qt];
#pragma unroll
        for (int dh = 0; dh < 2; ++dh)
#pragma unroll
            for (int r = 0; r < 4; ++r) {
                int q = q0 + wave * 32 + qt * 16 + qd * 4 + r;
                Op[(grp * 3200 + q) * 32 + dh * 16 + ln] = o[qt][dh][r];
            }
    }
}

// ---------------------------------------------------------------------------
// Combine 4 k-split partials, normalize, transpose, ADD into xo (holds vres).
// ---------------------------------------------------------------------------
__global__ __launch_bounds__(256)
void attn_combine_kernel(const float* __restrict__ Op, const float* __restrict__ lp,
                         float* __restrict__ xo)
{
    const int qc = blockIdx.x, bh = blockIdx.y;
    const int b = bh >> 3, h = bh & 7;
    const int q0 = qc * 64;
    __shared__ float T[32][65];
    const int tid = threadIdx.x;

    for (int i = tid; i < 64 * 32; i += 256) {
        int ql = i >> 5, d = i & 31;
        float ov = 0.f, l = 0.f;
#pragma unroll
        for (int s = 0; s < 4; ++s) {
            long g = (long)(s * 16 + bh);
            ov += Op[(g * 3200 + q0 + ql) * 32 + d];
            l  += lp[g * 3200 + q0 + ql];
        }
        T[d][ql] = ov / l;
    }
    __syncthreads();
    for (int i = tid; i < 32 * 64; i += 256) {
        int d = i >> 6, ql = i & 63;
        xo[(long)b * kCN + (long)(h * kHD + d) * kN + q0 + ql] += T[d][ql];
    }
}

// ---------------------------------------------------------------------------
// Fused gate + blend. Block = (64 pixels, batch). Gate dot via 4 c-groups +
// LDS reduce, then blend all 256 channels for those pixels.
// ---------------------------------------------------------------------------
__global__ __launch_bounds__(256)
void gateblend_kernel(const float* __restrict__ hbuf, const float* __restrict__ w2,
                      const float* __restrict__ b2, const float* __restrict__ gcat,
                      float* __restrict__ out)
{
    const int n0 = blockIdx.x * 64;
    const int b = blockIdx.y;
    const int lane = threadIdx.x & 63;
    const int g = threadIdx.x >> 6;
    const float* hb = hbuf + (long)b * kCN + n0 + lane;
    float s = 0.f;
#pragma unroll 8
    for (int c = g * 64; c < g * 64 + 64; ++c)
        s = fmaf(w2[c], hb[(long)c * kN], s);
    __shared__ float red[4][64];
    __shared__ float sgate[64];
    red[g][lane] = s;
    __syncthreads();
    if (g == 0) {
        float t = red[0][lane] + red[1][lane] + red[2][lane] + red[3][lane];
        sgate[lane] = 1.f / (1.f + __expf(-(t + b2[0])));
    }
    __syncthreads();
    const float gt = sgate[lane];
    const float* osp = gcat + (long)b * 2 * kCN + n0 + lane;
    const float* otp = osp + kCN;
    float* op = out + (long)b * kCN + n0 + lane;
    for (int c = g; c < kC; c += 4) {
        float os = osp[(long)c * kN];
        float ot = otp[(long)c * kN];
        op[(long)c * kN] = gt * os + (1.f - gt) * ot;
    }
}

// ---------------------------------------------------------------------------
extern "C" void kernel_launch(void* const* d_in, const int* in_sizes, int n_in,
                              void* d_out, int out_size, void* d_ws, size_t ws_size,
                              hipStream_t stream)
{
    const float* x      = (const float*)d_in[0];
    const float* ctx    = (const float*)d_in[1];
    const float* s_q_w  = (const float*)d_in[2];
    const float* s_kv_w = (const float*)d_in[3];
    const float* s_p_w  = (const float*)d_in[4];
    const float* s_p_b  = (const float*)d_in[5];
    const float* s_dw_w = (const float*)d_in[6];
    const float* s_dw_b = (const float*)d_in[7];
    const float* t_q_w  = (const float*)d_in[8];
    const float* t_kv_w = (const float*)d_in[9];
    const float* t_p_w  = (const float*)d_in[10];
    const float* t_p_b  = (const float*)d_in[11];
    const float* t_cw   = (const float*)d_in[12];
    const float* g_w1   = (const float*)d_in[13];
    const float* g_bn_g = (const float*)d_in[14];
    const float* g_bn_b = (const float*)d_in[15];
    const float* g_w2   = (const float*)d_in[16];
    const float* g_b2   = (const float*)d_in[17];
    float* out = (float*)d_out;

    float* ws = (float*)d_ws;
    const long SPEC2 = (long)kB * kC * kSpec * 2;
    float* sq   = ws;                    // B*C*N   (sq -> vres -> tpre)
    float* skv  = sq   + kB * kCN;       // B*2C*N
    float* tq   = skv  + kB * 2 * kCN;   // B*C*N
    float* tkv  = tq   + kB * kCN;       // B*2C*N  (later: h)
    float* vloc = tkv  + kB * 2 * kCN;   // B*C*N   (spre result)
    float* fQ   = vloc + kB * kCN;
    float* fK   = fQ   + SPEC2;
    float* fV   = fK   + SPEC2;
    float* gcat = fV   + SPEC2;          // B*2C*N : [os ; ot]
    float* gate = gcat + kB * 2 * kCN;   // B*N (unused slot, kept for layout)
    unsigned short* tw = (unsigned short*)(gate + kB * kN);  // twiddles
    unsigned short* Kp = tw + TWTOT;                         // 16*196*512 u16
    unsigned short* Vp = Kp + (long)16 * 196 * 512;          // 16*49*2048 u16
    float* Opart = (float*)(Vp + (long)16 * 49 * 2048);      // 64*3200*32 f32
    float* lpart = Opart + (long)64 * 3200 * 32;             // 64*3200 f32

    dim3 blk(256, 1, 1);

    twiddle_init_kernel<<<dim3(TWTOT / 256), blk, 0, stream>>>(tw);

    // q projections (both branches share input x); kv projections (share ctx)
    gemm_fused<<<dim3(25, 8, kB), blk, 0, stream>>>(
        s_q_w, t_q_w, x, x, nullptr, nullptr, sq, tq, 4, kC, kCN, kCN, 0);
    gemm_fused<<<dim3(25, 16, kB), blk, 0, stream>>>(
        s_kv_w, t_kv_w, ctx, ctx, nullptr, nullptr, skv, tkv, 8, kC, kCN, 2 * kCN, 0);

    // three forward DFTs + attention K/V prepack, one dispatch (2320 blocks)
    fwd3_prepack_kernel<<<dim3(3 * kB * kC + kB * kNH * 49), blk, 0, stream>>>(
        sq, skv, tkv + kCN, fQ, fK, fV, tw, tkv, Kp, Vp);

    // both inverse DFTs in one dispatch:
    //   unit0: vloc = dwconv3(sv) + irfft(fQ*fK)*sv ; unit1: sq = irfft(fV*cw)
    dft_inv_mfma2<<<dim3(2 * kB * kC), blk, 0, stream>>>(
        fQ, fK, fV, t_cw, vloc, sq, skv, s_dw_w, s_dw_b, tw);

    attn_mfma_kernel<<<dim3(25, kNH, 4 * kB), blk, 0, stream>>>(tq, Kp, Vp, Opart, lpart);
    attn_combine_kernel<<<dim3(49, 16), blk, 0, stream>>>(Opart, lpart, sq);  // sq += xattn

    // both output projections (different inputs) in one dispatch -> gcat
    gemm_fused<<<dim3(25, 8, kB), blk, 0, stream>>>(
        s_p_w, t_p_w, vloc, sq, s_p_b, t_p_b, gcat, gcat, 4, kC, kCN, 2 * kCN, 256);

    gemm_bn_kernel<<<dim3(25, 4, kB), blk, 0, stream>>>(g_w1, gcat, g_bn_g, g_bn_b, tkv, 2 * kC, 2 * kCN, kCN); // h
    gateblend_kernel<<<dim3(49, kB), blk, 0, stream>>>(tkv, g_w2, g_b2, gcat, out);
}

// Round 11
// 280.355 us; speedup vs baseline: 4.8006x; 1.0040x over previous
//
#include <hip/hip_runtime.h>

namespace {
constexpr int kB = 2;
constexpr int kC = 256;
constexpr int kH = 56;
constexpr int kW = 56;
constexpr int kN = kH * kW;        // 3136
constexpr int kNH = 8;
constexpr int kHD = 32;
constexpr int kNF = kW / 2 + 1;    // 29
constexpr int kSpec = kH * kNF;    // 1624
constexpr long kCN = (long)kC * kN;        // 802816
constexpr float kAttScale = 0.17677669529663687f;   // 32^-0.5
constexpr float kLog2e = 1.4426950408889634f;
constexpr float kAng = 6.283185307179586f / 56.0f;  // 2*pi/56
// twiddle table offsets in u16 units
constexpr int TW1F = 0;            // [128][64]
constexpr int TW2F = 8192;         // [64][64]
constexpr int TW1I = 12288;        // [128][64]
constexpr int TW2I = 20480;        // [64][64]
constexpr int TWTOT = 24576;
}

typedef __attribute__((ext_vector_type(8))) short short8;
typedef __attribute__((ext_vector_type(4))) float float4v;

union Frag {
    short8 s;
    unsigned short u[8];
    uint2 u2[2];
    uint4 u4;
};

__device__ __forceinline__ unsigned short f2b(float f) {
    unsigned u = __float_as_uint(f);
    return (unsigned short)((u + 0x7FFFu + ((u >> 16) & 1u)) >> 16);
}
__device__ __forceinline__ float b2f(unsigned short u) {
    return __uint_as_float((unsigned)u << 16);
}
__device__ __forceinline__ unsigned f2b_pk(float a, float b) {
    unsigned ua = __float_as_uint(a); ua = (ua + 0x7FFFu + ((ua >> 16) & 1u)) >> 16;
    unsigned ub = __float_as_uint(b); ub = (ub + 0x7FFFu + ((ub >> 16) & 1u)) >> 16;
    return ua | (ub << 16);
}
__device__ __forceinline__ unsigned pk_trunc(float a, float b) {
    return (__float_as_uint(a) >> 16) | (__float_as_uint(b) & 0xFFFF0000u);
}
__device__ __forceinline__ uint4 pk8(const float* v) {
    return make_uint4(f2b_pk(v[0], v[1]), f2b_pk(v[2], v[3]),
                      f2b_pk(v[4], v[5]), f2b_pk(v[6], v[7]));
}

// ---------------------------------------------------------------------------
// Twiddle tables (bf16), built fresh every launch into d_ws.
// ---------------------------------------------------------------------------
__global__ __launch_bounds__(256)
void twiddle_init_kernel(unsigned short* __restrict__ tw)
{
    int idx = blockIdx.x * 256 + threadIdx.x;
    if (idx >= TWTOT) return;
    float val = 0.f;
    if (idx < TW2F) {                       // TW1F
        int r = idx >> 6, c = idx & 63;
        if (c < 56) {
            if (r < 56)       val = cosf(kAng * (float)((r * c) % 56));
            else if (r < 112) val = sinf(kAng * (float)(((r - 56) * c) % 56));
        }
    } else if (idx < TW1I) {                // TW2F
        int t = idx - TW2F; int r = t >> 6, c = t & 63;
        if (c < 56) {
            if (r < 29)                  val = cosf(kAng * (float)((r * c) % 56));
            else if (r >= 32 && r < 61)  val = sinf(kAng * (float)(((r - 32) * c) % 56));
        }
    } else if (idx < TW2I) {                // TW1I
        int t = idx - TW1I; int r = t >> 6, c = t & 63;
        if (c < 56) {
            if (r < 56)                  val = cosf(kAng * (float)((r * c) % 56));
            else if (r >= 64 && r < 120) val = sinf(kAng * (float)(((r - 64) * c) % 56));
        }
    } else {                                // TW2I
        int t = idx - TW2I; int x = t >> 6, c = t & 63;
        if (x < 56 && c < 58) {
            int v = c >> 1;
            float wv = ((v == 0) || (v == 28)) ? 1.f : 2.f;
            float a = kAng * (float)((v * x) % 56);
            val = (c & 1) ? (-wv * sinf(a)) : (wv * cosf(a));
        }
    }
    tw[idx] = f2b(val);
}

// ---------------------------------------------------------------------------
// Forward 2D DFT body (one channel image per block). Yb stored bf16 to cut
// LDS 48128 -> 33280 (3 -> 4 blocks/CU).
// ---------------------------------------------------------------------------
__device__ void dft_fwd_body(char* smem, int bx,
                             const float* __restrict__ s0, const float* __restrict__ s1,
                             const float* __restrict__ s2, float* __restrict__ d0,
                             float* __restrict__ d1, float* __restrict__ d2,
                             const unsigned short* __restrict__ tw)
{
    const int which = bx >> 9, ch = bx & 511;
    const int b = ch >> 8, c = ch & 255;
    const float* src; long stride; float* spec;
    if (which == 0)      { src = s0; stride = kCN;     spec = d0; }
    else if (which == 1) { src = s1; stride = 2 * kCN; spec = d1; }
    else                 { src = s2; stride = 2 * kCN; spec = d2; }
    const float* img = src + (long)b * stride + (long)c * kN;

    unsigned short (*Gb)[72]    = (unsigned short(*)[72])smem;            // 18432
    unsigned short (*imgT)[72]  = (unsigned short(*)[72])(smem + 18432);  // 9216
    unsigned short (*Yb)[116]   = (unsigned short(*)[116])(smem + 18432); // 14848, overlays imgT after F1

    const int tid = threadIdx.x;
    const int wave = tid >> 6, lane = tid & 63;
    const int ln = lane & 15, qd = lane >> 4;

    for (int i = tid; i < 64 * 72; i += 256) {
        int r = i / 72, cc = i - r * 72;
        if (r >= 56 || cc >= 56) imgT[r][cc] = 0;
    }
    for (int i = tid; i < kN; i += 256) {
        int y = i / 56, x = i - y * 56;
        imgT[x][y] = f2b(img[i]);
    }
    __syncthreads();

    float4v acc1[2][4];
#pragma unroll
    for (int m = 0; m < 2; ++m)
#pragma unroll
        for (int n = 0; n < 4; ++n) acc1[m][n] = (float4v){0.f, 0.f, 0.f, 0.f};
#pragma unroll
    for (int ks = 0; ks < 2; ++ks) {
        Frag a[2], bf[4];
#pragma unroll
        for (int m = 0; m < 2; ++m)
            a[m].u4 = *(const uint4*)(tw + TW1F + ((2 * wave + m) * 16 + ln) * 64 + ks * 32 + qd * 8);
#pragma unroll
        for (int n = 0; n < 4; ++n)
            bf[n].u4 = *(const uint4*)&imgT[n * 16 + ln][ks * 32 + qd * 8];
#pragma unroll
        for (int m = 0; m < 2; ++m)
#pragma unroll
            for (int n = 0; n < 4; ++n)
                acc1[m][n] = __builtin_amdgcn_mfma_f32_16x16x32_bf16(a[m].s, bf[n].s, acc1[m][n], 0, 0, 0);
    }
#pragma unroll
    for (int m = 0; m < 2; ++m)
#pragma unroll
        for (int n = 0; n < 4; ++n)
#pragma unroll
            for (int r = 0; r < 4; ++r)
                Gb[(2 * wave + m) * 16 + qd * 4 + r][n * 16 + ln] = f2b(acc1[m][n][r]);
    __syncthreads();

    float4v acc2[7];
#pragma unroll
    for (int n = 0; n < 7; ++n) acc2[n] = (float4v){0.f, 0.f, 0.f, 0.f};
#pragma unroll
    for (int ks = 0; ks < 2; ++ks) {
        Frag a;
        a.u4 = *(const uint4*)(tw + TW2F + (wave * 16 + ln) * 64 + ks * 32 + qd * 8);
#pragma unroll
        for (int n = 0; n < 7; ++n) {
            Frag bb;
            bb.u4 = *(const uint4*)&Gb[n * 16 + ln][ks * 32 + qd * 8];
            acc2[n] = __builtin_amdgcn_mfma_f32_16x16x32_bf16(a.s, bb.s, acc2[n], 0, 0, 0);
        }
    }
#pragma unroll
    for (int n = 0; n < 7; ++n)
#pragma unroll
        for (int r = 0; r < 4; ++r)
            Yb[wave * 16 + qd * 4 + r][n * 16 + ln] = f2b(acc2[n][r]);
    __syncthreads();

    float2* outp = (float2*)spec + (long)ch * kSpec;
    for (int i = tid; i < kSpec; i += 256) {
        int u = i / kNF, v = i - u * kNF;
        float Qr = b2f(Yb[v][u]) - b2f(Yb[32 + v][56 + u]);
        float Qi = -b2f(Yb[32 + v][u]) - b2f(Yb[v][56 + u]);
        outp[i] = make_float2(Qr, Qi);
    }
}

// ---------------------------------------------------------------------------
// Attention K/V prepack body
// ---------------------------------------------------------------------------
__device__ void prepack_body(char* smem, int blk, const float* __restrict__ tkv,
                             unsigned short* __restrict__ Kp,
                             unsigned short* __restrict__ Vp)
{
    const int i = blk % 49;
    const int h = (blk / 49) & 7;
    const int b = blk / (49 * 8);
    const float* kb = tkv + (long)b * 2 * kCN + (long)h * kHD * kN;
    const float* vb = kb + kCN;
    const int tid = threadIdx.x;

    float (*Ks)[72] = (float(*)[72])smem;   // 32*72*4 = 9216 B
#pragma unroll
    for (int j = 0; j < 8; ++j) {
        int e = tid + j * 256;
        int d = e >> 6, c = e & 63;
        Ks[d][c] = kb[(long)d * kN + i * 64 + c];
    }
    __syncthreads();
    {
        int tl = tid >> 6, lnn = (tid >> 2) & 15, qdd = tid & 3;
        float v[8];
#pragma unroll
        for (int j = 0; j < 8; ++j) v[j] = Ks[qdd * 8 + j][tl * 16 + lnn];
        unsigned short* dst = Kp + ((long)(b * 8 + h) * 196 + 4 * i + tl) * 512 + lnn * 32 + qdd * 8;
        *(uint4*)dst = pk8(v);
    }
    {
        int g = tid >> 7, dh = (tid >> 6) & 1, lnn = (tid >> 2) & 15, qdd = tid & 3;
        int d = dh * 16 + lnn;
        const float* src = vb + (long)d * kN + i * 64 + g * 32 + qdd * 8;
        float v[8];
        *(float4*)&v[0] = *(const float4*)src;
        *(float4*)&v[4] = *(const float4*)(src + 4);
        unsigned short* dst = Vp + ((long)(b * 8 + h) * 49 + i) * 2048 + ((g * 2 + dh) * 16 + lnn) * 32 + qdd * 8;
        *(uint4*)dst = pk8(v);
    }
}

// ---------------------------------------------------------------------------
// Merged dispatch: blocks [0,1536) forward DFTs; [1536,2320) K/V prepack.
// ---------------------------------------------------------------------------
__global__ __launch_bounds__(256)
void fwd3_prepack_kernel(const float* __restrict__ s0, const float* __restrict__ s1,
                         const float* __restrict__ s2, float* __restrict__ d0,
                         float* __restrict__ d1, float* __restrict__ d2,
                         const unsigned short* __restrict__ tw,
                         const float* __restrict__ tkv,
                         unsigned short* __restrict__ Kp, unsigned short* __restrict__ Vp)
{
    __shared__ __align__(16) char smem[33280];
    if (blockIdx.x < 1536)
        dft_fwd_body(smem, blockIdx.x, s0, s1, s2, d0, d1, d2, tw);
    else
        prepack_body(smem, blockIdx.x - 1536, tkv, Kp, Vp);
}

// ---------------------------------------------------------------------------
// Inverse 2D DFT via MFMA, both branches in one dispatch (1024 blocks).
// Yb stored bf16: LDS 41984 -> 27648 (3 -> 5 blocks/CU).
// unit 0 (spectral): P = fQ*fK * s1; epilogue dst1 = dwconv3(sv) + acc*sv
// unit 1 (token):    P = fV*cw[c] * s2; epilogue dst2 = acc (pure store)
// ---------------------------------------------------------------------------
__global__ __launch_bounds__(256)
void dft_inv_mfma2(const float* __restrict__ fQ, const float* __restrict__ fK,
                   const float* __restrict__ fV, const float* __restrict__ cw,
                   float* __restrict__ dst1, float* __restrict__ dst2,
                   const float* __restrict__ skvp, const float* __restrict__ dww,
                   const float* __restrict__ dwb, const unsigned short* __restrict__ tw)
{
    const int unit = blockIdx.x >> 9;
    const int ch = blockIdx.x & 511;
    const int b = ch >> 8, c = ch & 255;
    __shared__ __align__(16) char smem[27648];
    unsigned short (*Pb)[72]  = (unsigned short(*)[72])smem;           // 9216
    unsigned short (*Yb)[72]  = (unsigned short(*)[72])(smem + 9216);  // 18432 (128 rows)
    unsigned short (*T2)[72]  = (unsigned short(*)[72])smem;           // overlays Pb after I1
    float (*svs)[65]          = (float(*)[65])(smem + 9216);           // overlays Yb after T2 built

    const int tid = threadIdx.x;
    const int wave = tid >> 6, lane = tid & 63;
    const int ln = lane & 15, qd = lane >> 4;

    const float2* Pin; const float2* Min; float scale; float* dst;
    if (unit == 0) {
        Pin = (const float2*)fQ + (long)ch * kSpec;
        Min = (const float2*)fK + (long)ch * kSpec;
        scale = 1.0f / 175616.0f; dst = dst1;
    } else {
        Pin = (const float2*)fV + (long)ch * kSpec;
        Min = (const float2*)cw + (long)c * kSpec;
        scale = 1.0f / 3136.0f; dst = dst2;
    }

    for (int i = tid; i < 64 * 72; i += 256) {
        int r = i / 72, cc = i - r * 72;
        if (r >= 58 || cc >= 56) Pb[r][cc] = 0;
    }
    for (int i = tid; i < kSpec; i += 256) {
        int u = i / kNF, v = i - u * kNF;
        float2 p = Pin[i];
        float2 m = Min[i];
        float pr = (p.x * m.x - p.y * m.y) * scale;
        float pi = (p.x * m.y + p.y * m.x) * scale;
        Pb[2 * v][u]     = f2b(pr);
        Pb[2 * v + 1][u] = f2b(pi);
    }
    __syncthreads();

    float4v acc1[2][4];
#pragma unroll
    for (int m = 0; m < 2; ++m)
#pragma unroll
        for (int n = 0; n < 4; ++n) acc1[m][n] = (float4v){0.f, 0.f, 0.f, 0.f};
#pragma unroll
    for (int ks = 0; ks < 2; ++ks) {
        Frag a[2], bf[4];
#pragma unroll
        for (int m = 0; m < 2; ++m)
            a[m].u4 = *(const uint4*)(tw + TW1I + ((2 * wave + m) * 16 + ln) * 64 + ks * 32 + qd * 8);
#pragma unroll
        for (int n = 0; n < 4; ++n)
            bf[n].u4 = *(const uint4*)&Pb[n * 16 + ln][ks * 32 + qd * 8];
#pragma unroll
        for (int m = 0; m < 2; ++m)
#pragma unroll
            for (int n = 0; n < 4; ++n)
                acc1[m][n] = __builtin_amdgcn_mfma_f32_16x16x32_bf16(a[m].s, bf[n].s, acc1[m][n], 0, 0, 0);
    }
#pragma unroll
    for (int m = 0; m < 2; ++m)
#pragma unroll
        for (int n = 0; n < 4; ++n)
#pragma unroll
            for (int r = 0; r < 4; ++r)
                Yb[(2 * wave + m) * 16 + qd * 4 + r][n * 16 + ln] = f2b(acc1[m][n][r]);
    __syncthreads();

    for (int i = tid; i < 64 * 72; i += 256) {
        int r = i / 72, cc = i - r * 72;
        if (r >= 56 || cc >= 58) T2[r][cc] = 0;
    }
    __syncthreads();
    for (int i = tid; i < 56 * kNF; i += 256) {
        int y = i / kNF, v = i - y * kNF;
        float Tr = b2f(Yb[y][2 * v])     - b2f(Yb[64 + y][2 * v + 1]);
        float Ti = b2f(Yb[y][2 * v + 1]) + b2f(Yb[64 + y][2 * v]);
        T2[y][2 * v]     = f2b(Tr);
        T2[y][2 * v + 1] = f2b(Ti);
    }
    __syncthreads();   // Yb dead from here; svs region free

    float wreg[9]; float bias = 0.f;
    if (unit == 0) {
        const float* svp = skvp + (long)b * 2 * kCN + kCN + (long)c * kN;
        for (int i = tid; i < 58 * 65; i += 256) {
            int y = i / 65, x = i - y * 65;
            if (y == 0 || y == 57 || x == 0 || x >= 57) ((float*)svs)[i] = 0.f;
        }
        for (int i = tid; i < kN; i += 256) {
            int y = i / 56, x = i - y * 56;
            svs[y + 1][x + 1] = svp[i];
        }
#pragma unroll
        for (int j = 0; j < 9; ++j) wreg[j] = dww[c * 9 + j];
        bias = dwb[c];
    }

    float4v acc2[4];
#pragma unroll
    for (int n = 0; n < 4; ++n) acc2[n] = (float4v){0.f, 0.f, 0.f, 0.f};
#pragma unroll
    for (int ks = 0; ks < 2; ++ks) {
        Frag a;
        a.u4 = *(const uint4*)(tw + TW2I + (wave * 16 + ln) * 64 + ks * 32 + qd * 8);
#pragma unroll
        for (int n = 0; n < 4; ++n) {
            Frag bb;
            bb.u4 = *(const uint4*)&T2[n * 16 + ln][ks * 32 + qd * 8];
            acc2[n] = __builtin_amdgcn_mfma_f32_16x16x32_bf16(a.s, bb.s, acc2[n], 0, 0, 0);
        }
    }
    __syncthreads();   // svs visible to all

    float* outd = dst + (long)ch * kN;
#pragma unroll
    for (int n = 0; n < 4; ++n) {
        int y = n * 16 + ln;
        if (y < 56) {
#pragma unroll
            for (int r = 0; r < 4; ++r) {
                int x = wave * 16 + qd * 4 + r;
                if (x < 56) {
                    int e = y * 56 + x;
                    if (unit == 0) {
                        float s = bias;
                        s = fmaf(wreg[0], svs[y][x],     s);
                        s = fmaf(wreg[1], svs[y][x + 1], s);
                        s = fmaf(wreg[2], svs[y][x + 2], s);
                        s = fmaf(wreg[3], svs[y + 1][x],     s);
                        s = fmaf(wreg[4], svs[y + 1][x + 1], s);
                        s = fmaf(wreg[5], svs[y + 1][x + 2], s);
                        s = fmaf(wreg[6], svs[y + 2][x],     s);
                        s = fmaf(wreg[7], svs[y + 2][x + 1], s);
                        s = fmaf(wreg[8], svs[y + 2][x + 2], s);
                        outd[e] = fmaf(acc2[n][r], svs[y + 1][x + 1], s);
                    } else {
                        outd[e] = acc2[n][r];     // pure store (vres), combine adds xattn
                    }
                }
            }
        }
    }
}

// ---------------------------------------------------------------------------
// Fused dual-GEMM (bias epilogue). Weight/bias rows: local o0; output rows:
// oY = o0 + sel*oOffset.
// ---------------------------------------------------------------------------
__global__ __launch_bounds__(256)
void gemm_fused(const float* __restrict__ W0, const float* __restrict__ W1,
                const float* __restrict__ X0, const float* __restrict__ X1,
                const float* __restrict__ b0, const float* __restrict__ b1,
                float* __restrict__ Y0, float* __restrict__ Y1,
                int oHalf, int CI, long xbs, long ybs, int oOffset)
{
    const int b  = blockIdx.z;
    const int sel = blockIdx.y >= oHalf;
    const int o0 = (sel ? blockIdx.y - oHalf : blockIdx.y) * 64;   // weight/bias row base
    const int oY = o0 + (sel ? oOffset : 0);                       // output row base
    const int n0 = blockIdx.x * 128;
    const float* Wm = sel ? W1 : W0;
    const float* bias = sel ? b1 : b0;
    const float* Xb = (sel ? X1 : X0) + (long)b * xbs;
    float* Yb = (sel ? Y1 : Y0) + (long)b * ybs;

    __shared__ __align__(16) unsigned short Wt[64][40];
    __shared__ __align__(16) unsigned short Xt[128][40];

    const int tid = threadIdx.x;
    const int wave = tid >> 6, lane = tid & 63;
    const int ln = lane & 15, qd = lane >> 4;
    const int wy = wave >> 1, wx = wave & 1;

    const int ow = tid >> 2, kcw = tid & 3;
    const int nx = tid & 127, kcx = tid >> 7;
    const bool xvalid = (n0 + nx) < kN;

    float4v acc[2][4];
#pragma unroll
    for (int i = 0; i < 2; ++i)
#pragma unroll
        for (int j = 0; j < 4; ++j) acc[i][j] = (float4v){0.f, 0.f, 0.f, 0.f};

    float wpre[8], xpre[16];
    {
        const float* ws = Wm + (long)(o0 + ow) * CI + kcw * 8;
        *(float4*)&wpre[0] = *(const float4*)ws;
        *(float4*)&wpre[4] = *(const float4*)(ws + 4);
#pragma unroll
        for (int j = 0; j < 16; ++j)
            xpre[j] = xvalid ? Xb[(long)(kcx * 16 + j) * kN + n0 + nx] : 0.f;
    }

    for (int k0 = 0; k0 < CI; k0 += 32) {
        *(uint4*)&Wt[ow][kcw * 8]      = pk8(wpre);
        *(uint4*)&Xt[nx][kcx * 16]     = pk8(xpre);
        *(uint4*)&Xt[nx][kcx * 16 + 8] = pk8(xpre + 8);
        __syncthreads();

        if (k0 + 32 < CI) {
            const float* ws = Wm + (long)(o0 + ow) * CI + k0 + 32 + kcw * 8;
            *(float4*)&wpre[0] = *(const float4*)ws;
            *(float4*)&wpre[4] = *(const float4*)(ws + 4);
#pragma unroll
            for (int j = 0; j < 16; ++j)
                xpre[j] = xvalid ? Xb[(long)(k0 + 32 + kcx * 16 + j) * kN + n0 + nx] : 0.f;
        }

        Frag af[2], bf4[4];
#pragma unroll
        for (int mt = 0; mt < 2; ++mt)
            af[mt].u4 = *(const uint4*)&Wt[wy * 32 + mt * 16 + ln][qd * 8];
#pragma unroll
        for (int nt = 0; nt < 4; ++nt)
            bf4[nt].u4 = *(const uint4*)&Xt[wx * 64 + nt * 16 + ln][qd * 8];
#pragma unroll
        for (int mt = 0; mt < 2; ++mt)
#pragma unroll
            for (int nt = 0; nt < 4; ++nt)
                acc[mt][nt] = __builtin_amdgcn_mfma_f32_16x16x32_bf16(
                    af[mt].s, bf4[nt].s, acc[mt][nt], 0, 0, 0);
        __syncthreads();
    }

#pragma unroll
    for (int mt = 0; mt < 2; ++mt) {
        const int obL = o0 + wy * 32 + mt * 16 + qd * 4;   // bias row
        const int obY = oY + wy * 32 + mt * 16 + qd * 4;   // output row
#pragma unroll
        for (int nt = 0; nt < 4; ++nt) {
            const int n = n0 + wx * 64 + nt * 16 + ln;
            if (n < kN) {
#pragma unroll
                for (int r = 0; r < 4; ++r) {
                    float v = acc[mt][nt][r];
                    if (bias) v += bias[obL + r];
                    Yb[(long)(obY + r) * kN + n] = v;
                }
            }
        }
    }
}

// ---------------------------------------------------------------------------
// BN+ReLU GEMM for the gate hidden layer (CI=512)
// ---------------------------------------------------------------------------
__global__ __launch_bounds__(256)
void gemm_bn_kernel(const float* __restrict__ Wm, const float* __restrict__ X,
                    const float* __restrict__ gamma, const float* __restrict__ beta,
                    float* __restrict__ Y, int CI, long xbs, long ybs)
{
    const int b  = blockIdx.z;
    const int o0 = blockIdx.y * 64;
    const int n0 = blockIdx.x * 128;
    const float* Xb = X + (long)b * xbs;
    float* Yb = Y + (long)b * ybs;

    __shared__ __align__(16) unsigned short Wt[64][40];
    __shared__ __align__(16) unsigned short Xt[128][40];

    const int tid = threadIdx.x;
    const int wave = tid >> 6, lane = tid & 63;
    const int ln = lane & 15, qd = lane >> 4;
    const int wy = wave >> 1, wx = wave & 1;

    const int ow = tid >> 2, kcw = tid & 3;
    const int nx = tid & 127, kcx = tid >> 7;
    const bool xvalid = (n0 + nx) < kN;

    float4v acc[2][4];
#pragma unroll
    for (int i = 0; i < 2; ++i)
#pragma unroll
        for (int j = 0; j < 4; ++j) acc[i][j] = (float4v){0.f, 0.f, 0.f, 0.f};

    float wpre[8], xpre[16];
    {
        const float* ws = Wm + (long)(o0 + ow) * CI + kcw * 8;
        *(float4*)&wpre[0] = *(const float4*)ws;
        *(float4*)&wpre[4] = *(const float4*)(ws + 4);
#pragma unroll
        for (int j = 0; j < 16; ++j)
            xpre[j] = xvalid ? Xb[(long)(kcx * 16 + j) * kN + n0 + nx] : 0.f;
    }

    for (int k0 = 0; k0 < CI; k0 += 32) {
        *(uint4*)&Wt[ow][kcw * 8]      = pk8(wpre);
        *(uint4*)&Xt[nx][kcx * 16]     = pk8(xpre);
        *(uint4*)&Xt[nx][kcx * 16 + 8] = pk8(xpre + 8);
        __syncthreads();

        if (k0 + 32 < CI) {
            const float* ws = Wm + (long)(o0 + ow) * CI + k0 + 32 + kcw * 8;
            *(float4*)&wpre[0] = *(const float4*)ws;
            *(float4*)&wpre[4] = *(const float4*)(ws + 4);
#pragma unroll
            for (int j = 0; j < 16; ++j)
                xpre[j] = xvalid ? Xb[(long)(k0 + 32 + kcx * 16 + j) * kN + n0 + nx] : 0.f;
        }

        Frag af[2], bf4[4];
#pragma unroll
        for (int mt = 0; mt < 2; ++mt)
            af[mt].u4 = *(const uint4*)&Wt[wy * 32 + mt * 16 + ln][qd * 8];
#pragma unroll
        for (int nt = 0; nt < 4; ++nt)
            bf4[nt].u4 = *(const uint4*)&Xt[wx * 64 + nt * 16 + ln][qd * 8];
#pragma unroll
        for (int mt = 0; mt < 2; ++mt)
#pragma unroll
            for (int nt = 0; nt < 4; ++nt)
                acc[mt][nt] = __builtin_amdgcn_mfma_f32_16x16x32_bf16(
                    af[mt].s, bf4[nt].s, acc[mt][nt], 0, 0, 0);
        __syncthreads();
    }

    const float rs = rsqrtf(1.0f + 1e-5f);
#pragma unroll
    for (int mt = 0; mt < 2; ++mt) {
        const int ob = o0 + wy * 32 + mt * 16 + qd * 4;
#pragma unroll
        for (int nt = 0; nt < 4; ++nt) {
            const int n = n0 + wx * 64 + nt * 16 + ln;
            if (n < kN) {
#pragma unroll
                for (int r = 0; r < 4; ++r) {
                    const int o = ob + r;
                    float v = fmaxf(fmaf(acc[mt][nt][r], gamma[o] * rs, beta[o]), 0.f);
                    Yb[(long)o * kN + n] = v;
                }
            }
        }
    }
}

// ---------------------------------------------------------------------------
// Token attention, k-split x4, software-pipelined, XCD-swizzled:
// 1600 blocks 1-D; consecutive block IDs round-robin XCDs, so we pin both
// (b,h) groups with group%8 == (blockIdx.x&7) to that XCD -> per-XCD K/V/Q
// working set ~1.2 MB, L2-resident (was ~6.4 MB thrashing to L3).
// ---------------------------------------------------------------------------
__global__ __launch_bounds__(256, 4)
void attn_mfma_kernel(const float* __restrict__ tq,
                      const unsigned short* __restrict__ Kp,
                      const unsigned short* __restrict__ Vp,
                      float* __restrict__ Op, float* __restrict__ lp)
{
    const int bi = blockIdx.x;
    const int xcd = bi & 7;
    const int t = bi >> 3;              // 0..199
    const int gsel = (t >= 100) ? 1 : 0;
    const int r0 = t - gsel * 100;      // 0..99
    const int grpId = (gsel << 3) | xcd;  // 0..15, pinned to xcd
    const int b = grpId >> 3, h = grpId & 7;
    const int sp = r0 / 25;
    const int q0 = (r0 % 25) * 128;
    const int tid = threadIdx.x;
    const int wave = tid >> 6, lane = tid & 63;
    const int qd = lane >> 4, ln = lane & 15;
    const int i0 = (sp == 0) ? 0 : (12 * sp + 1);
    const int i1 = 12 * sp + 13;

    const float* qb = tq + (long)b * kCN + (long)h * kHD * kN;
    const unsigned short* KpB = Kp + (long)(b * 8 + h) * 196 * 512 + ln * 32 + qd * 8;
    const unsigned short* VpB = Vp + (long)(b * 8 + h) * 49 * 2048 + ln * 32 + qd * 8;

    __shared__ __align__(16) unsigned short Ps[4][32 * 40];
    unsigned short* PsW = Ps[wave];

    const float qscale = kAttScale * kLog2e;
    Frag qf[2];
#pragma unroll
    for (int qt = 0; qt < 2; ++qt) {
        int qg = q0 + wave * 32 + qt * 16 + ln;
        bool qv = qg < kN;
#pragma unroll
        for (int j = 0; j < 8; ++j) {
            int d = qd * 8 + j;
            float v = qv ? qb[(long)d * kN + qg] * qscale : 0.f;
            qf[qt].u[j] = f2b(v);
        }
    }

    float4v o[2][2];
#pragma unroll
    for (int qt = 0; qt < 2; ++qt)
#pragma unroll
        for (int dh = 0; dh < 2; ++dh) o[qt][dh] = (float4v){0.f, 0.f, 0.f, 0.f};
    float lsum[2] = {0.f, 0.f};

    unsigned W[4][2][2];
    Frag ka[4];
#pragma unroll
    for (int m = 0; m < 4; ++m)
        ka[m].u4 = *(const uint4*)(KpB + (long)(4 * i0 + m) * 512);

    auto computeW = [&]() {
#pragma unroll
        for (int m = 0; m < 4; ++m) {
            float4v s0 = __builtin_amdgcn_mfma_f32_16x16x32_bf16(
                ka[m].s, qf[0].s, (float4v){0.f, 0.f, 0.f, 0.f}, 0, 0, 0);
            float4v s1 = __builtin_amdgcn_mfma_f32_16x16x32_bf16(
                ka[m].s, qf[1].s, (float4v){0.f, 0.f, 0.f, 0.f}, 0, 0, 0);
            float a0 = __builtin_amdgcn_exp2f(s0[0]);
            float a1 = __builtin_amdgcn_exp2f(s0[1]);
            float a2 = __builtin_amdgcn_exp2f(s0[2]);
            float a3 = __builtin_amdgcn_exp2f(s0[3]);
            lsum[0] += (a0 + a1) + (a2 + a3);
            W[m][0][0] = pk_trunc(a0, a1);
            W[m][0][1] = pk_trunc(a2, a3);
            float b0 = __builtin_amdgcn_exp2f(s1[0]);
            float b1 = __builtin_amdgcn_exp2f(s1[1]);
            float b2 = __builtin_amdgcn_exp2f(s1[2]);
            float b3 = __builtin_amdgcn_exp2f(s1[3]);
            lsum[1] += (b0 + b1) + (b2 + b3);
            W[m][1][0] = pk_trunc(b0, b1);
            W[m][1][1] = pk_trunc(b2, b3);
        }
    };

    computeW();
    if (i0 + 1 < i1) {
#pragma unroll
        for (int m = 0; m < 4; ++m)
            ka[m].u4 = *(const uint4*)(KpB + (long)(4 * (i0 + 1) + m) * 512);
    }

    for (int i = i0; i < i1; ++i) {
        Frag va[2][2];
#pragma unroll
        for (int g = 0; g < 2; ++g)
#pragma unroll
            for (int dh = 0; dh < 2; ++dh)
                va[g][dh].u4 = *(const uint4*)(VpB + (long)i * 2048 + (g * 2 + dh) * 512);

#pragma unroll
        for (int m = 0; m < 4; ++m)
#pragma unroll
            for (int qt = 0; qt < 2; ++qt)
                *(uint2*)&PsW[(qt * 16 + ln) * 40 + m * 16 + qd * 4] =
                    make_uint2(W[m][qt][0], W[m][qt][1]);

        if (i + 1 < i1) {
            computeW();
            if (i + 2 < i1) {
#pragma unroll
                for (int m = 0; m < 4; ++m)
                    ka[m].u4 = *(const uint4*)(KpB + (long)(4 * (i + 2) + m) * 512);
            }
        }

#pragma unroll
        for (int g = 0; g < 2; ++g) {
            Frag pa[2];
#pragma unroll
            for (int qt = 0; qt < 2; ++qt)
                pa[qt].u4 = *(const uint4*)&PsW[(qt * 16 + ln) * 40 + g * 32 + qd * 8];
#pragma unroll
            for (int qt = 0; qt < 2; ++qt)
#pragma unroll
                for (int dh = 0; dh < 2; ++dh)
                    o[qt][dh] = __builtin_amdgcn_mfma_f32_16x16x32_bf16(
                        pa[qt].s, va[g][dh].s, o[qt][dh], 0, 0, 0);
        }
    }

    const long grp = (long)(sp * 16 + b * 8 + h);
#pragma unroll
    for (int qt = 0; qt < 2; ++qt) {
        lsum[qt] += __shfl_xor(lsum[qt], 16, 64);
        lsum[qt] += __shfl_xor(lsum[qt], 32, 64);
        if (qd == 0)
            lp[grp * 3200 + q0 + wave * 32 + qt * 16 + ln] = lsum[qt];
#pragma unroll
        for (int dh = 0; dh < 2; ++dh)
#pragma unroll
            for (int r = 0; r < 4; ++r) {
                int q = q0 + wave * 32 + qt * 16 + qd * 4 + r;
                Op[(grp * 3200 + q) * 32 + dh * 16 + ln] = o[qt][dh][r];
            }
    }
}

// ---------------------------------------------------------------------------
// Combine 4 k-split partials, normalize, transpose, ADD into xo (holds vres).
// ---------------------------------------------------------------------------
__global__ __launch_bounds__(256)
void attn_combine_kernel(const float* __restrict__ Op, const float* __restrict__ lp,
                         float* __restrict__ xo)
{
    const int qc = blockIdx.x, bh = blockIdx.y;
    const int b = bh >> 3, h = bh & 7;
    const int q0 = qc * 64;
    __shared__ float T[32][65];
    const int tid = threadIdx.x;

    for (int i = tid; i < 64 * 32; i += 256) {
        int ql = i >> 5, d = i & 31;
        float ov = 0.f, l = 0.f;
#pragma unroll
        for (int s = 0; s < 4; ++s) {
            long g = (long)(s * 16 + bh);
            ov += Op[(g * 3200 + q0 + ql) * 32 + d];
            l  += lp[g * 3200 + q0 + ql];
        }
        T[d][ql] = ov / l;
    }
    __syncthreads();
    for (int i = tid; i < 32 * 64; i += 256) {
        int d = i >> 6, ql = i & 63;
        xo[(long)b * kCN + (long)(h * kHD + d) * kN + q0 + ql] += T[d][ql];
    }
}

// ---------------------------------------------------------------------------
// Fused gate + blend.
// ---------------------------------------------------------------------------
__global__ __launch_bounds__(256)
void gateblend_kernel(const float* __restrict__ hbuf, const float* __restrict__ w2,
                      const float* __restrict__ b2, const float* __restrict__ gcat,
                      float* __restrict__ out)
{
    const int n0 = blockIdx.x * 64;
    const int b = blockIdx.y;
    const int lane = threadIdx.x & 63;
    const int g = threadIdx.x >> 6;
    const float* hb = hbuf + (long)b * kCN + n0 + lane;
    float s = 0.f;
#pragma unroll 8
    for (int c = g * 64; c < g * 64 + 64; ++c)
        s = fmaf(w2[c], hb[(long)c * kN], s);
    __shared__ float red[4][64];
    __shared__ float sgate[64];
    red[g][lane] = s;
    __syncthreads();
    if (g == 0) {
        float t = red[0][lane] + red[1][lane] + red[2][lane] + red[3][lane];
        sgate[lane] = 1.f / (1.f + __expf(-(t + b2[0])));
    }
    __syncthreads();
    const float gt = sgate[lane];
    const float* osp = gcat + (long)b * 2 * kCN + n0 + lane;
    const float* otp = osp + kCN;
    float* op = out + (long)b * kCN + n0 + lane;
    for (int c = g; c < kC; c += 4) {
        float os = osp[(long)c * kN];
        float ot = otp[(long)c * kN];
        op[(long)c * kN] = gt * os + (1.f - gt) * ot;
    }
}

// ---------------------------------------------------------------------------
extern "C" void kernel_launch(void* const* d_in, const int* in_sizes, int n_in,
                              void* d_out, int out_size, void* d_ws, size_t ws_size,
                              hipStream_t stream)
{
    const float* x      = (const float*)d_in[0];
    const float* ctx    = (const float*)d_in[1];
    const float* s_q_w  = (const float*)d_in[2];
    const float* s_kv_w = (const float*)d_in[3];
    const float* s_p_w  = (const float*)d_in[4];
    const float* s_p_b  = (const float*)d_in[5];
    const float* s_dw_w = (const float*)d_in[6];
    const float* s_dw_b = (const float*)d_in[7];
    const float* t_q_w  = (const float*)d_in[8];
    const float* t_kv_w = (const float*)d_in[9];
    const float* t_p_w  = (const float*)d_in[10];
    const float* t_p_b  = (const float*)d_in[11];
    const float* t_cw   = (const float*)d_in[12];
    const float* g_w1   = (const float*)d_in[13];
    const float* g_bn_g = (const float*)d_in[14];
    const float* g_bn_b = (const float*)d_in[15];
    const float* g_w2   = (const float*)d_in[16];
    const float* g_b2   = (const float*)d_in[17];
    float* out = (float*)d_out;

    float* ws = (float*)d_ws;
    const long SPEC2 = (long)kB * kC * kSpec * 2;
    float* sq   = ws;                    // B*C*N   (sq -> vres -> tpre)
    float* skv  = sq   + kB * kCN;       // B*2C*N
    float* tq   = skv  + kB * 2 * kCN;   // B*C*N
    float* tkv  = tq   + kB * kCN;       // B*2C*N  (later: h)
    float* vloc = tkv  + kB * 2 * kCN;   // B*C*N   (spre result)
    float* fQ   = vloc + kB * kCN;
    float* fK   = fQ   + SPEC2;
    float* fV   = fK   + SPEC2;
    float* gcat = fV   + SPEC2;          // B*2C*N : [os ; ot]
    float* gate = gcat + kB * 2 * kCN;   // B*N (unused slot, kept for layout)
    unsigned short* tw = (unsigned short*)(gate + kB * kN);  // twiddles
    unsigned short* Kp = tw + TWTOT;                         // 16*196*512 u16
    unsigned short* Vp = Kp + (long)16 * 196 * 512;          // 16*49*2048 u16
    float* Opart = (float*)(Vp + (long)16 * 49 * 2048);      // 64*3200*32 f32
    float* lpart = Opart + (long)64 * 3200 * 32;             // 64*3200 f32

    dim3 blk(256, 1, 1);

    twiddle_init_kernel<<<dim3(TWTOT / 256), blk, 0, stream>>>(tw);

    gemm_fused<<<dim3(25, 8, kB), blk, 0, stream>>>(
        s_q_w, t_q_w, x, x, nullptr, nullptr, sq, tq, 4, kC, kCN, kCN, 0);
    gemm_fused<<<dim3(25, 16, kB), blk, 0, stream>>>(
        s_kv_w, t_kv_w, ctx, ctx, nullptr, nullptr, skv, tkv, 8, kC, kCN, 2 * kCN, 0);

    fwd3_prepack_kernel<<<dim3(3 * kB * kC + kB * kNH * 49), blk, 0, stream>>>(
        sq, skv, tkv + kCN, fQ, fK, fV, tw, tkv, Kp, Vp);

    dft_inv_mfma2<<<dim3(2 * kB * kC), blk, 0, stream>>>(
        fQ, fK, fV, t_cw, vloc, sq, skv, s_dw_w, s_dw_b, tw);

    attn_mfma_kernel<<<dim3(1600), blk, 0, stream>>>(tq, Kp, Vp, Opart, lpart);
    attn_combine_kernel<<<dim3(49, 16), blk, 0, stream>>>(Opart, lpart, sq);  // sq += xattn

    gemm_fused<<<dim3(25, 8, kB), blk, 0, stream>>>(
        s_p_w, t_p_w, vloc, sq, s_p_b, t_p_b, gcat, gcat, 4, kC, kCN, 2 * kCN, 256);

    gemm_bn_kernel<<<dim3(25, 4, kB), blk, 0, stream>>>(g_w1, gcat, g_bn_g, g_bn_b, tkv, 2 * kC, 2 * kCN, kCN); // h
    gateblend_kernel<<<dim3(49, kB), blk, 0, stream>>>(tkv, g_w2, g_b2, gcat, out);
}

// Round 12
// 265.843 us; speedup vs baseline: 5.0627x; 1.0546x over previous
//
#include <hip/hip_runtime.h>

namespace {
constexpr int kB = 2;
constexpr int kC = 256;
constexpr int kH = 56;
constexpr int kW = 56;
constexpr int kN = kH * kW;        // 3136
constexpr int kNH = 8;
constexpr int kHD = 32;
constexpr int kNF = kW / 2 + 1;    // 29
constexpr int kSpec = kH * kNF;    // 1624
constexpr long kCN = (long)kC * kN;        // 802816
constexpr float kAttScale = 0.17677669529663687f;   // 32^-0.5
constexpr float kLog2e = 1.4426950408889634f;
constexpr float kAng = 6.283185307179586f / 56.0f;  // 2*pi/56
// twiddle table offsets in u16 units
constexpr int TW1F = 0;            // [128][64]
constexpr int TW2F = 8192;         // [64][64]
constexpr int TW1I = 12288;        // [128][64]
constexpr int TW2I = 20480;        // [64][64]
constexpr int TWTOT = 24576;
}

typedef __attribute__((ext_vector_type(8))) short short8;
typedef __attribute__((ext_vector_type(4))) float float4v;

union Frag {
    short8 s;
    unsigned short u[8];
    uint2 u2[2];
    uint4 u4;
};

__device__ __forceinline__ unsigned short f2b(float f) {
    unsigned u = __float_as_uint(f);
    return (unsigned short)((u + 0x7FFFu + ((u >> 16) & 1u)) >> 16);
}
__device__ __forceinline__ float b2f(unsigned short u) {
    return __uint_as_float((unsigned)u << 16);
}
__device__ __forceinline__ unsigned f2b_pk(float a, float b) {
    unsigned ua = __float_as_uint(a); ua = (ua + 0x7FFFu + ((ua >> 16) & 1u)) >> 16;
    unsigned ub = __float_as_uint(b); ub = (ub + 0x7FFFu + ((ub >> 16) & 1u)) >> 16;
    return ua | (ub << 16);
}
__device__ __forceinline__ unsigned pk_trunc(float a, float b) {
    return (__float_as_uint(a) >> 16) | (__float_as_uint(b) & 0xFFFF0000u);
}
__device__ __forceinline__ uint4 pk8(const float* v) {
    return make_uint4(f2b_pk(v[0], v[1]), f2b_pk(v[2], v[3]),
                      f2b_pk(v[4], v[5]), f2b_pk(v[6], v[7]));
}

// ---------------------------------------------------------------------------
// Twiddle body (bf16 tables into d_ws)
// ---------------------------------------------------------------------------
__device__ void twiddle_body(int blk, unsigned short* __restrict__ tw)
{
    int idx = blk * 256 + threadIdx.x;
    if (idx >= TWTOT) return;
    float val = 0.f;
    if (idx < TW2F) {                       // TW1F
        int r = idx >> 6, c = idx & 63;
        if (c < 56) {
            if (r < 56)       val = cosf(kAng * (float)((r * c) % 56));
            else if (r < 112) val = sinf(kAng * (float)(((r - 56) * c) % 56));
        }
    } else if (idx < TW1I) {                // TW2F
        int t = idx - TW2F; int r = t >> 6, c = t & 63;
        if (c < 56) {
            if (r < 29)                  val = cosf(kAng * (float)((r * c) % 56));
            else if (r >= 32 && r < 61)  val = sinf(kAng * (float)(((r - 32) * c) % 56));
        }
    } else if (idx < TW2I) {                // TW1I
        int t = idx - TW1I; int r = t >> 6, c = t & 63;
        if (c < 56) {
            if (r < 56)                  val = cosf(kAng * (float)((r * c) % 56));
            else if (r >= 64 && r < 120) val = sinf(kAng * (float)(((r - 64) * c) % 56));
        }
    } else {                                // TW2I
        int t = idx - TW2I; int x = t >> 6, c = t & 63;
        if (x < 56 && c < 58) {
            int v = c >> 1;
            float wv = ((v == 0) || (v == 28)) ? 1.f : 2.f;
            float a = kAng * (float)((v * x) % 56);
            val = (c & 1) ? (-wv * sinf(a)) : (wv * cosf(a));
        }
    }
    tw[idx] = f2b(val);
}

// ---------------------------------------------------------------------------
// GEMM body (bias epilogue). Weight/bias rows: o0; output rows: oY.
// smem: Wt[64][40] @0 (5120 B) + Xt[128][40] @5120 (10240 B) = 15360 B
// ---------------------------------------------------------------------------
__device__ void gemm_bias_body(char* smem, const float* __restrict__ Wm,
                               const float* __restrict__ Xb,
                               const float* __restrict__ bias, float* __restrict__ Yb,
                               int o0, int oY, int n0, int CI)
{
    unsigned short (*Wt)[40] = (unsigned short(*)[40])smem;
    unsigned short (*Xt)[40] = (unsigned short(*)[40])(smem + 5120);

    const int tid = threadIdx.x;
    const int wave = tid >> 6, lane = tid & 63;
    const int ln = lane & 15, qd = lane >> 4;
    const int wy = wave >> 1, wx = wave & 1;

    const int ow = tid >> 2, kcw = tid & 3;
    const int nx = tid & 127, kcx = tid >> 7;
    const bool xvalid = (n0 + nx) < kN;

    float4v acc[2][4];
#pragma unroll
    for (int i = 0; i < 2; ++i)
#pragma unroll
        for (int j = 0; j < 4; ++j) acc[i][j] = (float4v){0.f, 0.f, 0.f, 0.f};

    float wpre[8], xpre[16];
    {
        const float* ws = Wm + (long)(o0 + ow) * CI + kcw * 8;
        *(float4*)&wpre[0] = *(const float4*)ws;
        *(float4*)&wpre[4] = *(const float4*)(ws + 4);
#pragma unroll
        for (int j = 0; j < 16; ++j)
            xpre[j] = xvalid ? Xb[(long)(kcx * 16 + j) * kN + n0 + nx] : 0.f;
    }

    for (int k0 = 0; k0 < CI; k0 += 32) {
        *(uint4*)&Wt[ow][kcw * 8]      = pk8(wpre);
        *(uint4*)&Xt[nx][kcx * 16]     = pk8(xpre);
        *(uint4*)&Xt[nx][kcx * 16 + 8] = pk8(xpre + 8);
        __syncthreads();

        if (k0 + 32 < CI) {
            const float* ws = Wm + (long)(o0 + ow) * CI + k0 + 32 + kcw * 8;
            *(float4*)&wpre[0] = *(const float4*)ws;
            *(float4*)&wpre[4] = *(const float4*)(ws + 4);
#pragma unroll
            for (int j = 0; j < 16; ++j)
                xpre[j] = xvalid ? Xb[(long)(k0 + 32 + kcx * 16 + j) * kN + n0 + nx] : 0.f;
        }

        Frag af[2], bf4[4];
#pragma unroll
        for (int mt = 0; mt < 2; ++mt)
            af[mt].u4 = *(const uint4*)&Wt[wy * 32 + mt * 16 + ln][qd * 8];
#pragma unroll
        for (int nt = 0; nt < 4; ++nt)
            bf4[nt].u4 = *(const uint4*)&Xt[wx * 64 + nt * 16 + ln][qd * 8];
#pragma unroll
        for (int mt = 0; mt < 2; ++mt)
#pragma unroll
            for (int nt = 0; nt < 4; ++nt)
                acc[mt][nt] = __builtin_amdgcn_mfma_f32_16x16x32_bf16(
                    af[mt].s, bf4[nt].s, acc[mt][nt], 0, 0, 0);
        __syncthreads();
    }

#pragma unroll
    for (int mt = 0; mt < 2; ++mt) {
        const int obL = o0 + wy * 32 + mt * 16 + qd * 4;
        const int obY = oY + wy * 32 + mt * 16 + qd * 4;
#pragma unroll
        for (int nt = 0; nt < 4; ++nt) {
            const int n = n0 + wx * 64 + nt * 16 + ln;
            if (n < kN) {
#pragma unroll
                for (int r = 0; r < 4; ++r) {
                    float v = acc[mt][nt][r];
                    if (bias) v += bias[obL + r];
                    Yb[(long)(obY + r) * kN + n] = v;
                }
            }
        }
    }
}

// ---------------------------------------------------------------------------
// Mega dispatch 1: twiddle init + all 4 projection GEMMs (1296 blocks).
// [0,96): twiddle; [96,496): q-projections; [496,1296): kv-projections.
// ---------------------------------------------------------------------------
__global__ __launch_bounds__(256)
void init_proj_kernel(unsigned short* __restrict__ tw,
                      const float* __restrict__ x, const float* __restrict__ ctx,
                      const float* __restrict__ s_q_w, const float* __restrict__ t_q_w,
                      const float* __restrict__ s_kv_w, const float* __restrict__ t_kv_w,
                      float* __restrict__ sq, float* __restrict__ tq,
                      float* __restrict__ skv, float* __restrict__ tkv)
{
    __shared__ __align__(16) char smem[15360];
    int bi = blockIdx.x;
    if (bi < 96) { twiddle_body(bi, tw); return; }
    bi -= 96;
    if (bi < 400) {
        // q-projections: 2b x 8y x 25n
        int b = bi / 200, rem = bi % 200;
        int y = rem / 25, xb = rem % 25;
        int sel = y >= 4;
        int o0 = (sel ? y - 4 : y) * 64;
        gemm_bias_body(smem, sel ? t_q_w : s_q_w, (x + (long)b * kCN), nullptr,
                       (sel ? tq : sq) + (long)b * kCN, o0, o0, xb * 128, kC);
    } else {
        bi -= 400;
        int b = bi / 400, rem = bi % 400;
        int y = rem / 25, xb = rem % 25;
        int sel = y >= 8;
        int o0 = (sel ? y - 8 : y) * 64;
        gemm_bias_body(smem, sel ? t_kv_w : s_kv_w, (ctx + (long)b * kCN), nullptr,
                       (sel ? tkv : skv) + (long)b * 2 * kCN, o0, o0, xb * 128, kC);
    }
}

// ---------------------------------------------------------------------------
// Forward 2D DFT body (bf16 Yb; smem use 33280 B)
// ---------------------------------------------------------------------------
__device__ void dft_fwd_body(char* smem, int bx,
                             const float* __restrict__ s0, const float* __restrict__ s1,
                             const float* __restrict__ s2, float* __restrict__ d0,
                             float* __restrict__ d1, float* __restrict__ d2,
                             const unsigned short* __restrict__ tw)
{
    const int which = bx >> 9, ch = bx & 511;
    const int b = ch >> 8, c = ch & 255;
    const float* src; long stride; float* spec;
    if (which == 0)      { src = s0; stride = kCN;     spec = d0; }
    else if (which == 1) { src = s1; stride = 2 * kCN; spec = d1; }
    else                 { src = s2; stride = 2 * kCN; spec = d2; }
    const float* img = src + (long)b * stride + (long)c * kN;

    unsigned short (*Gb)[72]    = (unsigned short(*)[72])smem;            // 18432
    unsigned short (*imgT)[72]  = (unsigned short(*)[72])(smem + 18432);  // 9216
    unsigned short (*Yb)[116]   = (unsigned short(*)[116])(smem + 18432); // 14848 overlay

    const int tid = threadIdx.x;
    const int wave = tid >> 6, lane = tid & 63;
    const int ln = lane & 15, qd = lane >> 4;

    for (int i = tid; i < 64 * 72; i += 256) {
        int r = i / 72, cc = i - r * 72;
        if (r >= 56 || cc >= 56) imgT[r][cc] = 0;
    }
    for (int i = tid; i < kN; i += 256) {
        int y = i / 56, x = i - y * 56;
        imgT[x][y] = f2b(img[i]);
    }
    __syncthreads();

    float4v acc1[2][4];
#pragma unroll
    for (int m = 0; m < 2; ++m)
#pragma unroll
        for (int n = 0; n < 4; ++n) acc1[m][n] = (float4v){0.f, 0.f, 0.f, 0.f};
#pragma unroll
    for (int ks = 0; ks < 2; ++ks) {
        Frag a[2], bf[4];
#pragma unroll
        for (int m = 0; m < 2; ++m)
            a[m].u4 = *(const uint4*)(tw + TW1F + ((2 * wave + m) * 16 + ln) * 64 + ks * 32 + qd * 8);
#pragma unroll
        for (int n = 0; n < 4; ++n)
            bf[n].u4 = *(const uint4*)&imgT[n * 16 + ln][ks * 32 + qd * 8];
#pragma unroll
        for (int m = 0; m < 2; ++m)
#pragma unroll
            for (int n = 0; n < 4; ++n)
                acc1[m][n] = __builtin_amdgcn_mfma_f32_16x16x32_bf16(a[m].s, bf[n].s, acc1[m][n], 0, 0, 0);
    }
#pragma unroll
    for (int m = 0; m < 2; ++m)
#pragma unroll
        for (int n = 0; n < 4; ++n)
#pragma unroll
            for (int r = 0; r < 4; ++r)
                Gb[(2 * wave + m) * 16 + qd * 4 + r][n * 16 + ln] = f2b(acc1[m][n][r]);
    __syncthreads();

    float4v acc2[7];
#pragma unroll
    for (int n = 0; n < 7; ++n) acc2[n] = (float4v){0.f, 0.f, 0.f, 0.f};
#pragma unroll
    for (int ks = 0; ks < 2; ++ks) {
        Frag a;
        a.u4 = *(const uint4*)(tw + TW2F + (wave * 16 + ln) * 64 + ks * 32 + qd * 8);
#pragma unroll
        for (int n = 0; n < 7; ++n) {
            Frag bb;
            bb.u4 = *(const uint4*)&Gb[n * 16 + ln][ks * 32 + qd * 8];
            acc2[n] = __builtin_amdgcn_mfma_f32_16x16x32_bf16(a.s, bb.s, acc2[n], 0, 0, 0);
        }
    }
#pragma unroll
    for (int n = 0; n < 7; ++n)
#pragma unroll
        for (int r = 0; r < 4; ++r)
            Yb[wave * 16 + qd * 4 + r][n * 16 + ln] = f2b(acc2[n][r]);
    __syncthreads();

    float2* outp = (float2*)spec + (long)ch * kSpec;
    for (int i = tid; i < kSpec; i += 256) {
        int u = i / kNF, v = i - u * kNF;
        float Qr = b2f(Yb[v][u]) - b2f(Yb[32 + v][56 + u]);
        float Qi = -b2f(Yb[32 + v][u]) - b2f(Yb[v][56 + u]);
        outp[i] = make_float2(Qr, Qi);
    }
}

// ---------------------------------------------------------------------------
// Attention K/V prepack body
// ---------------------------------------------------------------------------
__device__ void prepack_body(char* smem, int blk, const float* __restrict__ tkv,
                             unsigned short* __restrict__ Kp,
                             unsigned short* __restrict__ Vp)
{
    const int i = blk % 49;
    const int h = (blk / 49) & 7;
    const int b = blk / (49 * 8);
    const float* kb = tkv + (long)b * 2 * kCN + (long)h * kHD * kN;
    const float* vb = kb + kCN;
    const int tid = threadIdx.x;

    float (*Ks)[72] = (float(*)[72])smem;
#pragma unroll
    for (int j = 0; j < 8; ++j) {
        int e = tid + j * 256;
        int d = e >> 6, c = e & 63;
        Ks[d][c] = kb[(long)d * kN + i * 64 + c];
    }
    __syncthreads();
    {
        int tl = tid >> 6, lnn = (tid >> 2) & 15, qdd = tid & 3;
        float v[8];
#pragma unroll
        for (int j = 0; j < 8; ++j) v[j] = Ks[qdd * 8 + j][tl * 16 + lnn];
        unsigned short* dst = Kp + ((long)(b * 8 + h) * 196 + 4 * i + tl) * 512 + lnn * 32 + qdd * 8;
        *(uint4*)dst = pk8(v);
    }
    {
        int g = tid >> 7, dh = (tid >> 6) & 1, lnn = (tid >> 2) & 15, qdd = tid & 3;
        int d = dh * 16 + lnn;
        const float* src = vb + (long)d * kN + i * 64 + g * 32 + qdd * 8;
        float v[8];
        *(float4*)&v[0] = *(const float4*)src;
        *(float4*)&v[4] = *(const float4*)(src + 4);
        unsigned short* dst = Vp + ((long)(b * 8 + h) * 49 + i) * 2048 + ((g * 2 + dh) * 16 + lnn) * 32 + qdd * 8;
        *(uint4*)dst = pk8(v);
    }
}

// ---------------------------------------------------------------------------
// Mega dispatch 2: [0,1536) forward DFTs; [1536,2320) K/V prepack.
// ---------------------------------------------------------------------------
__global__ __launch_bounds__(256)
void fwd3_prepack_kernel(const float* __restrict__ s0, const float* __restrict__ s1,
                         const float* __restrict__ s2, float* __restrict__ d0,
                         float* __restrict__ d1, float* __restrict__ d2,
                         const unsigned short* __restrict__ tw,
                         const float* __restrict__ tkv,
                         unsigned short* __restrict__ Kp, unsigned short* __restrict__ Vp)
{
    __shared__ __align__(16) char smem[33280];
    if (blockIdx.x < 1536)
        dft_fwd_body(smem, blockIdx.x, s0, s1, s2, d0, d1, d2, tw);
    else
        prepack_body(smem, blockIdx.x - 1536, tkv, Kp, Vp);
}

// ---------------------------------------------------------------------------
// Inverse 2D DFT body (bf16 Yb; smem use 27648 B)
// ---------------------------------------------------------------------------
__device__ void dft_inv_body(char* smem, int bx,
                             const float* __restrict__ fQ, const float* __restrict__ fK,
                             const float* __restrict__ fV, const float* __restrict__ cw,
                             float* __restrict__ dst1, float* __restrict__ dst2,
                             const float* __restrict__ skvp, const float* __restrict__ dww,
                             const float* __restrict__ dwb, const unsigned short* __restrict__ tw)
{
    const int unit = bx >> 9;
    const int ch = bx & 511;
    const int b = ch >> 8, c = ch & 255;
    unsigned short (*Pb)[72]  = (unsigned short(*)[72])smem;           // 9216
    unsigned short (*Yb)[72]  = (unsigned short(*)[72])(smem + 9216);  // 18432
    unsigned short (*T2)[72]  = (unsigned short(*)[72])smem;           // overlays Pb
    float (*svs)[65]          = (float(*)[65])(smem + 9216);           // overlays Yb

    const int tid = threadIdx.x;
    const int wave = tid >> 6, lane = tid & 63;
    const int ln = lane & 15, qd = lane >> 4;

    const float2* Pin; const float2* Min; float scale; float* dst;
    if (unit == 0) {
        Pin = (const float2*)fQ + (long)ch * kSpec;
        Min = (const float2*)fK + (long)ch * kSpec;
        scale = 1.0f / 175616.0f; dst = dst1;
    } else {
        Pin = (const float2*)fV + (long)ch * kSpec;
        Min = (const float2*)cw + (long)c * kSpec;
        scale = 1.0f / 3136.0f; dst = dst2;
    }

    for (int i = tid; i < 64 * 72; i += 256) {
        int r = i / 72, cc = i - r * 72;
        if (r >= 58 || cc >= 56) Pb[r][cc] = 0;
    }
    for (int i = tid; i < kSpec; i += 256) {
        int u = i / kNF, v = i - u * kNF;
        float2 p = Pin[i];
        float2 m = Min[i];
        float pr = (p.x * m.x - p.y * m.y) * scale;
        float pi = (p.x * m.y + p.y * m.x) * scale;
        Pb[2 * v][u]     = f2b(pr);
        Pb[2 * v + 1][u] = f2b(pi);
    }
    __syncthreads();

    float4v acc1[2][4];
#pragma unroll
    for (int m = 0; m < 2; ++m)
#pragma unroll
        for (int n = 0; n < 4; ++n) acc1[m][n] = (float4v){0.f, 0.f, 0.f, 0.f};
#pragma unroll
    for (int ks = 0; ks < 2; ++ks) {
        Frag a[2], bf[4];
#pragma unroll
        for (int m = 0; m < 2; ++m)
            a[m].u4 = *(const uint4*)(tw + TW1I + ((2 * wave + m) * 16 + ln) * 64 + ks * 32 + qd * 8);
#pragma unroll
        for (int n = 0; n < 4; ++n)
            bf[n].u4 = *(const uint4*)&Pb[n * 16 + ln][ks * 32 + qd * 8];
#pragma unroll
        for (int m = 0; m < 2; ++m)
#pragma unroll
            for (int n = 0; n < 4; ++n)
                acc1[m][n] = __builtin_amdgcn_mfma_f32_16x16x32_bf16(a[m].s, bf[n].s, acc1[m][n], 0, 0, 0);
    }
#pragma unroll
    for (int m = 0; m < 2; ++m)
#pragma unroll
        for (int n = 0; n < 4; ++n)
#pragma unroll
            for (int r = 0; r < 4; ++r)
                Yb[(2 * wave + m) * 16 + qd * 4 + r][n * 16 + ln] = f2b(acc1[m][n][r]);
    __syncthreads();

    for (int i = tid; i < 64 * 72; i += 256) {
        int r = i / 72, cc = i - r * 72;
        if (r >= 56 || cc >= 58) T2[r][cc] = 0;
    }
    __syncthreads();
    for (int i = tid; i < 56 * kNF; i += 256) {
        int y = i / kNF, v = i - y * kNF;
        float Tr = b2f(Yb[y][2 * v])     - b2f(Yb[64 + y][2 * v + 1]);
        float Ti = b2f(Yb[y][2 * v + 1]) + b2f(Yb[64 + y][2 * v]);
        T2[y][2 * v]     = f2b(Tr);
        T2[y][2 * v + 1] = f2b(Ti);
    }
    __syncthreads();   // Yb dead; svs region free

    float wreg[9]; float bias = 0.f;
    if (unit == 0) {
        const float* svp = skvp + (long)b * 2 * kCN + kCN + (long)c * kN;
        for (int i = tid; i < 58 * 65; i += 256) {
            int y = i / 65, x = i - y * 65;
            if (y == 0 || y == 57 || x == 0 || x >= 57) ((float*)svs)[i] = 0.f;
        }
        for (int i = tid; i < kN; i += 256) {
            int y = i / 56, x = i - y * 56;
            svs[y + 1][x + 1] = svp[i];
        }
#pragma unroll
        for (int j = 0; j < 9; ++j) wreg[j] = dww[c * 9 + j];
        bias = dwb[c];
    }

    float4v acc2[4];
#pragma unroll
    for (int n = 0; n < 4; ++n) acc2[n] = (float4v){0.f, 0.f, 0.f, 0.f};
#pragma unroll
    for (int ks = 0; ks < 2; ++ks) {
        Frag a;
        a.u4 = *(const uint4*)(tw + TW2I + (wave * 16 + ln) * 64 + ks * 32 + qd * 8);
#pragma unroll
        for (int n = 0; n < 4; ++n) {
            Frag bb;
            bb.u4 = *(const uint4*)&T2[n * 16 + ln][ks * 32 + qd * 8];
            acc2[n] = __builtin_amdgcn_mfma_f32_16x16x32_bf16(a.s, bb.s, acc2[n], 0, 0, 0);
        }
    }
    __syncthreads();   // svs visible

    float* outd = dst + (long)ch * kN;
#pragma unroll
    for (int n = 0; n < 4; ++n) {
        int y = n * 16 + ln;
        if (y < 56) {
#pragma unroll
            for (int r = 0; r < 4; ++r) {
                int x = wave * 16 + qd * 4 + r;
                if (x < 56) {
                    int e = y * 56 + x;
                    if (unit == 0) {
                        float s = bias;
                        s = fmaf(wreg[0], svs[y][x],     s);
                        s = fmaf(wreg[1], svs[y][x + 1], s);
                        s = fmaf(wreg[2], svs[y][x + 2], s);
                        s = fmaf(wreg[3], svs[y + 1][x],     s);
                        s = fmaf(wreg[4], svs[y + 1][x + 1], s);
                        s = fmaf(wreg[5], svs[y + 1][x + 2], s);
                        s = fmaf(wreg[6], svs[y + 2][x],     s);
                        s = fmaf(wreg[7], svs[y + 2][x + 1], s);
                        s = fmaf(wreg[8], svs[y + 2][x + 2], s);
                        outd[e] = fmaf(acc2[n][r], svs[y + 1][x + 1], s);
                    } else {
                        outd[e] = acc2[n][r];     // pure store (vres)
                    }
                }
            }
        }
    }
}

// ---------------------------------------------------------------------------
// Attention body (k-split x4, software-pipelined, XCD-swizzled; smem 10240 B)
// ---------------------------------------------------------------------------
__device__ void attn_body(char* smem, int abi,
                          const float* __restrict__ tq,
                          const unsigned short* __restrict__ Kp,
                          const unsigned short* __restrict__ Vp,
                          float* __restrict__ Op, float* __restrict__ lp)
{
    const int xcd = abi & 7;
    const int t = abi >> 3;             // 0..199
    const int gsel = (t >= 100) ? 1 : 0;
    const int r0 = t - gsel * 100;      // 0..99
    const int grpId = (gsel << 3) | xcd;
    const int b = grpId >> 3, h = grpId & 7;
    const int sp = r0 / 25;
    const int q0 = (r0 % 25) * 128;
    const int tid = threadIdx.x;
    const int wave = tid >> 6, lane = tid & 63;
    const int qd = lane >> 4, ln = lane & 15;
    const int i0 = (sp == 0) ? 0 : (12 * sp + 1);
    const int i1 = 12 * sp + 13;

    const float* qb = tq + (long)b * kCN + (long)h * kHD * kN;
    const unsigned short* KpB = Kp + (long)(b * 8 + h) * 196 * 512 + ln * 32 + qd * 8;
    const unsigned short* VpB = Vp + (long)(b * 8 + h) * 49 * 2048 + ln * 32 + qd * 8;

    unsigned short* PsW = (unsigned short*)smem + wave * (32 * 40);

    const float qscale = kAttScale * kLog2e;
    Frag qf[2];
#pragma unroll
    for (int qt = 0; qt < 2; ++qt) {
        int qg = q0 + wave * 32 + qt * 16 + ln;
        bool qv = qg < kN;
#pragma unroll
        for (int j = 0; j < 8; ++j) {
            int d = qd * 8 + j;
            float v = qv ? qb[(long)d * kN + qg] * qscale : 0.f;
            qf[qt].u[j] = f2b(v);
        }
    }

    float4v o[2][2];
#pragma unroll
    for (int qt = 0; qt < 2; ++qt)
#pragma unroll
        for (int dh = 0; dh < 2; ++dh) o[qt][dh] = (float4v){0.f, 0.f, 0.f, 0.f};
    float lsum[2] = {0.f, 0.f};

    unsigned W[4][2][2];
    Frag ka[4];
#pragma unroll
    for (int m = 0; m < 4; ++m)
        ka[m].u4 = *(const uint4*)(KpB + (long)(4 * i0 + m) * 512);

    auto computeW = [&]() {
#pragma unroll
        for (int m = 0; m < 4; ++m) {
            float4v s0 = __builtin_amdgcn_mfma_f32_16x16x32_bf16(
                ka[m].s, qf[0].s, (float4v){0.f, 0.f, 0.f, 0.f}, 0, 0, 0);
            float4v s1 = __builtin_amdgcn_mfma_f32_16x16x32_bf16(
                ka[m].s, qf[1].s, (float4v){0.f, 0.f, 0.f, 0.f}, 0, 0, 0);
            float a0 = __builtin_amdgcn_exp2f(s0[0]);
            float a1 = __builtin_amdgcn_exp2f(s0[1]);
            float a2 = __builtin_amdgcn_exp2f(s0[2]);
            float a3 = __builtin_amdgcn_exp2f(s0[3]);
            lsum[0] += (a0 + a1) + (a2 + a3);
            W[m][0][0] = pk_trunc(a0, a1);
            W[m][0][1] = pk_trunc(a2, a3);
            float b0 = __builtin_amdgcn_exp2f(s1[0]);
            float b1 = __builtin_amdgcn_exp2f(s1[1]);
            float b2 = __builtin_amdgcn_exp2f(s1[2]);
            float b3 = __builtin_amdgcn_exp2f(s1[3]);
            lsum[1] += (b0 + b1) + (b2 + b3);
            W[m][1][0] = pk_trunc(b0, b1);
            W[m][1][1] = pk_trunc(b2, b3);
        }
    };

    computeW();
    if (i0 + 1 < i1) {
#pragma unroll
        for (int m = 0; m < 4; ++m)
            ka[m].u4 = *(const uint4*)(KpB + (long)(4 * (i0 + 1) + m) * 512);
    }

    for (int i = i0; i < i1; ++i) {
        Frag va[2][2];
#pragma unroll
        for (int g = 0; g < 2; ++g)
#pragma unroll
            for (int dh = 0; dh < 2; ++dh)
                va[g][dh].u4 = *(const uint4*)(VpB + (long)i * 2048 + (g * 2 + dh) * 512);

#pragma unroll
        for (int m = 0; m < 4; ++m)
#pragma unroll
            for (int qt = 0; qt < 2; ++qt)
                *(uint2*)&PsW[(qt * 16 + ln) * 40 + m * 16 + qd * 4] =
                    make_uint2(W[m][qt][0], W[m][qt][1]);

        if (i + 1 < i1) {
            computeW();
            if (i + 2 < i1) {
#pragma unroll
                for (int m = 0; m < 4; ++m)
                    ka[m].u4 = *(const uint4*)(KpB + (long)(4 * (i + 2) + m) * 512);
            }
        }

#pragma unroll
        for (int g = 0; g < 2; ++g) {
            Frag pa[2];
#pragma unroll
            for (int qt = 0; qt < 2; ++qt)
                pa[qt].u4 = *(const uint4*)&PsW[(qt * 16 + ln) * 40 + g * 32 + qd * 8];
#pragma unroll
            for (int qt = 0; qt < 2; ++qt)
#pragma unroll
                for (int dh = 0; dh < 2; ++dh)
                    o[qt][dh] = __builtin_amdgcn_mfma_f32_16x16x32_bf16(
                        pa[qt].s, va[g][dh].s, o[qt][dh], 0, 0, 0);
        }
    }

    const long grp = (long)(sp * 16 + b * 8 + h);
#pragma unroll
    for (int qt = 0; qt < 2; ++qt) {
        lsum[qt] += __shfl_xor(lsum[qt], 16, 64);
        lsum[qt] += __shfl_xor(lsum[qt], 32, 64);
        if (qd == 0)
            lp[grp * 3200 + q0 + wave * 32 + qt * 16 + ln] = lsum[qt];
#pragma unroll
        for (int dh = 0; dh < 2; ++dh)
#pragma unroll
            for (int r = 0; r < 4; ++r) {
                int q = q0 + wave * 32 + qt * 16 + qd * 4 + r;
                Op[(grp * 3200 + q) * 32 + dh * 16 + ln] = o[qt][dh][r];
            }
    }
}

// ---------------------------------------------------------------------------
// Mega dispatch 3: inverse DFTs + attention, interleaved (2624 blocks).
// Period 328 = 128 inv + 200 attn (×8 periods). 328%8==0 and 128%8==0 so
// attn-local index ≡ blockIdx (mod 8) — XCD swizzle preserved.
// ---------------------------------------------------------------------------
__global__ __launch_bounds__(256, 4)
void inv_attn_kernel(const float* __restrict__ fQ, const float* __restrict__ fK,
                     const float* __restrict__ fV, const float* __restrict__ cw,
                     float* __restrict__ dst1, float* __restrict__ dst2,
                     const float* __restrict__ skvp, const float* __restrict__ dww,
                     const float* __restrict__ dwb, const unsigned short* __restrict__ tw,
                     const float* __restrict__ tq,
                     const unsigned short* __restrict__ Kp,
                     const unsigned short* __restrict__ Vp,
                     float* __restrict__ Op, float* __restrict__ lp)
{
    __shared__ __align__(16) char smem[27648];
    const int per = blockIdx.x / 328;
    const int off = blockIdx.x % 328;
    if (off < 128)
        dft_inv_body(smem, per * 128 + off, fQ, fK, fV, cw, dst1, dst2, skvp, dww, dwb, tw);
    else
        attn_body(smem, per * 200 + (off - 128), tq, Kp, Vp, Op, lp);
}

// ---------------------------------------------------------------------------
// Combine 4 k-split partials, normalize, transpose, ADD into xo (holds vres).
// ---------------------------------------------------------------------------
__global__ __launch_bounds__(256)
void attn_combine_kernel(const float* __restrict__ Op, const float* __restrict__ lp,
                         float* __restrict__ xo)
{
    const int qc = blockIdx.x, bh = blockIdx.y;
    const int b = bh >> 3, h = bh & 7;
    const int q0 = qc * 64;
    __shared__ float T[32][65];
    const int tid = threadIdx.x;

    for (int i = tid; i < 64 * 32; i += 256) {
        int ql = i >> 5, d = i & 31;
        float ov = 0.f, l = 0.f;
#pragma unroll
        for (int s = 0; s < 4; ++s) {
            long g = (long)(s * 16 + bh);
            ov += Op[(g * 3200 + q0 + ql) * 32 + d];
            l  += lp[g * 3200 + q0 + ql];
        }
        T[d][ql] = ov / l;
    }
    __syncthreads();
    for (int i = tid; i < 32 * 64; i += 256) {
        int d = i >> 6, ql = i & 63;
        xo[(long)b * kCN + (long)(h * kHD + d) * kN + q0 + ql] += T[d][ql];
    }
}

// ---------------------------------------------------------------------------
// Output projections (dual GEMM, different inputs) -> gcat
// ---------------------------------------------------------------------------
__global__ __launch_bounds__(256)
void gemm_fused(const float* __restrict__ W0, const float* __restrict__ W1,
                const float* __restrict__ X0, const float* __restrict__ X1,
                const float* __restrict__ b0, const float* __restrict__ b1,
                float* __restrict__ Y0, float* __restrict__ Y1,
                int oHalf, int CI, long xbs, long ybs, int oOffset)
{
    __shared__ __align__(16) char smem[15360];
    const int b  = blockIdx.z;
    const int sel = blockIdx.y >= oHalf;
    const int o0 = (sel ? blockIdx.y - oHalf : blockIdx.y) * 64;
    const int oY = o0 + (sel ? oOffset : 0);
    gemm_bias_body(smem, sel ? W1 : W0, (sel ? X1 : X0) + (long)b * xbs,
                   sel ? b1 : b0, (sel ? Y1 : Y0) + (long)b * ybs,
                   o0, oY, blockIdx.x * 128, CI);
}

// ---------------------------------------------------------------------------
// BN+ReLU GEMM for the gate hidden layer (CI=512)
// ---------------------------------------------------------------------------
__global__ __launch_bounds__(256)
void gemm_bn_kernel(const float* __restrict__ Wm, const float* __restrict__ X,
                    const float* __restrict__ gamma, const float* __restrict__ beta,
                    float* __restrict__ Y, int CI, long xbs, long ybs)
{
    const int b  = blockIdx.z;
    const int o0 = blockIdx.y * 64;
    const int n0 = blockIdx.x * 128;
    const float* Xb = X + (long)b * xbs;
    float* Yb = Y + (long)b * ybs;

    __shared__ __align__(16) unsigned short Wt[64][40];
    __shared__ __align__(16) unsigned short Xt[128][40];

    const int tid = threadIdx.x;
    const int wave = tid >> 6, lane = tid & 63;
    const int ln = lane & 15, qd = lane >> 4;
    const int wy = wave >> 1, wx = wave & 1;

    const int ow = tid >> 2, kcw = tid & 3;
    const int nx = tid & 127, kcx = tid >> 7;
    const bool xvalid = (n0 + nx) < kN;

    float4v acc[2][4];
#pragma unroll
    for (int i = 0; i < 2; ++i)
#pragma unroll
        for (int j = 0; j < 4; ++j) acc[i][j] = (float4v){0.f, 0.f, 0.f, 0.f};

    float wpre[8], xpre[16];
    {
        const float* ws = Wm + (long)(o0 + ow) * CI + kcw * 8;
        *(float4*)&wpre[0] = *(const float4*)ws;
        *(float4*)&wpre[4] = *(const float4*)(ws + 4);
#pragma unroll
        for (int j = 0; j < 16; ++j)
            xpre[j] = xvalid ? Xb[(long)(kcx * 16 + j) * kN + n0 + nx] : 0.f;
    }

    for (int k0 = 0; k0 < CI; k0 += 32) {
        *(uint4*)&Wt[ow][kcw * 8]      = pk8(wpre);
        *(uint4*)&Xt[nx][kcx * 16]     = pk8(xpre);
        *(uint4*)&Xt[nx][kcx * 16 + 8] = pk8(xpre + 8);
        __syncthreads();

        if (k0 + 32 < CI) {
            const float* ws = Wm + (long)(o0 + ow) * CI + k0 + 32 + kcw * 8;
            *(float4*)&wpre[0] = *(const float4*)ws;
            *(float4*)&wpre[4] = *(const float4*)(ws + 4);
#pragma unroll
            for (int j = 0; j < 16; ++j)
                xpre[j] = xvalid ? Xb[(long)(k0 + 32 + kcx * 16 + j) * kN + n0 + nx] : 0.f;
        }

        Frag af[2], bf4[4];
#pragma unroll
        for (int mt = 0; mt < 2; ++mt)
            af[mt].u4 = *(const uint4*)&Wt[wy * 32 + mt * 16 + ln][qd * 8];
#pragma unroll
        for (int nt = 0; nt < 4; ++nt)
            bf4[nt].u4 = *(const uint4*)&Xt[wx * 64 + nt * 16 + ln][qd * 8];
#pragma unroll
        for (int mt = 0; mt < 2; ++mt)
#pragma unroll
            for (int nt = 0; nt < 4; ++nt)
                acc[mt][nt] = __builtin_amdgcn_mfma_f32_16x16x32_bf16(
                    af[mt].s, bf4[nt].s, acc[mt][nt], 0, 0, 0);
        __syncthreads();
    }

    const float rs = rsqrtf(1.0f + 1e-5f);
#pragma unroll
    for (int mt = 0; mt < 2; ++mt) {
        const int ob = o0 + wy * 32 + mt * 16 + qd * 4;
#pragma unroll
        for (int nt = 0; nt < 4; ++nt) {
            const int n = n0 + wx * 64 + nt * 16 + ln;
            if (n < kN) {
#pragma unroll
                for (int r = 0; r < 4; ++r) {
                    const int o = ob + r;
                    float v = fmaxf(fmaf(acc[mt][nt][r], gamma[o] * rs, beta[o]), 0.f);
                    Yb[(long)o * kN + n] = v;
                }
            }
        }
    }
}

// ---------------------------------------------------------------------------
// Fused gate + blend.
// ---------------------------------------------------------------------------
__global__ __launch_bounds__(256)
void gateblend_kernel(const float* __restrict__ hbuf, const float* __restrict__ w2,
                      const float* __restrict__ b2, const float* __restrict__ gcat,
                      float* __restrict__ out)
{
    const int n0 = blockIdx.x * 64;
    const int b = blockIdx.y;
    const int lane = threadIdx.x & 63;
    const int g = threadIdx.x >> 6;
    const float* hb = hbuf + (long)b * kCN + n0 + lane;
    float s = 0.f;
#pragma unroll 8
    for (int c = g * 64; c < g * 64 + 64; ++c)
        s = fmaf(w2[c], hb[(long)c * kN], s);
    __shared__ float red[4][64];
    __shared__ float sgate[64];
    red[g][lane] = s;
    __syncthreads();
    if (g == 0) {
        float t = red[0][lane] + red[1][lane] + red[2][lane] + red[3][lane];
        sgate[lane] = 1.f / (1.f + __expf(-(t + b2[0])));
    }
    __syncthreads();
    const float gt = sgate[lane];
    const float* osp = gcat + (long)b * 2 * kCN + n0 + lane;
    const float* otp = osp + kCN;
    float* op = out + (long)b * kCN + n0 + lane;
    for (int c = g; c < kC; c += 4) {
        float os = osp[(long)c * kN];
        float ot = otp[(long)c * kN];
        op[(long)c * kN] = gt * os + (1.f - gt) * ot;
    }
}

// ---------------------------------------------------------------------------
extern "C" void kernel_launch(void* const* d_in, const int* in_sizes, int n_in,
                              void* d_out, int out_size, void* d_ws, size_t ws_size,
                              hipStream_t stream)
{
    const float* x      = (const float*)d_in[0];
    const float* ctx    = (const float*)d_in[1];
    const float* s_q_w  = (const float*)d_in[2];
    const float* s_kv_w = (const float*)d_in[3];
    const float* s_p_w  = (const float*)d_in[4];
    const float* s_p_b  = (const float*)d_in[5];
    const float* s_dw_w = (const float*)d_in[6];
    const float* s_dw_b = (const float*)d_in[7];
    const float* t_q_w  = (const float*)d_in[8];
    const float* t_kv_w = (const float*)d_in[9];
    const float* t_p_w  = (const float*)d_in[10];
    const float* t_p_b  = (const float*)d_in[11];
    const float* t_cw   = (const float*)d_in[12];
    const float* g_w1   = (const float*)d_in[13];
    const float* g_bn_g = (const float*)d_in[14];
    const float* g_bn_b = (const float*)d_in[15];
    const float* g_w2   = (const float*)d_in[16];
    const float* g_b2   = (const float*)d_in[17];
    float* out = (float*)d_out;

    float* ws = (float*)d_ws;
    const long SPEC2 = (long)kB * kC * kSpec * 2;
    float* sq   = ws;                    // B*C*N   (sq -> vres -> tpre)
    float* skv  = sq   + kB * kCN;       // B*2C*N
    float* tq   = skv  + kB * 2 * kCN;   // B*C*N
    float* tkv  = tq   + kB * kCN;       // B*2C*N  (later: h)
    float* vloc = tkv  + kB * 2 * kCN;   // B*C*N   (spre result)
    float* fQ   = vloc + kB * kCN;
    float* fK   = fQ   + SPEC2;
    float* fV   = fK   + SPEC2;
    float* gcat = fV   + SPEC2;          // B*2C*N : [os ; ot]
    float* gate = gcat + kB * 2 * kCN;   // B*N (unused slot, kept for layout)
    unsigned short* tw = (unsigned short*)(gate + kB * kN);  // twiddles
    unsigned short* Kp = tw + TWTOT;                         // 16*196*512 u16
    unsigned short* Vp = Kp + (long)16 * 196 * 512;          // 16*49*2048 u16
    float* Opart = (float*)(Vp + (long)16 * 49 * 2048);      // 64*3200*32 f32
    float* lpart = Opart + (long)64 * 3200 * 32;             // 64*3200 f32

    dim3 blk(256, 1, 1);

    // 1: twiddle + all 4 projection GEMMs
    init_proj_kernel<<<dim3(1296), blk, 0, stream>>>(
        tw, x, ctx, s_q_w, t_q_w, s_kv_w, t_kv_w, sq, tq, skv, tkv);

    // 2: three forward DFTs + attention K/V prepack
    fwd3_prepack_kernel<<<dim3(3 * kB * kC + kB * kNH * 49), blk, 0, stream>>>(
        sq, skv, tkv + kCN, fQ, fK, fV, tw, tkv, Kp, Vp);

    // 3: both inverse DFTs + attention (independent; interleaved co-schedule)
    inv_attn_kernel<<<dim3(2624), blk, 0, stream>>>(
        fQ, fK, fV, t_cw, vloc, sq, skv, s_dw_w, s_dw_b, tw,
        tq, Kp, Vp, Opart, lpart);

    // 4: combine k-split partials -> sq += xattn (sq holds vres)
    attn_combine_kernel<<<dim3(49, 16), blk, 0, stream>>>(Opart, lpart, sq);

    // 5: both output projections -> gcat
    gemm_fused<<<dim3(25, 8, kB), blk, 0, stream>>>(
        s_p_w, t_p_w, vloc, sq, s_p_b, t_p_b, gcat, gcat, 4, kC, kCN, 2 * kCN, 256);

    // 6: gate hidden GEMM (BN+ReLU)
    gemm_bn_kernel<<<dim3(25, 4, kB), blk, 0, stream>>>(g_w1, gcat, g_bn_g, g_bn_b, tkv, 2 * kC, 2 * kCN, kCN);

    // 7: gate + blend
    gateblend_kernel<<<dim3(49, kB), blk, 0, stream>>>(tkv, g_w2, g_b2, gcat, out);
}